// Round 9
// baseline (932.737 us; speedup 1.0000x reference)
//
#include <hip/hip_runtime.h>

// ---------------------------------------------------------------------------
// Longformer (2-layer) forward, MI355X.
// R8: (a) revert gemm2 to R6 2-buffer loop; (b) T2 bank-conflict swizzle via
//     pre-swizzled global source (linear LDS dest, XOR'd read granule);
//     (c) new gemm3: 256x256 tile, 8 waves, BK=32, 2-phase -- for QKV-fused
//     and FF1 (32 MFMA/wave/barrier, half the staging traffic).
// ---------------------------------------------------------------------------

#define Bb 2
#define Ss 4096
#define Dd 768
#define Hh 12
#define Gg 33
#define NSEPn 32
#define Ll 2
#define SPAD 4640   // S + 544 (PADL=256 left, 288 right)
#define PADL 256
#define NCLSn 5
#define NCH 16      // key chunks for global-q attention (256 keys each)
#define PARTF 1056  // floats per (bh,qt,chunk) partial: 16*64 o + 16 m + 16 l
#define PSTR 72     // Plds row stride in u16 (144B: 16B-aligned, bank-spread)

typedef unsigned short u16;
typedef __attribute__((ext_vector_type(8))) short bv8;   // 8 x bf16
typedef __attribute__((ext_vector_type(4))) short sv4;   // 4 x bf16
typedef __attribute__((ext_vector_type(4))) float f32x4;

__device__ __forceinline__ float bf2f(u16 u) {
  unsigned v = ((unsigned)u) << 16;
  return __builtin_bit_cast(float, v);
}
__device__ __forceinline__ u16 f2bf(float f) {
  unsigned u = __builtin_bit_cast(unsigned, f);
  u += 0x7fffu + ((u >> 16) & 1u);
  return (u16)(u >> 16);
}
__device__ __forceinline__ void glds16(const void* g, void* l) {
  __builtin_amdgcn_global_load_lds(
      (const __attribute__((address_space(1))) void*)g,
      (__attribute__((address_space(3))) void*)l, 16, 0, 0);
}

// ---------------- sep finding --------------------------------------------
__global__ void sep_find_kernel(const int* __restrict__ ids, int* __restrict__ cnt,
                                int* __restrict__ list) {
  int i = blockIdx.x * 256 + threadIdx.x;
  if (i >= Bb * Ss) return;
  int b = i >> 12;
  if (ids[i] == 2) {
    int idx = atomicAdd(&cnt[b], 1);
    if (idx < 64) list[b * 64 + idx] = i & (Ss - 1);
  }
}

__global__ void sep_sort_kernel(const int* __restrict__ cnt, const int* __restrict__ list,
                                int* __restrict__ gpos) {
  int b = blockIdx.x;
  int t = threadIdx.x;
  int n = cnt[b]; if (n > 64) n = 64;
  if (t < Gg) gpos[b * Gg + t] = (t == 0) ? 0 : (Ss - 1);
  __syncthreads();
  if (t < n) {
    int v = list[b * 64 + t];
    int rank = 0;
    for (int j = 0; j < n; ++j) rank += (list[b * 64 + j] < v) ? 1 : 0;
    if (rank < NSEPn) gpos[b * Gg + 1 + rank] = v;
  }
}

// ------- weight fp32 (K,N) -> bf16 (N,K), batched; src slice (z/grp)*sstr+z%grp
__global__ __launch_bounds__(256)
void wconv_kernel(const float* __restrict__ src0, u16* __restrict__ dst0,
                  int K, int N, int grp, int sstr, long unit, long WLs) {
  __shared__ float t[32][33];
  int z = blockIdx.z;
  const float* src = src0 + (size_t)((z / grp) * sstr + (z % grp)) * K * N;
  u16* dst = dst0 + (size_t)(z / grp) * WLs + (size_t)(z % grp) * unit;
  int n0 = blockIdx.x * 32, k0 = blockIdx.y * 32;
  int tx = threadIdx.x & 31, ty = threadIdx.x >> 5;  // ty 0..7
  #pragma unroll
  for (int i = 0; i < 4; ++i)
    t[ty + i * 8][tx] = src[(size_t)(k0 + ty + i * 8) * N + n0 + tx];
  __syncthreads();
  #pragma unroll
  for (int i = 0; i < 4; ++i)
    dst[(size_t)(n0 + ty + i * 8) * K + k0 + tx] = f2bf(t[tx][ty + i * 8]);
}

// ---------------- embedding + LN -------------------------------------------
__global__ __launch_bounds__(256)
void embed_ln_kernel(const int* __restrict__ ids, const float* __restrict__ we,
                     const float* __restrict__ pe, const float* __restrict__ te,
                     const float* __restrict__ lnp, float* __restrict__ x,
                     u16* __restrict__ xb) {
  int row = blockIdx.x;
  int s = row & (Ss - 1);
  int id = ids[row];
  int tid = threadIdx.x;
  float v[3]; float sm = 0.f, s2 = 0.f;
  #pragma unroll
  for (int i = 0; i < 3; ++i) {
    int c = tid + i * 256;
    float t = we[(size_t)id * Dd + c] + pe[(size_t)(s + 2) * Dd + c] + te[c];
    v[i] = t; sm += t; s2 += t * t;
  }
  __shared__ float r1[256], r2[256];
  r1[tid] = sm; r2[tid] = s2; __syncthreads();
  for (int o = 128; o; o >>= 1) {
    if (tid < o) { r1[tid] += r1[tid + o]; r2[tid] += r2[tid + o]; }
    __syncthreads();
  }
  float mean = r1[0] * (1.f / 768.f);
  float var  = r2[0] * (1.f / 768.f) - mean * mean;
  float rs = rsqrtf(var + 1e-5f);
  #pragma unroll
  for (int i = 0; i < 3; ++i) {
    int c = tid + i * 256;
    float o = (v[i] - mean) * rs * lnp[c] + lnp[Dd + c];
    x[(size_t)row * Dd + c] = o;
    xb[(size_t)row * Dd + c] = f2bf(o);
  }
}

// ---------------- residual(3-input) + LN ------------------------------------
__global__ __launch_bounds__(256)
void add_ln3_kernel(const float* __restrict__ xin, const float* __restrict__ y0,
                    const float* __restrict__ y1, const float* __restrict__ lnp,
                    float* __restrict__ xout, u16* __restrict__ xbout) {
  int row = blockIdx.x;
  int tid = threadIdx.x;
  float v[3]; float sm = 0.f, s2 = 0.f;
  #pragma unroll
  for (int i = 0; i < 3; ++i) {
    int c = tid + i * 256;
    size_t idx = (size_t)row * Dd + c;
    float t = xin[idx] + y0[idx] + y1[idx];
    v[i] = t; sm += t; s2 += t * t;
  }
  __shared__ float r1[256], r2[256];
  r1[tid] = sm; r2[tid] = s2; __syncthreads();
  for (int o = 128; o; o >>= 1) {
    if (tid < o) { r1[tid] += r1[tid + o]; r2[tid] += r2[tid + o]; }
    __syncthreads();
  }
  float mean = r1[0] * (1.f / 768.f);
  float var  = r2[0] * (1.f / 768.f) - mean * mean;
  float rs = rsqrtf(var + 1e-5f);
  #pragma unroll
  for (int i = 0; i < 3; ++i) {
    int c = tid + i * 256;
    float o = (v[i] - mean) * rs * lnp[c] + lnp[Dd + c];
    xout[(size_t)row * Dd + c] = o;
    xbout[(size_t)row * Dd + c] = f2bf(o);
  }
}

// ---------------- GEMM2: 128x128 2-buffer (R6 structure) + T2 swizzle -------
// MODE 0: fp32 [M][N] (+bias on z==0); z==1 writes outf2 (split-K)
// MODE 4: bf16 [M][N] * scale
template <int MODE>
__global__ __launch_bounds__(256)
void gemm2_kernel(const u16* __restrict__ A, const u16* __restrict__ Bt,
                  const float* __restrict__ bias, float* __restrict__ outf,
                  float* __restrict__ outf2, u16* __restrict__ o0,
                  int N, int Ks, int Kl, float scale) {
  __shared__ u16 la[2][128 * 32], lb[2][128 * 32];
  int tid = threadIdx.x;
  int wave = tid >> 6, lane = tid & 63;
  int wr = wave >> 1, wc = wave & 1;
  int lg = lane >> 4, lc = lane & 15;
  int row0 = blockIdx.y * 128, col0 = blockIdx.x * 128;
  int koff = blockIdx.z * Kl;

  // T2 swizzle: linear LDS dest; lane fetches logical granule (l&3)^((l>>3)&3)
  int sgr = (lane & 3) ^ ((lane >> 3) & 3);
  const u16* Ag = A + (size_t)(row0 + wave * 32 + (lane >> 2)) * Ks + sgr * 8 + koff;
  const u16* Bg = Bt + (size_t)(col0 + wave * 32 + (lane >> 2)) * Ks + sgr * 8 + koff;
  int wofs = wave * 1024;
  int gph = (lg ^ ((lc >> 1) & 3)) * 8;   // swizzled read granule offset (u16)

  f32x4 acc[4][4];
  #pragma unroll
  for (int m = 0; m < 4; ++m)
    #pragma unroll
    for (int n = 0; n < 4; ++n) acc[m][n] = (f32x4){0.f, 0.f, 0.f, 0.f};

  glds16(Ag, la[0] + wofs);
  glds16(Ag + (size_t)16 * Ks, la[0] + wofs + 512);
  glds16(Bg, lb[0] + wofs);
  glds16(Bg + (size_t)16 * Ks, lb[0] + wofs + 512);
  __syncthreads();

  int nk = Kl >> 5;
  for (int t = 0; t < nk; ++t) {
    int cur = t & 1;
    if (t + 1 < nk) {
      int k1 = (t + 1) << 5;
      glds16(Ag + k1, la[cur ^ 1] + wofs);
      glds16(Ag + (size_t)16 * Ks + k1, la[cur ^ 1] + wofs + 512);
      glds16(Bg + k1, lb[cur ^ 1] + wofs);
      glds16(Bg + (size_t)16 * Ks + k1, lb[cur ^ 1] + wofs + 512);
    }
    bv8 af[4], bf_[4];
    #pragma unroll
    for (int m = 0; m < 4; ++m)
      af[m] = *reinterpret_cast<const bv8*>(la[cur] + (wr * 64 + m * 16 + lc) * 32 + gph);
    #pragma unroll
    for (int n = 0; n < 4; ++n)
      bf_[n] = *reinterpret_cast<const bv8*>(lb[cur] + (wc * 64 + n * 16 + lc) * 32 + gph);
    __builtin_amdgcn_s_setprio(1);
    #pragma unroll
    for (int m = 0; m < 4; ++m)
      #pragma unroll
      for (int n = 0; n < 4; ++n)
        acc[m][n] = __builtin_amdgcn_mfma_f32_16x16x32_bf16(af[m], bf_[n], acc[m][n], 0, 0, 0);
    __builtin_amdgcn_s_setprio(0);
    __syncthreads();
  }

  #pragma unroll
  for (int m = 0; m < 4; ++m) {
    int grow0 = row0 + wr * 64 + m * 16 + lg * 4;
    #pragma unroll
    for (int n = 0; n < 4; ++n) {
      int gcol = col0 + wc * 64 + n * 16 + lc;
      float bvl = bias[gcol];
      if (MODE == 0) {
        float* od = blockIdx.z ? outf2 : outf;
        float badd = blockIdx.z ? 0.f : bvl;
        #pragma unroll
        for (int r = 0; r < 4; ++r)
          od[(size_t)(grow0 + r) * N + gcol] = acc[m][n][r] + badd;
      } else {
        #pragma unroll
        for (int r = 0; r < 4; ++r)
          o0[(size_t)(grow0 + r) * N + gcol] = f2bf((acc[m][n][r] + bvl) * scale);
      }
    }
  }
}

// ---------------- GEMM3: 256x256 tile, 8 waves, BK=32, 2-buffer + swizzle ---
// MODE 1: bf16 [M][N], exact gelu (FF1)
// MODE 2: fused QKV+gKV: N=3840; secs: q pk / k pad / v^T pad / gk pk / gv^T
template <int MODE>
__global__ __launch_bounds__(512, 2)
void gemm3_kernel(const u16* __restrict__ A, const u16* __restrict__ Bt,
                  const float* __restrict__ bias,
                  u16* __restrict__ o0, u16* __restrict__ o1, u16* __restrict__ o2,
                  u16* __restrict__ o3, u16* __restrict__ o4,
                  int N, int K, float scale) {
  __shared__ u16 SA[2][8192], SB[2][8192];  // [dbuf][half*4096 + row*32 + g*8]
  int tid = threadIdx.x;                    // 0..511
  int w = tid >> 6, lane = tid & 63;
  int wm = w >> 2, wn = w & 3;
  int lg = lane >> 4, lc = lane & 15;
  int row0 = blockIdx.y * 256, col0 = blockIdx.x * 256;

  // staging: thread t covers (per half) row t>>2, phys granule t&3;
  // pre-swizzled source granule = (t&3)^((t>>3)&3)
  int srow = tid >> 2;
  int sgr  = (tid & 3) ^ ((tid >> 3) & 3);
  const u16* Ag0 = A + (size_t)(row0 + srow) * K + sgr * 8;
  const u16* Ag1 = Ag0 + (size_t)128 * K;
  const u16* Bg0 = Bt + (size_t)(col0 + srow) * K + sgr * 8;
  const u16* Bg1 = Bg0 + (size_t)128 * K;
  int wofs = w * 512;                       // u16, per-wave dest base
  int gph = (lg ^ ((lc >> 1) & 3)) * 8;     // swizzled read granule offset

  f32x4 acc[8][4];
  #pragma unroll
  for (int m = 0; m < 8; ++m)
    #pragma unroll
    for (int n = 0; n < 4; ++n) acc[m][n] = (f32x4){0.f, 0.f, 0.f, 0.f};

  glds16(Ag0, &SA[0][wofs]);
  glds16(Ag1, &SA[0][4096 + wofs]);
  glds16(Bg0, &SB[0][wofs]);
  glds16(Bg1, &SB[0][4096 + wofs]);
  __syncthreads();

  const int nk = K >> 5;
  const u16* pa_base;
  const u16* pb_base;
  int brow = (wn & 1) * 64;
  for (int t = 0; t < nk; ++t) {
    int cur = t & 1;
    if (t + 1 < nk) {
      int k1 = (t + 1) << 5;
      glds16(Ag0 + k1, &SA[cur ^ 1][wofs]);
      glds16(Ag1 + k1, &SA[cur ^ 1][4096 + wofs]);
      glds16(Bg0 + k1, &SB[cur ^ 1][wofs]);
      glds16(Bg1 + k1, &SB[cur ^ 1][4096 + wofs]);
    }
    pa_base = &SA[cur][wm * 4096];
    pb_base = &SB[cur][(wn >> 1) * 4096];
    bv8 af[8], bf_[4];
    #pragma unroll
    for (int fm = 0; fm < 8; ++fm)
      af[fm] = *reinterpret_cast<const bv8*>(pa_base + (fm * 16 + lc) * 32 + gph);
    #pragma unroll
    for (int fn = 0; fn < 4; ++fn)
      bf_[fn] = *reinterpret_cast<const bv8*>(pb_base + (brow + fn * 16 + lc) * 32 + gph);
    __builtin_amdgcn_s_setprio(1);
    #pragma unroll
    for (int fm = 0; fm < 8; ++fm)
      #pragma unroll
      for (int fn = 0; fn < 4; ++fn)
        acc[fm][fn] = __builtin_amdgcn_mfma_f32_16x16x32_bf16(af[fm], bf_[fn], acc[fm][fn], 0, 0, 0);
    __builtin_amdgcn_s_setprio(0);
    __syncthreads();
  }

  int sec = (MODE == 2) ? (col0 / 768) : 0;   // block-uniform (768 % 256 == 0)
  #pragma unroll
  for (int fm = 0; fm < 8; ++fm) {
    int grow0 = row0 + wm * 128 + fm * 16 + lg * 4;
    #pragma unroll
    for (int fn = 0; fn < 4; ++fn) {
      int gcol = col0 + wn * 64 + fn * 16 + lc;
      float bvl = bias[gcol];
      if (MODE == 1) {
        #pragma unroll
        for (int r = 0; r < 4; ++r) {
          float v = acc[fm][fn][r] + bvl;
          v = 0.5f * v * (1.0f + erff(v * 0.70710678118654752f));
          o0[(size_t)(grow0 + r) * N + gcol] = f2bf(v);
        }
      } else {
        int colr = gcol - sec * 768;
        int hh = colr >> 6, d = colr & 63;
        int bb = grow0 >> 12, s = grow0 & (Ss - 1);
        size_t bhh = (size_t)(bb * Hh + hh);
        if (sec == 0) {
          #pragma unroll
          for (int r = 0; r < 4; ++r)
            o0[(bhh * Ss + s + r) * 64 + d] = f2bf((acc[fm][fn][r] + bvl) * scale);
        } else if (sec == 1) {
          #pragma unroll
          for (int r = 0; r < 4; ++r)
            o1[(bhh * SPAD + PADL + s + r) * 64 + d] = f2bf(acc[fm][fn][r] + bvl);
        } else if (sec == 2) {
          sv4 pk;
          #pragma unroll
          for (int r = 0; r < 4; ++r) pk[r] = (short)f2bf(acc[fm][fn][r] + bvl);
          *reinterpret_cast<sv4*>(o2 + (bhh * 64 + d) * SPAD + PADL + s) = pk;
        } else if (sec == 3) {
          #pragma unroll
          for (int r = 0; r < 4; ++r)
            o3[(bhh * Ss + s + r) * 64 + d] = f2bf(acc[fm][fn][r] + bvl);
        } else {
          sv4 pk;
          #pragma unroll
          for (int r = 0; r < 4; ++r) pk[r] = (short)f2bf(acc[fm][fn][r] + bvl);
          *reinterpret_cast<sv4*>(o4 + (bhh * 64 + d) * Ss + s) = pk;
        }
      }
    }
  }
}

// ---------------- gathers ---------------------------------------------------
__global__ __launch_bounds__(256)
void gather_glob_kernel(const u16* __restrict__ kpk, const u16* __restrict__ vtpk,
                        const int* __restrict__ gpos, u16* __restrict__ kg,
                        u16* __restrict__ vgt) {
  int bh = blockIdx.x;
  int b = bh / Hh;
  int tid = threadIdx.x;
  for (int idx = tid; idx < 64 * 64; idx += 256) {
    int g = idx >> 6, d = idx & 63;
    u16 kv = 0, vv = 0;
    if (g < Gg) {
      int p = gpos[b * Gg + g];
      kv = kpk[((size_t)bh * SPAD + PADL + p) * 64 + d];
      vv = vtpk[((size_t)bh * 64 + d) * SPAD + PADL + p];
    }
    kg[(size_t)bh * 4096 + idx] = kv;
    vgt[((size_t)bh * 64 + d) * 64 + g] = vv;
  }
}

__global__ __launch_bounds__(256)
void gather_xg_kernel(const u16* __restrict__ xb, const int* __restrict__ gpos,
                      u16* __restrict__ xg) {
  int rg = blockIdx.x;  // b*G+g
  int b = rg / Gg;
  int p = gpos[rg];
  int tid = threadIdx.x;
  for (int c = tid; c < Dd; c += 256)
    xg[(size_t)rg * Dd + c] = xb[((size_t)b * Ss + p) * Dd + c];
}

// ---------------- local (sliding window + global-key) attention -------------
#define LOCAL_NB (Bb * Hh * (Ss / 64))   // 1536 blocks, %8 == 0
__global__ __launch_bounds__(256)
void attn_local_kernel(const u16* __restrict__ qpk, const u16* __restrict__ kpk,
                       const u16* __restrict__ vtpk, const u16* __restrict__ kg,
                       const u16* __restrict__ vgt, const int* __restrict__ amask,
                       u16* __restrict__ ctx) {
  __shared__ u16 Plds[4][16 * PSTR];
  int bid = blockIdx.x;
  int swz = (bid & 7) * (LOCAL_NB / 8) + (bid >> 3);
  int qb = swz & 63;
  int bh = swz >> 6;
  int b = bh / Hh;
  int h = bh - b * Hh;
  int wv = threadIdx.x >> 6;
  int q0 = qb * 64 + wv * 16;
  int lane = threadIdx.x & 63;
  int lg = lane >> 4, lc = lane & 15;
  int lg4 = lg * 4;
  int q = q0 + lc;   // query owned by this lane for softmax state

  const u16* qbase = qpk + (((size_t)bh) * Ss + q0) * 64;
  bv8 aq0 = *reinterpret_cast<const bv8*>(qbase + (size_t)lc * 64 + lg * 8);
  bv8 aq1 = *reinterpret_cast<const bv8*>(qbase + (size_t)lc * 64 + 32 + lg * 8);

  f32x4 o[4];
  #pragma unroll
  for (int i = 0; i < 4; ++i) o[i] = (f32x4){0.f, 0.f, 0.f, 0.f};
  float mrun = -1e30f, lrun = 0.f;

  const u16* kgb = kg + ((size_t)bh) * 64 * 64;
  const u16* vgb = vgt + ((size_t)bh) * 64 * 64;
  const u16* kb = kpk + ((size_t)bh) * SPAD * 64;
  const u16* vb = vtpk + ((size_t)bh) * 64 * SPAD;
  const int* amb = amask + b * Ss;
  u16* P = &Plds[wv][0];

  // preload K frags for step 0 (global keys)
  bv8 kc[8];
  #pragma unroll
  for (int j = 0; j < 4; ++j) {
    const u16* kr = kgb + (size_t)(j * 16 + lc) * 64;
    kc[2 * j]     = *reinterpret_cast<const bv8*>(kr + lg * 8);
    kc[2 * j + 1] = *reinterpret_cast<const bv8*>(kr + 32 + lg * 8);
  }
  // prefetch amask word for step 1
  int amvN;
  { int ni = min(max(q0 - 256 + lane, 0), Ss - 1); amvN = amb[ni]; }

  for (int step = 0; step < 10; ++step) {
    bool isg = (step == 0);
    int ks = isg ? 0 : (q0 - 256 + (step - 1) * 64);
    int amvC = amvN;
    if (step < 9) { int ni = min(max(q0 - 256 + step * 64 + lane, 0), Ss - 1); amvN = amb[ni]; }

    // issue V loads for this step (consumed after softmax)
    bv8 vf[8];
    #pragma unroll
    for (int j2 = 0; j2 < 2; ++j2)
      #pragma unroll
      for (int nt = 0; nt < 4; ++nt) {
        const u16* vr = isg ? (vgb + (size_t)(nt * 16 + lc) * 64 + j2 * 32)
                            : (vb + (size_t)(nt * 16 + lc) * SPAD + PADL + ks + j2 * 32);
        vf[j2 * 4 + nt] = *reinterpret_cast<const bv8*>(vr + lg * 8);
      }
    // key-validity mask
    unsigned long long kmask;
    if (isg) {
      kmask = (1ull << Gg) - 1;
    } else {
      int kidx = ks + lane;
      kmask = __ballot((kidx >= 0) && (kidx < Ss) && (amvC > 0));
    }
    // QK^T (swapped operands): sc[j] = scores for keys ks+j*16+lg4..+3, query lc
    f32x4 sc[4];
    __builtin_amdgcn_s_setprio(1);
    #pragma unroll
    for (int j = 0; j < 4; ++j) {
      f32x4 z = (f32x4){0.f, 0.f, 0.f, 0.f};
      sc[j] = __builtin_amdgcn_mfma_f32_16x16x32_bf16(kc[2 * j], aq0, z, 0, 0, 0);
      sc[j] = __builtin_amdgcn_mfma_f32_16x16x32_bf16(kc[2 * j + 1], aq1, sc[j], 0, 0, 0);
    }
    __builtin_amdgcn_s_setprio(0);
    // reload kc IN PLACE for next step (WAR on QK^T; hides under softmax+PV)
    if (step < 9) {
      int ksn = q0 - 256 + step * 64;
      #pragma unroll
      for (int j = 0; j < 4; ++j) {
        const u16* kr = kb + (size_t)(PADL + ksn + j * 16 + lc) * 64;
        kc[2 * j]     = *reinterpret_cast<const bv8*>(kr + lg * 8);
        kc[2 * j + 1] = *reinterpret_cast<const bv8*>(kr + 32 + lg * 8);
      }
    }
    // masking: steps 2..8 with full kmask are band-safe for all 16 queries
    float mloc = -1e30f;
    bool fast = (!isg) && (step >= 2) && (step <= 8) && (kmask == ~0ull);
    if (fast) {
      #pragma unroll
      for (int j = 0; j < 4; ++j)
        #pragma unroll
        for (int r = 0; r < 4; ++r) mloc = fmaxf(mloc, sc[j][r]);
    } else {
      #pragma unroll
      for (int j = 0; j < 4; ++j)
        #pragma unroll
        for (int r = 0; r < 4; ++r) {
          int kk = ks + j * 16 + lg4 + r;
          bool ok = (kmask >> (j * 16 + lg4 + r)) & 1;
          if (!isg) ok = ok && ((unsigned)(kk - q + 256) <= 512u);
          sc[j][r] = ok ? sc[j][r] : -1e9f;
          mloc = fmaxf(mloc, sc[j][r]);
        }
    }
    mloc = fmaxf(mloc, __shfl_xor(mloc, 16));
    mloc = fmaxf(mloc, __shfl_xor(mloc, 32));
    if (__any(mloc > mrun)) {
      float nm = fmaxf(mrun, mloc);
      float scal = __expf(mrun - nm);
      mrun = nm;
      lrun *= scal;
      #pragma unroll
      for (int r = 0; r < 4; ++r) {
        float sr = __shfl(scal, lg4 + r);  // scal of query lg4+r
        #pragma unroll
        for (int nt = 0; nt < 4; ++nt) o[nt][r] *= sr;
      }
    }
    float psum = 0.f;
    #pragma unroll
    for (int j = 0; j < 4; ++j) {
      sv4 pk;
      #pragma unroll
      for (int r = 0; r < 4; ++r) {
        float p = __expf(sc[j][r] - mrun);
        psum += p;
        pk[r] = (short)f2bf(p);
      }
      *reinterpret_cast<sv4*>(P + lc * PSTR + j * 16 + lg4) = pk;
    }
    psum += __shfl_xor(psum, 16);
    psum += __shfl_xor(psum, 32);
    lrun += psum;
    // PV with prefetched V frags
    __builtin_amdgcn_s_setprio(1);
    #pragma unroll
    for (int j2 = 0; j2 < 2; ++j2) {
      bv8 ap = *reinterpret_cast<const bv8*>(P + lc * PSTR + j2 * 32 + lg * 8);
      #pragma unroll
      for (int nt = 0; nt < 4; ++nt)
        o[nt] = __builtin_amdgcn_mfma_f32_16x16x32_bf16(ap, vf[j2 * 4 + nt], o[nt], 0, 0, 0);
    }
    __builtin_amdgcn_s_setprio(0);
  }
  float inv = 1.0f / lrun;
  #pragma unroll
  for (int r = 0; r < 4; ++r) {
    float invr = __shfl(inv, lg4 + r);
    size_t rowoff = ((size_t)b * Ss + q0 + lg4 + r) * Dd + h * 64;
    #pragma unroll
    for (int nt = 0; nt < 4; ++nt)
      ctx[rowoff + nt * 16 + lc] = f2bf(o[nt][r] * invr);
  }
}

// ---------------- global-query attention: chunked flash MFMA ----------------
__global__ __launch_bounds__(192)
void attn_globalq_kernel(const u16* __restrict__ qgb, const u16* __restrict__ kgf,
                         const u16* __restrict__ vgt, const int* __restrict__ amask,
                         float* __restrict__ part) {
  __shared__ u16 Plds[3][16 * 32];
  int blk = blockIdx.x;
  int ch = blk & (NCH - 1);
  int bh = blk / NCH;
  int b = bh / Hh, h = bh - b * Hh;
  int wv = threadIdx.x >> 6;  // q-tile 0..2
  int lane = threadIdx.x & 63;
  int lg = lane >> 4, lc = lane & 15;

  int qrow = wv * 16 + lc;
  bv8 aq0 = (bv8)0, aq1 = (bv8)0;
  if (qrow < Gg) {
    const u16* qr = qgb + (size_t)(b * Gg + qrow) * Dd + h * 64;
    aq0 = *reinterpret_cast<const bv8*>(qr + lg * 8);
    aq1 = *reinterpret_cast<const bv8*>(qr + 32 + lg * 8);
  }

  f32x4 o[4];
  float mrun[4], lrun[4];
  #pragma unroll
  for (int i = 0; i < 4; ++i) { o[i] = (f32x4){0.f,0.f,0.f,0.f}; mrun[i] = -1e30f; lrun[i] = 0.f; }

  const u16* kb = kgf + ((size_t)bh) * Ss * 64;
  const u16* vb = vgt + ((size_t)bh) * 64 * Ss;
  const int* amb = amask + b * Ss;
  int ks0 = ch * (Ss / NCH);

  for (int st = 0; st < (Ss / NCH) / 32; ++st) {
    int ks = ks0 + st * 32;
    f32x4 sc0, sc1;
    {
      const u16* kr0 = kb + (size_t)(ks + lc) * 64;
      const u16* kr1 = kr0 + 16 * 64;
      bv8 b00 = *reinterpret_cast<const bv8*>(kr0 + lg * 8);
      bv8 b01 = *reinterpret_cast<const bv8*>(kr0 + 32 + lg * 8);
      bv8 b10 = *reinterpret_cast<const bv8*>(kr1 + lg * 8);
      bv8 b11 = *reinterpret_cast<const bv8*>(kr1 + 32 + lg * 8);
      f32x4 z = (f32x4){0.f,0.f,0.f,0.f};
      sc0 = __builtin_amdgcn_mfma_f32_16x16x32_bf16(aq0, b00, z, 0, 0, 0);
      sc0 = __builtin_amdgcn_mfma_f32_16x16x32_bf16(aq1, b01, sc0, 0, 0, 0);
      sc1 = __builtin_amdgcn_mfma_f32_16x16x32_bf16(aq0, b10, z, 0, 0, 0);
      sc1 = __builtin_amdgcn_mfma_f32_16x16x32_bf16(aq1, b11, sc1, 0, 0, 0);
    }
    bool v0 = amb[ks + lc] > 0;
    bool v1 = amb[ks + 16 + lc] > 0;
    #pragma unroll
    for (int r = 0; r < 4; ++r) {
      float s0 = v0 ? sc0[r] : -1e9f;
      float s1 = v1 ? sc1[r] : -1e9f;
      float rm = fmaxf(s0, s1);
      #pragma unroll
      for (int off = 1; off < 16; off <<= 1) rm = fmaxf(rm, __shfl_xor(rm, off));
      float nm = fmaxf(mrun[r], rm);
      float scal = __expf(mrun[r] - nm);
      float p0 = __expf(s0 - nm);
      float p1 = __expf(s1 - nm);
      float ps = p0 + p1;
      #pragma unroll
      for (int off = 1; off < 16; off <<= 1) ps += __shfl_xor(ps, off);
      lrun[r] = lrun[r] * scal + ps;
      mrun[r] = nm;
      #pragma unroll
      for (int nt = 0; nt < 4; ++nt) o[nt][r] *= scal;
      int prow = lg * 4 + r;
      Plds[wv][prow * 32 + lc] = f2bf(p0);
      Plds[wv][prow * 32 + 16 + lc] = f2bf(p1);
    }
    bv8 ap = *reinterpret_cast<const bv8*>(&Plds[wv][lc * 32 + lg * 8]);
    #pragma unroll
    for (int nt = 0; nt < 4; ++nt) {
      const u16* vr = vb + (size_t)(nt * 16 + lc) * Ss + ks;
      bv8 bvv = *reinterpret_cast<const bv8*>(vr + lg * 8);
      o[nt] = __builtin_amdgcn_mfma_f32_16x16x32_bf16(ap, bvv, o[nt], 0, 0, 0);
    }
  }

  float* pb = part + ((size_t)(bh * 3 + wv) * NCH + ch) * PARTF;
  #pragma unroll
  for (int r = 0; r < 4; ++r) {
    int row = lg * 4 + r;
    #pragma unroll
    for (int nt = 0; nt < 4; ++nt)
      pb[row * 64 + nt * 16 + lc] = o[nt][r];
    if (lc == 0) {
      pb[1024 + row] = mrun[r];
      pb[1040 + row] = lrun[r];
    }
  }
}

// merge NCH chunk-partials and scatter into ctx rows at gpos
__global__ __launch_bounds__(256)
void attn_gmerge_kernel(const float* __restrict__ part, const int* __restrict__ gpos,
                        u16* __restrict__ ctx) {
  __shared__ float wgt[Gg][NCH];
  __shared__ float sinvl[Gg];
  int bh = blockIdx.x;
  int b = bh / Hh, h = bh - b * Hh;
  int tid = threadIdx.x;
  if (tid < Gg) {
    int qt = tid >> 4, rr = tid & 15;
    const float* pb = part + ((size_t)(bh * 3 + qt) * NCH) * PARTF;
    float mx = -1e30f;
    for (int c = 0; c < NCH; ++c) mx = fmaxf(mx, pb[c * PARTF + 1024 + rr]);
    float l = 0.f;
    for (int c = 0; c < NCH; ++c) {
      float w = __expf(pb[c * PARTF + 1024 + rr] - mx);
      wgt[tid][c] = w;
      l += w * pb[c * PARTF + 1040 + rr];
    }
    sinvl[tid] = 1.0f / l;
  }
  __syncthreads();
  for (int e = tid; e < Gg * 64; e += 256) {
    int row = e >> 6, d = e & 63;
    int qt = row >> 4, rr = row & 15;
    const float* pb = part + ((size_t)(bh * 3 + qt) * NCH) * PARTF + rr * 64 + d;
    float acc = 0.f;
    #pragma unroll
    for (int c = 0; c < NCH; ++c) acc += wgt[row][c] * pb[c * PARTF];
    int pos = gpos[b * Gg + row];
    ctx[((size_t)b * Ss + pos) * Dd + h * 64 + d] = f2bf(acc * sinvl[row]);
  }
}

// ---------------- classifier ------------------------------------------------
__global__ __launch_bounds__(64)
void cls_kernel(const float* __restrict__ x, const float* __restrict__ W,
                const float* __restrict__ bias, const int* __restrict__ gpos,
                float* __restrict__ out) {
  int r = blockIdx.x;  // b*32 + i
  int b = r >> 5, i = r & 31;
  int pos = gpos[b * Gg + 1 + i];
  int lane = threadIdx.x;
  const float* xr = x + ((size_t)b * Ss + pos) * Dd;
  float acc[NCLSn] = {0.f, 0.f, 0.f, 0.f, 0.f};
  for (int k = lane; k < Dd; k += 64) {
    float xv = xr[k];
    #pragma unroll
    for (int c = 0; c < NCLSn; ++c) acc[c] += xv * W[c * Dd + k];
  }
  #pragma unroll
  for (int c = 0; c < NCLSn; ++c) {
    #pragma unroll
    for (int off = 1; off < 64; off <<= 1) acc[c] += __shfl_xor(acc[c], off);
  }
  if (lane == 0) {
    #pragma unroll
    for (int c = 0; c < NCLSn; ++c) out[r * NCLSn + c] = acc[c] + bias[c];
  }
}

// ---------------------------------------------------------------------------
extern "C" void kernel_launch(void* const* d_in, const int* in_sizes, int n_in,
                              void* d_out, int out_size, void* d_ws, size_t ws_size,
                              hipStream_t stream) {
  const int* ids     = (const int*)d_in[0];
  const int* amask   = (const int*)d_in[1];
  const float* we    = (const float*)d_in[2];
  const float* pe    = (const float*)d_in[3];
  const float* te    = (const float*)d_in[4];
  const float* embln = (const float*)d_in[5];
  const float* Wqkv  = (const float*)d_in[6];
  const float* bqkv  = (const float*)d_in[7];
  const float* Wqkvg = (const float*)d_in[8];
  const float* bqkvg = (const float*)d_in[9];
  const float* Wo    = (const float*)d_in[10];
  const float* bo    = (const float*)d_in[11];
  const float* ln1   = (const float*)d_in[12];
  const float* Wff1  = (const float*)d_in[13];
  const float* bff1  = (const float*)d_in[14];
  const float* Wff2  = (const float*)d_in[15];
  const float* bff2  = (const float*)d_in[16];
  const float* ln2   = (const float*)d_in[17];
  const float* clsW  = (const float*)d_in[18];
  const float* clsb  = (const float*)d_in[19];
  float* out = (float*)d_out;

  char* ws = (char*)d_ws;
  size_t off = 0;
  auto alloc = [&](size_t bytes) { size_t o = off; off += (bytes + 255) & ~(size_t)255; return o; };

  const size_t DD = (size_t)Dd * Dd;        // 589824
  const size_t DF = (size_t)Dd * 4 * Dd;    // 2359296
  const size_t WL = 7 * DD + 2 * DF;        // elems per layer
  // Wb layout per layer: [q,k,v, gk,gv, gq, wo, ff1, ff2]

  size_t o_cnt  = alloc(Bb * 4);
  size_t o_list = alloc(Bb * 64 * 4);
  size_t o_gpos = alloc(Bb * Gg * 4);
  size_t o_bias = alloc((size_t)Ll * 3840 * 4);
  size_t o_w    = alloc(WL * Ll * 2);
  size_t o_x    = alloc((size_t)Bb * Ss * Dd * 4);
  size_t o_xb   = alloc((size_t)Bb * Ss * Dd * 2);
  // kgf/vgf first: their 25.17 MB doubles as split-K buffer B (dead by Wo/FF2)
  size_t o_kgf  = alloc((size_t)Bb * Hh * Ss * 64 * 2);
  size_t o_vgf  = alloc((size_t)Bb * Hh * Ss * 64 * 2);
  size_t o_accB = o_kgf;  // 2*12.58 MB = exactly 8192*768*4 bytes
  size_t o_qpk  = alloc((size_t)Bb * Hh * Ss * 64 * 2);
  size_t o_kpk  = alloc((size_t)Bb * Hh * SPAD * 64 * 2);
  size_t o_vtpk = alloc((size_t)Bb * Hh * 64 * SPAD * 2);
  size_t o_kg   = alloc((size_t)Bb * Hh * 64 * 64 * 2);
  size_t o_vgt  = alloc((size_t)Bb * Hh * 64 * 64 * 2);
  size_t o_xg   = alloc((size_t)128 * Dd * 2);
  size_t o_qg   = alloc((size_t)128 * Dd * 2);
  size_t o_part = alloc((size_t)Bb * Hh * 3 * NCH * PARTF * 4);
  size_t o_f1b  = o_qpk;  // FFN hidden aliases the (dead-by-then) attention buffers
  {
    size_t f1b_bytes = (size_t)Bb * Ss * 4 * Dd * 2;
    if (off - o_qpk < f1b_bytes) off = o_qpk + ((f1b_bytes + 255) & ~(size_t)255);
  }
  size_t o_ctx = alloc((size_t)Bb * Ss * Dd * 2);
  size_t o_acc = alloc((size_t)Bb * Ss * Dd * 4);
  if (ws_size < off) return;  // workspace too small -> fail visibly

  u16* Wb = (u16*)(ws + o_w);
  int* gposp = (int*)(ws + o_gpos);
  float* accA = (float*)(ws + o_acc);
  float* accB = (float*)(ws + o_accB);

  (void)hipMemsetAsync(ws + o_cnt, 0, Bb * 4, stream);
  // zero padded K / V^T so first-call pads are finite (later calls: finite stale bf16)
  (void)hipMemsetAsync(ws + o_kpk, 0, (size_t)Bb * Hh * SPAD * 64 * 2, stream);
  (void)hipMemsetAsync(ws + o_vtpk, 0, (size_t)Bb * Hh * 64 * SPAD * 2, stream);
  (void)hipMemsetAsync(ws + o_xg, 0, (size_t)128 * Dd * 2, stream);

  // concat bias per layer: [bqkv(3x768) | bqkvg_k(768) | bqkvg_v(768)]
  for (int l = 0; l < Ll; ++l) {
    (void)hipMemcpyAsync(ws + o_bias + (size_t)l * 3840 * 4, bqkv + (size_t)l * 3 * Dd,
                         3 * Dd * 4, hipMemcpyDeviceToDevice, stream);
    (void)hipMemcpyAsync(ws + o_bias + (size_t)l * 3840 * 4 + 3 * Dd * 4,
                         bqkvg + (size_t)(l * 3 + 1) * Dd,
                         2 * Dd * 4, hipMemcpyDeviceToDevice, stream);
  }

  sep_find_kernel<<<(Bb * Ss + 255) / 256, 256, 0, stream>>>(ids, (int*)(ws + o_cnt), (int*)(ws + o_list));
  sep_sort_kernel<<<Bb, 64, 0, stream>>>((int*)(ws + o_cnt), (int*)(ws + o_list), gposp);

  // weight conversions (batched over z); Wb layout [q,k,v,gk,gv,gq,wo,ff1,ff2]
  wconv_kernel<<<dim3(24, 24, 6), 256, 0, stream>>>(Wqkv,       Wb,          Dd, Dd, 3, 3, (long)DD, (long)WL);
  wconv_kernel<<<dim3(24, 24, 2), 256, 0, stream>>>(Wqkvg + DD,     Wb + 3 * DD, Dd, Dd, 1, 3, 0L, (long)WL);  // gk
  wconv_kernel<<<dim3(24, 24, 2), 256, 0, stream>>>(Wqkvg + 2 * DD, Wb + 4 * DD, Dd, Dd, 1, 3, 0L, (long)WL);  // gv
  wconv_kernel<<<dim3(24, 24, 2), 256, 0, stream>>>(Wqkvg,          Wb + 5 * DD, Dd, Dd, 1, 3, 0L, (long)WL);  // gq
  wconv_kernel<<<dim3(24, 24, 2), 256, 0, stream>>>(Wo,         Wb + 6 * DD, Dd, Dd, 1, 1, 0L, (long)WL);
  wconv_kernel<<<dim3(96, 24, 2), 256, 0, stream>>>(Wff1,       Wb + 7 * DD, Dd, 4 * Dd, 1, 1, 0L, (long)WL);
  wconv_kernel<<<dim3(24, 96, 2), 256, 0, stream>>>(Wff2,       Wb + 7 * DD + DF, 4 * Dd, Dd, 1, 1, 0L, (long)WL);

  embed_ln_kernel<<<Bb * Ss, 256, 0, stream>>>(ids, we, pe, te, embln, (float*)(ws + o_x), (u16*)(ws + o_xb));

  for (int l = 0; l < Ll; ++l) {
    size_t wb = (size_t)l * WL;
    u16* xb = (u16*)(ws + o_xb);
    // fused QKV + global K/V projection (N=3840, 5 sections) -- 256^2 kernel
    gemm3_kernel<2><<<dim3(15, 32), 512, 0, stream>>>(xb, Wb + wb, (float*)(ws + o_bias) + (size_t)l * 3840,
        (u16*)(ws + o_qpk), (u16*)(ws + o_kpk), (u16*)(ws + o_vtpk),
        (u16*)(ws + o_kgf), (u16*)(ws + o_vgf), 3840, Dd, 0.125f);
    gather_glob_kernel<<<Bb * Hh, 256, 0, stream>>>((u16*)(ws + o_kpk), (u16*)(ws + o_vtpk), gposp, (u16*)(ws + o_kg), (u16*)(ws + o_vgt));
    gather_xg_kernel<<<Bb * Gg, 256, 0, stream>>>(xb, gposp, (u16*)(ws + o_xg));
    // global q projection (M=128 padded rows)
    gemm2_kernel<4><<<dim3(6, 1), 256, 0, stream>>>((u16*)(ws + o_xg), Wb + wb + 5 * DD, bqkvg + (size_t)l * 3 * Dd,
        nullptr, nullptr, (u16*)(ws + o_qg), Dd, Dd, Dd, 0.125f);
    // attention
    attn_local_kernel<<<LOCAL_NB, 256, 0, stream>>>((u16*)(ws + o_qpk), (u16*)(ws + o_kpk), (u16*)(ws + o_vtpk), (u16*)(ws + o_kg), (u16*)(ws + o_vgt), amask, (u16*)(ws + o_ctx));
    attn_globalq_kernel<<<Bb * Hh * NCH, 192, 0, stream>>>((u16*)(ws + o_qg), (u16*)(ws + o_kgf), (u16*)(ws + o_vgf), amask, (float*)(ws + o_part));
    attn_gmerge_kernel<<<Bb * Hh, 256, 0, stream>>>((float*)(ws + o_part), gposp, (u16*)(ws + o_ctx));
    // output projection (split-K x2) + LN   [kgf/vgf dead from here on]
    gemm2_kernel<0><<<dim3(6, 64, 2), 256, 0, stream>>>((u16*)(ws + o_ctx), Wb + wb + 6 * DD, bo + (size_t)l * Dd, accA, accB,
        nullptr, Dd, Dd, Dd / 2, 1.0f);
    add_ln3_kernel<<<Bb * Ss, 256, 0, stream>>>((float*)(ws + o_x), accA, accB, ln1 + (size_t)l * 2 * Dd, (float*)(ws + o_x), xb);
    // FFN: FF1 on 256^2 kernel, FF2 split-K on 128^2
    gemm3_kernel<1><<<dim3(12, 32), 512, 0, stream>>>(xb, Wb + wb + 7 * DD, bff1 + (size_t)l * 4 * Dd,
        (u16*)(ws + o_f1b), nullptr, nullptr, nullptr, nullptr, 4 * Dd, Dd, 1.0f);
    gemm2_kernel<0><<<dim3(6, 64, 2), 256, 0, stream>>>((u16*)(ws + o_f1b), Wb + wb + 7 * DD + DF, bff2 + (size_t)l * Dd, accA, accB,
        nullptr, Dd, 4 * Dd, 2 * Dd, 1.0f);
    add_ln3_kernel<<<Bb * Ss, 256, 0, stream>>>((float*)(ws + o_x), accA, accB, ln2 + (size_t)l * 2 * Dd, (float*)(ws + o_x), xb);
  }

  cls_kernel<<<Bb * NSEPn, 64, 0, stream>>>((float*)(ws + o_x), clsW, clsb, gposp, out);
}

// Round 10
// 852.558 us; speedup vs baseline: 1.0940x; 1.0940x over previous
//
#include <hip/hip_runtime.h>

// ---------------------------------------------------------------------------
// Longformer (2-layer) forward, MI355X.
// R9: revert to 128^2 gemm2 for ALL GEMMs (256^2 tile starved the grid);
//     keep T2 LDS swizzle (verified 0 conflicts) and add T1 XCD-aware
//     bijective block swizzle (A-panel L2 residency -> shorter stage drain).
// ---------------------------------------------------------------------------

#define Bb 2
#define Ss 4096
#define Dd 768
#define Hh 12
#define Gg 33
#define NSEPn 32
#define Ll 2
#define SPAD 4640   // S + 544 (PADL=256 left, 288 right)
#define PADL 256
#define NCLSn 5
#define NCH 16      // key chunks for global-q attention (256 keys each)
#define PARTF 1056  // floats per (bh,qt,chunk) partial: 16*64 o + 16 m + 16 l
#define PSTR 72     // Plds row stride in u16 (144B: 16B-aligned, bank-spread)

typedef unsigned short u16;
typedef __attribute__((ext_vector_type(8))) short bv8;   // 8 x bf16
typedef __attribute__((ext_vector_type(4))) short sv4;   // 4 x bf16
typedef __attribute__((ext_vector_type(4))) float f32x4;

__device__ __forceinline__ float bf2f(u16 u) {
  unsigned v = ((unsigned)u) << 16;
  return __builtin_bit_cast(float, v);
}
__device__ __forceinline__ u16 f2bf(float f) {
  unsigned u = __builtin_bit_cast(unsigned, f);
  u += 0x7fffu + ((u >> 16) & 1u);
  return (u16)(u >> 16);
}
__device__ __forceinline__ void glds16(const void* g, void* l) {
  __builtin_amdgcn_global_load_lds(
      (const __attribute__((address_space(1))) void*)g,
      (__attribute__((address_space(3))) void*)l, 16, 0, 0);
}

// ---------------- sep finding --------------------------------------------
__global__ void sep_find_kernel(const int* __restrict__ ids, int* __restrict__ cnt,
                                int* __restrict__ list) {
  int i = blockIdx.x * 256 + threadIdx.x;
  if (i >= Bb * Ss) return;
  int b = i >> 12;
  if (ids[i] == 2) {
    int idx = atomicAdd(&cnt[b], 1);
    if (idx < 64) list[b * 64 + idx] = i & (Ss - 1);
  }
}

__global__ void sep_sort_kernel(const int* __restrict__ cnt, const int* __restrict__ list,
                                int* __restrict__ gpos) {
  int b = blockIdx.x;
  int t = threadIdx.x;
  int n = cnt[b]; if (n > 64) n = 64;
  if (t < Gg) gpos[b * Gg + t] = (t == 0) ? 0 : (Ss - 1);
  __syncthreads();
  if (t < n) {
    int v = list[b * 64 + t];
    int rank = 0;
    for (int j = 0; j < n; ++j) rank += (list[b * 64 + j] < v) ? 1 : 0;
    if (rank < NSEPn) gpos[b * Gg + 1 + rank] = v;
  }
}

// ------- weight fp32 (K,N) -> bf16 (N,K), batched; src slice (z/grp)*sstr+z%grp
__global__ __launch_bounds__(256)
void wconv_kernel(const float* __restrict__ src0, u16* __restrict__ dst0,
                  int K, int N, int grp, int sstr, long unit, long WLs) {
  __shared__ float t[32][33];
  int z = blockIdx.z;
  const float* src = src0 + (size_t)((z / grp) * sstr + (z % grp)) * K * N;
  u16* dst = dst0 + (size_t)(z / grp) * WLs + (size_t)(z % grp) * unit;
  int n0 = blockIdx.x * 32, k0 = blockIdx.y * 32;
  int tx = threadIdx.x & 31, ty = threadIdx.x >> 5;  // ty 0..7
  #pragma unroll
  for (int i = 0; i < 4; ++i)
    t[ty + i * 8][tx] = src[(size_t)(k0 + ty + i * 8) * N + n0 + tx];
  __syncthreads();
  #pragma unroll
  for (int i = 0; i < 4; ++i)
    dst[(size_t)(n0 + ty + i * 8) * K + k0 + tx] = f2bf(t[tx][ty + i * 8]);
}

// ---------------- embedding + LN -------------------------------------------
__global__ __launch_bounds__(256)
void embed_ln_kernel(const int* __restrict__ ids, const float* __restrict__ we,
                     const float* __restrict__ pe, const float* __restrict__ te,
                     const float* __restrict__ lnp, float* __restrict__ x,
                     u16* __restrict__ xb) {
  int row = blockIdx.x;
  int s = row & (Ss - 1);
  int id = ids[row];
  int tid = threadIdx.x;
  float v[3]; float sm = 0.f, s2 = 0.f;
  #pragma unroll
  for (int i = 0; i < 3; ++i) {
    int c = tid + i * 256;
    float t = we[(size_t)id * Dd + c] + pe[(size_t)(s + 2) * Dd + c] + te[c];
    v[i] = t; sm += t; s2 += t * t;
  }
  __shared__ float r1[256], r2[256];
  r1[tid] = sm; r2[tid] = s2; __syncthreads();
  for (int o = 128; o; o >>= 1) {
    if (tid < o) { r1[tid] += r1[tid + o]; r2[tid] += r2[tid + o]; }
    __syncthreads();
  }
  float mean = r1[0] * (1.f / 768.f);
  float var  = r2[0] * (1.f / 768.f) - mean * mean;
  float rs = rsqrtf(var + 1e-5f);
  #pragma unroll
  for (int i = 0; i < 3; ++i) {
    int c = tid + i * 256;
    float o = (v[i] - mean) * rs * lnp[c] + lnp[Dd + c];
    x[(size_t)row * Dd + c] = o;
    xb[(size_t)row * Dd + c] = f2bf(o);
  }
}

// ---------------- residual(3-input) + LN ------------------------------------
__global__ __launch_bounds__(256)
void add_ln3_kernel(const float* __restrict__ xin, const float* __restrict__ y0,
                    const float* __restrict__ y1, const float* __restrict__ lnp,
                    float* __restrict__ xout, u16* __restrict__ xbout) {
  int row = blockIdx.x;
  int tid = threadIdx.x;
  float v[3]; float sm = 0.f, s2 = 0.f;
  #pragma unroll
  for (int i = 0; i < 3; ++i) {
    int c = tid + i * 256;
    size_t idx = (size_t)row * Dd + c;
    float t = xin[idx] + y0[idx] + y1[idx];
    v[i] = t; sm += t; s2 += t * t;
  }
  __shared__ float r1[256], r2[256];
  r1[tid] = sm; r2[tid] = s2; __syncthreads();
  for (int o = 128; o; o >>= 1) {
    if (tid < o) { r1[tid] += r1[tid + o]; r2[tid] += r2[tid + o]; }
    __syncthreads();
  }
  float mean = r1[0] * (1.f / 768.f);
  float var  = r2[0] * (1.f / 768.f) - mean * mean;
  float rs = rsqrtf(var + 1e-5f);
  #pragma unroll
  for (int i = 0; i < 3; ++i) {
    int c = tid + i * 256;
    float o = (v[i] - mean) * rs * lnp[c] + lnp[Dd + c];
    xout[(size_t)row * Dd + c] = o;
    xbout[(size_t)row * Dd + c] = f2bf(o);
  }
}

// ---------------- GEMM2: 128x128 2-buffer + T2 LDS swizzle + T1 XCD swizzle -
// MODE 0: fp32 [M][N] (+bias on z==0); z==1 writes outf2 (split-K)
// MODE 1: bf16 [M][N], exact gelu
// MODE 2: fused QKV+gKV: N=3840; secs: q pk / k pad / v^T pad / gk pk / gv^T
// MODE 4: bf16 [M][N] * scale
template <int MODE, bool XSWZ>
__global__ __launch_bounds__(256)
void gemm2_kernel(const u16* __restrict__ A, const u16* __restrict__ Bt,
                  const float* __restrict__ bias, float* __restrict__ outf,
                  float* __restrict__ outf2,
                  u16* __restrict__ o0, u16* __restrict__ o1, u16* __restrict__ o2,
                  u16* __restrict__ o3, u16* __restrict__ o4,
                  int N, int Ks, int Kl, float scale) {
  __shared__ u16 la[2][128 * 32], lb[2][128 * 32];
  int tid = threadIdx.x;
  int wave = tid >> 6, lane = tid & 63;
  int wr = wave >> 1, wc = wave & 1;
  int lg = lane >> 4, lc = lane & 15;
  // T1: XCD-aware bijective remap of the x-y plane (requires NB % 8 == 0)
  int bx = blockIdx.x, by = blockIdx.y;
  if (XSWZ) {
    int gx = gridDim.x;
    int nlin = bx + gx * by;
    int NB = gx * gridDim.y;
    nlin = (nlin & 7) * (NB >> 3) + (nlin >> 3);
    bx = nlin % gx;
    by = nlin / gx;
  }
  int row0 = by * 128, col0 = bx * 128;
  int koff = blockIdx.z * Kl;

  // T2 swizzle: linear LDS dest; lane fetches logical granule (l&3)^((l>>3)&3)
  int sgr = (lane & 3) ^ ((lane >> 3) & 3);
  const u16* Ag = A + (size_t)(row0 + wave * 32 + (lane >> 2)) * Ks + sgr * 8 + koff;
  const u16* Bg = Bt + (size_t)(col0 + wave * 32 + (lane >> 2)) * Ks + sgr * 8 + koff;
  int wofs = wave * 1024;
  int gph = (lg ^ ((lc >> 1) & 3)) * 8;   // swizzled read granule offset (u16)

  f32x4 acc[4][4];
  #pragma unroll
  for (int m = 0; m < 4; ++m)
    #pragma unroll
    for (int n = 0; n < 4; ++n) acc[m][n] = (f32x4){0.f, 0.f, 0.f, 0.f};

  glds16(Ag, la[0] + wofs);
  glds16(Ag + (size_t)16 * Ks, la[0] + wofs + 512);
  glds16(Bg, lb[0] + wofs);
  glds16(Bg + (size_t)16 * Ks, lb[0] + wofs + 512);
  __syncthreads();

  int nk = Kl >> 5;
  for (int t = 0; t < nk; ++t) {
    int cur = t & 1;
    if (t + 1 < nk) {
      int k1 = (t + 1) << 5;
      glds16(Ag + k1, la[cur ^ 1] + wofs);
      glds16(Ag + (size_t)16 * Ks + k1, la[cur ^ 1] + wofs + 512);
      glds16(Bg + k1, lb[cur ^ 1] + wofs);
      glds16(Bg + (size_t)16 * Ks + k1, lb[cur ^ 1] + wofs + 512);
    }
    bv8 af[4], bf_[4];
    #pragma unroll
    for (int m = 0; m < 4; ++m)
      af[m] = *reinterpret_cast<const bv8*>(la[cur] + (wr * 64 + m * 16 + lc) * 32 + gph);
    #pragma unroll
    for (int n = 0; n < 4; ++n)
      bf_[n] = *reinterpret_cast<const bv8*>(lb[cur] + (wc * 64 + n * 16 + lc) * 32 + gph);
    __builtin_amdgcn_s_setprio(1);
    #pragma unroll
    for (int m = 0; m < 4; ++m)
      #pragma unroll
      for (int n = 0; n < 4; ++n)
        acc[m][n] = __builtin_amdgcn_mfma_f32_16x16x32_bf16(af[m], bf_[n], acc[m][n], 0, 0, 0);
    __builtin_amdgcn_s_setprio(0);
    __syncthreads();
  }

  #pragma unroll
  for (int m = 0; m < 4; ++m) {
    int grow0 = row0 + wr * 64 + m * 16 + lg * 4;
    #pragma unroll
    for (int n = 0; n < 4; ++n) {
      int gcol = col0 + wc * 64 + n * 16 + lc;
      float bvl = bias[gcol];
      if (MODE == 0) {
        float* od = blockIdx.z ? outf2 : outf;
        float badd = blockIdx.z ? 0.f : bvl;
        #pragma unroll
        for (int r = 0; r < 4; ++r)
          od[(size_t)(grow0 + r) * N + gcol] = acc[m][n][r] + badd;
      } else if (MODE == 1) {
        #pragma unroll
        for (int r = 0; r < 4; ++r) {
          float v = acc[m][n][r] + bvl;
          v = 0.5f * v * (1.0f + erff(v * 0.70710678118654752f));
          o0[(size_t)(grow0 + r) * N + gcol] = f2bf(v);
        }
      } else if (MODE == 4) {
        #pragma unroll
        for (int r = 0; r < 4; ++r)
          o0[(size_t)(grow0 + r) * N + gcol] = f2bf((acc[m][n][r] + bvl) * scale);
      } else if (MODE == 2) {
        int sec = (col0 >> 7) / 6;        // 0..4, block-uniform
        int colr = gcol - sec * 768;
        int hh = colr >> 6, d = colr & 63;
        int bb = grow0 >> 12, s = grow0 & (Ss - 1);
        size_t bhh = (size_t)(bb * Hh + hh);
        if (sec == 0) {
          #pragma unroll
          for (int r = 0; r < 4; ++r)
            o0[(bhh * Ss + s + r) * 64 + d] = f2bf((acc[m][n][r] + bvl) * scale);
        } else if (sec == 1) {
          #pragma unroll
          for (int r = 0; r < 4; ++r)
            o1[(bhh * SPAD + PADL + s + r) * 64 + d] = f2bf(acc[m][n][r] + bvl);
        } else if (sec == 2) {
          sv4 pk;
          #pragma unroll
          for (int r = 0; r < 4; ++r) pk[r] = (short)f2bf(acc[m][n][r] + bvl);
          *reinterpret_cast<sv4*>(o2 + (bhh * 64 + d) * SPAD + PADL + s) = pk;
        } else if (sec == 3) {
          #pragma unroll
          for (int r = 0; r < 4; ++r)
            o3[(bhh * Ss + s + r) * 64 + d] = f2bf(acc[m][n][r] + bvl);
        } else {
          sv4 pk;
          #pragma unroll
          for (int r = 0; r < 4; ++r) pk[r] = (short)f2bf(acc[m][n][r] + bvl);
          *reinterpret_cast<sv4*>(o4 + (bhh * 64 + d) * Ss + s) = pk;
        }
      }
    }
  }
}

// ---------------- gathers ---------------------------------------------------
__global__ __launch_bounds__(256)
void gather_glob_kernel(const u16* __restrict__ kpk, const u16* __restrict__ vtpk,
                        const int* __restrict__ gpos, u16* __restrict__ kg,
                        u16* __restrict__ vgt) {
  int bh = blockIdx.x;
  int b = bh / Hh;
  int tid = threadIdx.x;
  for (int idx = tid; idx < 64 * 64; idx += 256) {
    int g = idx >> 6, d = idx & 63;
    u16 kv = 0, vv = 0;
    if (g < Gg) {
      int p = gpos[b * Gg + g];
      kv = kpk[((size_t)bh * SPAD + PADL + p) * 64 + d];
      vv = vtpk[((size_t)bh * 64 + d) * SPAD + PADL + p];
    }
    kg[(size_t)bh * 4096 + idx] = kv;
    vgt[((size_t)bh * 64 + d) * 64 + g] = vv;
  }
}

__global__ __launch_bounds__(256)
void gather_xg_kernel(const u16* __restrict__ xb, const int* __restrict__ gpos,
                      u16* __restrict__ xg) {
  int rg = blockIdx.x;  // b*G+g
  int b = rg / Gg;
  int p = gpos[rg];
  int tid = threadIdx.x;
  for (int c = tid; c < Dd; c += 256)
    xg[(size_t)rg * Dd + c] = xb[((size_t)b * Ss + p) * Dd + c];
}

// ---------------- local (sliding window + global-key) attention -------------
#define LOCAL_NB (Bb * Hh * (Ss / 64))   // 1536 blocks, %8 == 0
__global__ __launch_bounds__(256)
void attn_local_kernel(const u16* __restrict__ qpk, const u16* __restrict__ kpk,
                       const u16* __restrict__ vtpk, const u16* __restrict__ kg,
                       const u16* __restrict__ vgt, const int* __restrict__ amask,
                       u16* __restrict__ ctx) {
  __shared__ u16 Plds[4][16 * PSTR];
  int bid = blockIdx.x;
  int swz = (bid & 7) * (LOCAL_NB / 8) + (bid >> 3);
  int qb = swz & 63;
  int bh = swz >> 6;
  int b = bh / Hh;
  int h = bh - b * Hh;
  int wv = threadIdx.x >> 6;
  int q0 = qb * 64 + wv * 16;
  int lane = threadIdx.x & 63;
  int lg = lane >> 4, lc = lane & 15;
  int lg4 = lg * 4;
  int q = q0 + lc;   // query owned by this lane for softmax state

  const u16* qbase = qpk + (((size_t)bh) * Ss + q0) * 64;
  bv8 aq0 = *reinterpret_cast<const bv8*>(qbase + (size_t)lc * 64 + lg * 8);
  bv8 aq1 = *reinterpret_cast<const bv8*>(qbase + (size_t)lc * 64 + 32 + lg * 8);

  f32x4 o[4];
  #pragma unroll
  for (int i = 0; i < 4; ++i) o[i] = (f32x4){0.f, 0.f, 0.f, 0.f};
  float mrun = -1e30f, lrun = 0.f;

  const u16* kgb = kg + ((size_t)bh) * 64 * 64;
  const u16* vgb = vgt + ((size_t)bh) * 64 * 64;
  const u16* kb = kpk + ((size_t)bh) * SPAD * 64;
  const u16* vb = vtpk + ((size_t)bh) * 64 * SPAD;
  const int* amb = amask + b * Ss;
  u16* P = &Plds[wv][0];

  // preload K frags for step 0 (global keys)
  bv8 kc[8];
  #pragma unroll
  for (int j = 0; j < 4; ++j) {
    const u16* kr = kgb + (size_t)(j * 16 + lc) * 64;
    kc[2 * j]     = *reinterpret_cast<const bv8*>(kr + lg * 8);
    kc[2 * j + 1] = *reinterpret_cast<const bv8*>(kr + 32 + lg * 8);
  }
  // prefetch amask word for step 1
  int amvN;
  { int ni = min(max(q0 - 256 + lane, 0), Ss - 1); amvN = amb[ni]; }

  for (int step = 0; step < 10; ++step) {
    bool isg = (step == 0);
    int ks = isg ? 0 : (q0 - 256 + (step - 1) * 64);
    int amvC = amvN;
    if (step < 9) { int ni = min(max(q0 - 256 + step * 64 + lane, 0), Ss - 1); amvN = amb[ni]; }

    // issue V loads for this step (consumed after softmax)
    bv8 vf[8];
    #pragma unroll
    for (int j2 = 0; j2 < 2; ++j2)
      #pragma unroll
      for (int nt = 0; nt < 4; ++nt) {
        const u16* vr = isg ? (vgb + (size_t)(nt * 16 + lc) * 64 + j2 * 32)
                            : (vb + (size_t)(nt * 16 + lc) * SPAD + PADL + ks + j2 * 32);
        vf[j2 * 4 + nt] = *reinterpret_cast<const bv8*>(vr + lg * 8);
      }
    // key-validity mask
    unsigned long long kmask;
    if (isg) {
      kmask = (1ull << Gg) - 1;
    } else {
      int kidx = ks + lane;
      kmask = __ballot((kidx >= 0) && (kidx < Ss) && (amvC > 0));
    }
    // QK^T (swapped operands): sc[j] = scores for keys ks+j*16+lg4..+3, query lc
    f32x4 sc[4];
    __builtin_amdgcn_s_setprio(1);
    #pragma unroll
    for (int j = 0; j < 4; ++j) {
      f32x4 z = (f32x4){0.f, 0.f, 0.f, 0.f};
      sc[j] = __builtin_amdgcn_mfma_f32_16x16x32_bf16(kc[2 * j], aq0, z, 0, 0, 0);
      sc[j] = __builtin_amdgcn_mfma_f32_16x16x32_bf16(kc[2 * j + 1], aq1, sc[j], 0, 0, 0);
    }
    __builtin_amdgcn_s_setprio(0);
    // reload kc IN PLACE for next step (WAR on QK^T; hides under softmax+PV)
    if (step < 9) {
      int ksn = q0 - 256 + step * 64;
      #pragma unroll
      for (int j = 0; j < 4; ++j) {
        const u16* kr = kb + (size_t)(PADL + ksn + j * 16 + lc) * 64;
        kc[2 * j]     = *reinterpret_cast<const bv8*>(kr + lg * 8);
        kc[2 * j + 1] = *reinterpret_cast<const bv8*>(kr + 32 + lg * 8);
      }
    }
    // masking: steps 2..8 with full kmask are band-safe for all 16 queries
    float mloc = -1e30f;
    bool fast = (!isg) && (step >= 2) && (step <= 8) && (kmask == ~0ull);
    if (fast) {
      #pragma unroll
      for (int j = 0; j < 4; ++j)
        #pragma unroll
        for (int r = 0; r < 4; ++r) mloc = fmaxf(mloc, sc[j][r]);
    } else {
      #pragma unroll
      for (int j = 0; j < 4; ++j)
        #pragma unroll
        for (int r = 0; r < 4; ++r) {
          int kk = ks + j * 16 + lg4 + r;
          bool ok = (kmask >> (j * 16 + lg4 + r)) & 1;
          if (!isg) ok = ok && ((unsigned)(kk - q + 256) <= 512u);
          sc[j][r] = ok ? sc[j][r] : -1e9f;
          mloc = fmaxf(mloc, sc[j][r]);
        }
    }
    mloc = fmaxf(mloc, __shfl_xor(mloc, 16));
    mloc = fmaxf(mloc, __shfl_xor(mloc, 32));
    if (__any(mloc > mrun)) {
      float nm = fmaxf(mrun, mloc);
      float scal = __expf(mrun - nm);
      mrun = nm;
      lrun *= scal;
      #pragma unroll
      for (int r = 0; r < 4; ++r) {
        float sr = __shfl(scal, lg4 + r);  // scal of query lg4+r
        #pragma unroll
        for (int nt = 0; nt < 4; ++nt) o[nt][r] *= sr;
      }
    }
    float psum = 0.f;
    #pragma unroll
    for (int j = 0; j < 4; ++j) {
      sv4 pk;
      #pragma unroll
      for (int r = 0; r < 4; ++r) {
        float p = __expf(sc[j][r] - mrun);
        psum += p;
        pk[r] = (short)f2bf(p);
      }
      *reinterpret_cast<sv4*>(P + lc * PSTR + j * 16 + lg4) = pk;
    }
    psum += __shfl_xor(psum, 16);
    psum += __shfl_xor(psum, 32);
    lrun += psum;
    // PV with prefetched V frags
    __builtin_amdgcn_s_setprio(1);
    #pragma unroll
    for (int j2 = 0; j2 < 2; ++j2) {
      bv8 ap = *reinterpret_cast<const bv8*>(P + lc * PSTR + j2 * 32 + lg * 8);
      #pragma unroll
      for (int nt = 0; nt < 4; ++nt)
        o[nt] = __builtin_amdgcn_mfma_f32_16x16x32_bf16(ap, vf[j2 * 4 + nt], o[nt], 0, 0, 0);
    }
    __builtin_amdgcn_s_setprio(0);
  }
  float inv = 1.0f / lrun;
  #pragma unroll
  for (int r = 0; r < 4; ++r) {
    float invr = __shfl(inv, lg4 + r);
    size_t rowoff = ((size_t)b * Ss + q0 + lg4 + r) * Dd + h * 64;
    #pragma unroll
    for (int nt = 0; nt < 4; ++nt)
      ctx[rowoff + nt * 16 + lc] = f2bf(o[nt][r] * invr);
  }
}

// ---------------- global-query attention: chunked flash MFMA ----------------
__global__ __launch_bounds__(192)
void attn_globalq_kernel(const u16* __restrict__ qgb, const u16* __restrict__ kgf,
                         const u16* __restrict__ vgt, const int* __restrict__ amask,
                         float* __restrict__ part) {
  __shared__ u16 Plds[3][16 * 32];
  int blk = blockIdx.x;
  int ch = blk & (NCH - 1);
  int bh = blk / NCH;
  int b = bh / Hh, h = bh - b * Hh;
  int wv = threadIdx.x >> 6;  // q-tile 0..2
  int lane = threadIdx.x & 63;
  int lg = lane >> 4, lc = lane & 15;

  int qrow = wv * 16 + lc;
  bv8 aq0 = (bv8)0, aq1 = (bv8)0;
  if (qrow < Gg) {
    const u16* qr = qgb + (size_t)(b * Gg + qrow) * Dd + h * 64;
    aq0 = *reinterpret_cast<const bv8*>(qr + lg * 8);
    aq1 = *reinterpret_cast<const bv8*>(qr + 32 + lg * 8);
  }

  f32x4 o[4];
  float mrun[4], lrun[4];
  #pragma unroll
  for (int i = 0; i < 4; ++i) { o[i] = (f32x4){0.f,0.f,0.f,0.f}; mrun[i] = -1e30f; lrun[i] = 0.f; }

  const u16* kb = kgf + ((size_t)bh) * Ss * 64;
  const u16* vb = vgt + ((size_t)bh) * 64 * Ss;
  const int* amb = amask + b * Ss;
  int ks0 = ch * (Ss / NCH);

  for (int st = 0; st < (Ss / NCH) / 32; ++st) {
    int ks = ks0 + st * 32;
    f32x4 sc0, sc1;
    {
      const u16* kr0 = kb + (size_t)(ks + lc) * 64;
      const u16* kr1 = kr0 + 16 * 64;
      bv8 b00 = *reinterpret_cast<const bv8*>(kr0 + lg * 8);
      bv8 b01 = *reinterpret_cast<const bv8*>(kr0 + 32 + lg * 8);
      bv8 b10 = *reinterpret_cast<const bv8*>(kr1 + lg * 8);
      bv8 b11 = *reinterpret_cast<const bv8*>(kr1 + 32 + lg * 8);
      f32x4 z = (f32x4){0.f,0.f,0.f,0.f};
      sc0 = __builtin_amdgcn_mfma_f32_16x16x32_bf16(aq0, b00, z, 0, 0, 0);
      sc0 = __builtin_amdgcn_mfma_f32_16x16x32_bf16(aq1, b01, sc0, 0, 0, 0);
      sc1 = __builtin_amdgcn_mfma_f32_16x16x32_bf16(aq0, b10, z, 0, 0, 0);
      sc1 = __builtin_amdgcn_mfma_f32_16x16x32_bf16(aq1, b11, sc1, 0, 0, 0);
    }
    bool v0 = amb[ks + lc] > 0;
    bool v1 = amb[ks + 16 + lc] > 0;
    #pragma unroll
    for (int r = 0; r < 4; ++r) {
      float s0 = v0 ? sc0[r] : -1e9f;
      float s1 = v1 ? sc1[r] : -1e9f;
      float rm = fmaxf(s0, s1);
      #pragma unroll
      for (int off = 1; off < 16; off <<= 1) rm = fmaxf(rm, __shfl_xor(rm, off));
      float nm = fmaxf(mrun[r], rm);
      float scal = __expf(mrun[r] - nm);
      float p0 = __expf(s0 - nm);
      float p1 = __expf(s1 - nm);
      float ps = p0 + p1;
      #pragma unroll
      for (int off = 1; off < 16; off <<= 1) ps += __shfl_xor(ps, off);
      lrun[r] = lrun[r] * scal + ps;
      mrun[r] = nm;
      #pragma unroll
      for (int nt = 0; nt < 4; ++nt) o[nt][r] *= scal;
      int prow = lg * 4 + r;
      Plds[wv][prow * 32 + lc] = f2bf(p0);
      Plds[wv][prow * 32 + 16 + lc] = f2bf(p1);
    }
    bv8 ap = *reinterpret_cast<const bv8*>(&Plds[wv][lc * 32 + lg * 8]);
    #pragma unroll
    for (int nt = 0; nt < 4; ++nt) {
      const u16* vr = vb + (size_t)(nt * 16 + lc) * Ss + ks;
      bv8 bvv = *reinterpret_cast<const bv8*>(vr + lg * 8);
      o[nt] = __builtin_amdgcn_mfma_f32_16x16x32_bf16(ap, bvv, o[nt], 0, 0, 0);
    }
  }

  float* pb = part + ((size_t)(bh * 3 + wv) * NCH + ch) * PARTF;
  #pragma unroll
  for (int r = 0; r < 4; ++r) {
    int row = lg * 4 + r;
    #pragma unroll
    for (int nt = 0; nt < 4; ++nt)
      pb[row * 64 + nt * 16 + lc] = o[nt][r];
    if (lc == 0) {
      pb[1024 + row] = mrun[r];
      pb[1040 + row] = lrun[r];
    }
  }
}

// merge NCH chunk-partials and scatter into ctx rows at gpos
__global__ __launch_bounds__(256)
void attn_gmerge_kernel(const float* __restrict__ part, const int* __restrict__ gpos,
                        u16* __restrict__ ctx) {
  __shared__ float wgt[Gg][NCH];
  __shared__ float sinvl[Gg];
  int bh = blockIdx.x;
  int b = bh / Hh, h = bh - b * Hh;
  int tid = threadIdx.x;
  if (tid < Gg) {
    int qt = tid >> 4, rr = tid & 15;
    const float* pb = part + ((size_t)(bh * 3 + qt) * NCH) * PARTF;
    float mx = -1e30f;
    for (int c = 0; c < NCH; ++c) mx = fmaxf(mx, pb[c * PARTF + 1024 + rr]);
    float l = 0.f;
    for (int c = 0; c < NCH; ++c) {
      float w = __expf(pb[c * PARTF + 1024 + rr] - mx);
      wgt[tid][c] = w;
      l += w * pb[c * PARTF + 1040 + rr];
    }
    sinvl[tid] = 1.0f / l;
  }
  __syncthreads();
  for (int e = tid; e < Gg * 64; e += 256) {
    int row = e >> 6, d = e & 63;
    int qt = row >> 4, rr = row & 15;
    const float* pb = part + ((size_t)(bh * 3 + qt) * NCH) * PARTF + rr * 64 + d;
    float acc = 0.f;
    #pragma unroll
    for (int c = 0; c < NCH; ++c) acc += wgt[row][c] * pb[c * PARTF];
    int pos = gpos[b * Gg + row];
    ctx[((size_t)b * Ss + pos) * Dd + h * 64 + d] = f2bf(acc * sinvl[row]);
  }
}

// ---------------- classifier ------------------------------------------------
__global__ __launch_bounds__(64)
void cls_kernel(const float* __restrict__ x, const float* __restrict__ W,
                const float* __restrict__ bias, const int* __restrict__ gpos,
                float* __restrict__ out) {
  int r = blockIdx.x;  // b*32 + i
  int b = r >> 5, i = r & 31;
  int pos = gpos[b * Gg + 1 + i];
  int lane = threadIdx.x;
  const float* xr = x + ((size_t)b * Ss + pos) * Dd;
  float acc[NCLSn] = {0.f, 0.f, 0.f, 0.f, 0.f};
  for (int k = lane; k < Dd; k += 64) {
    float xv = xr[k];
    #pragma unroll
    for (int c = 0; c < NCLSn; ++c) acc[c] += xv * W[c * Dd + k];
  }
  #pragma unroll
  for (int c = 0; c < NCLSn; ++c) {
    #pragma unroll
    for (int off = 1; off < 64; off <<= 1) acc[c] += __shfl_xor(acc[c], off);
  }
  if (lane == 0) {
    #pragma unroll
    for (int c = 0; c < NCLSn; ++c) out[r * NCLSn + c] = acc[c] + bias[c];
  }
}

// ---------------------------------------------------------------------------
extern "C" void kernel_launch(void* const* d_in, const int* in_sizes, int n_in,
                              void* d_out, int out_size, void* d_ws, size_t ws_size,
                              hipStream_t stream) {
  const int* ids     = (const int*)d_in[0];
  const int* amask   = (const int*)d_in[1];
  const float* we    = (const float*)d_in[2];
  const float* pe    = (const float*)d_in[3];
  const float* te    = (const float*)d_in[4];
  const float* embln = (const float*)d_in[5];
  const float* Wqkv  = (const float*)d_in[6];
  const float* bqkv  = (const float*)d_in[7];
  const float* Wqkvg = (const float*)d_in[8];
  const float* bqkvg = (const float*)d_in[9];
  const float* Wo    = (const float*)d_in[10];
  const float* bo    = (const float*)d_in[11];
  const float* ln1   = (const float*)d_in[12];
  const float* Wff1  = (const float*)d_in[13];
  const float* bff1  = (const float*)d_in[14];
  const float* Wff2  = (const float*)d_in[15];
  const float* bff2  = (const float*)d_in[16];
  const float* ln2   = (const float*)d_in[17];
  const float* clsW  = (const float*)d_in[18];
  const float* clsb  = (const float*)d_in[19];
  float* out = (float*)d_out;

  char* ws = (char*)d_ws;
  size_t off = 0;
  auto alloc = [&](size_t bytes) { size_t o = off; off += (bytes + 255) & ~(size_t)255; return o; };

  const size_t DD = (size_t)Dd * Dd;        // 589824
  const size_t DF = (size_t)Dd * 4 * Dd;    // 2359296
  const size_t WL = 7 * DD + 2 * DF;        // elems per layer
  // Wb layout per layer: [q,k,v, gk,gv, gq, wo, ff1, ff2]

  size_t o_cnt  = alloc(Bb * 4);
  size_t o_list = alloc(Bb * 64 * 4);
  size_t o_gpos = alloc(Bb * Gg * 4);
  size_t o_bias = alloc((size_t)Ll * 3840 * 4);
  size_t o_w    = alloc(WL * Ll * 2);
  size_t o_x    = alloc((size_t)Bb * Ss * Dd * 4);
  size_t o_xb   = alloc((size_t)Bb * Ss * Dd * 2);
  // kgf/vgf first: their 25.17 MB doubles as split-K buffer B (dead by Wo/FF2)
  size_t o_kgf  = alloc((size_t)Bb * Hh * Ss * 64 * 2);
  size_t o_vgf  = alloc((size_t)Bb * Hh * Ss * 64 * 2);
  size_t o_accB = o_kgf;  // 2*12.58 MB = exactly 8192*768*4 bytes
  size_t o_qpk  = alloc((size_t)Bb * Hh * Ss * 64 * 2);
  size_t o_kpk  = alloc((size_t)Bb * Hh * SPAD * 64 * 2);
  size_t o_vtpk = alloc((size_t)Bb * Hh * 64 * SPAD * 2);
  size_t o_kg   = alloc((size_t)Bb * Hh * 64 * 64 * 2);
  size_t o_vgt  = alloc((size_t)Bb * Hh * 64 * 64 * 2);
  size_t o_xg   = alloc((size_t)128 * Dd * 2);
  size_t o_qg   = alloc((size_t)128 * Dd * 2);
  size_t o_part = alloc((size_t)Bb * Hh * 3 * NCH * PARTF * 4);
  size_t o_f1b  = o_qpk;  // FFN hidden aliases the (dead-by-then) attention buffers
  {
    size_t f1b_bytes = (size_t)Bb * Ss * 4 * Dd * 2;
    if (off - o_qpk < f1b_bytes) off = o_qpk + ((f1b_bytes + 255) & ~(size_t)255);
  }
  size_t o_ctx = alloc((size_t)Bb * Ss * Dd * 2);
  size_t o_acc = alloc((size_t)Bb * Ss * Dd * 4);
  if (ws_size < off) return;  // workspace too small -> fail visibly

  u16* Wb = (u16*)(ws + o_w);
  int* gposp = (int*)(ws + o_gpos);
  float* accA = (float*)(ws + o_acc);
  float* accB = (float*)(ws + o_accB);

  (void)hipMemsetAsync(ws + o_cnt, 0, Bb * 4, stream);
  // zero padded K / V^T so first-call pads are finite (later calls: finite stale bf16)
  (void)hipMemsetAsync(ws + o_kpk, 0, (size_t)Bb * Hh * SPAD * 64 * 2, stream);
  (void)hipMemsetAsync(ws + o_vtpk, 0, (size_t)Bb * Hh * 64 * SPAD * 2, stream);
  (void)hipMemsetAsync(ws + o_xg, 0, (size_t)128 * Dd * 2, stream);

  // concat bias per layer: [bqkv(3x768) | bqkvg_k(768) | bqkvg_v(768)]
  for (int l = 0; l < Ll; ++l) {
    (void)hipMemcpyAsync(ws + o_bias + (size_t)l * 3840 * 4, bqkv + (size_t)l * 3 * Dd,
                         3 * Dd * 4, hipMemcpyDeviceToDevice, stream);
    (void)hipMemcpyAsync(ws + o_bias + (size_t)l * 3840 * 4 + 3 * Dd * 4,
                         bqkvg + (size_t)(l * 3 + 1) * Dd,
                         2 * Dd * 4, hipMemcpyDeviceToDevice, stream);
  }

  sep_find_kernel<<<(Bb * Ss + 255) / 256, 256, 0, stream>>>(ids, (int*)(ws + o_cnt), (int*)(ws + o_list));
  sep_sort_kernel<<<Bb, 64, 0, stream>>>((int*)(ws + o_cnt), (int*)(ws + o_list), gposp);

  // weight conversions (batched over z); Wb layout [q,k,v,gk,gv,gq,wo,ff1,ff2]
  wconv_kernel<<<dim3(24, 24, 6), 256, 0, stream>>>(Wqkv,       Wb,          Dd, Dd, 3, 3, (long)DD, (long)WL);
  wconv_kernel<<<dim3(24, 24, 2), 256, 0, stream>>>(Wqkvg + DD,     Wb + 3 * DD, Dd, Dd, 1, 3, 0L, (long)WL);  // gk
  wconv_kernel<<<dim3(24, 24, 2), 256, 0, stream>>>(Wqkvg + 2 * DD, Wb + 4 * DD, Dd, Dd, 1, 3, 0L, (long)WL);  // gv
  wconv_kernel<<<dim3(24, 24, 2), 256, 0, stream>>>(Wqkvg,          Wb + 5 * DD, Dd, Dd, 1, 3, 0L, (long)WL);  // gq
  wconv_kernel<<<dim3(24, 24, 2), 256, 0, stream>>>(Wo,         Wb + 6 * DD, Dd, Dd, 1, 1, 0L, (long)WL);
  wconv_kernel<<<dim3(96, 24, 2), 256, 0, stream>>>(Wff1,       Wb + 7 * DD, Dd, 4 * Dd, 1, 1, 0L, (long)WL);
  wconv_kernel<<<dim3(24, 96, 2), 256, 0, stream>>>(Wff2,       Wb + 7 * DD + DF, 4 * Dd, Dd, 1, 1, 0L, (long)WL);

  embed_ln_kernel<<<Bb * Ss, 256, 0, stream>>>(ids, we, pe, te, embln, (float*)(ws + o_x), (u16*)(ws + o_xb));

  for (int l = 0; l < Ll; ++l) {
    size_t wb = (size_t)l * WL;
    u16* xb = (u16*)(ws + o_xb);
    // fused QKV + global K/V projection (N=3840, 5 sections); grid 1920 %8==0
    gemm2_kernel<2, true><<<dim3(30, 64), 256, 0, stream>>>(xb, Wb + wb, (float*)(ws + o_bias) + (size_t)l * 3840,
        nullptr, nullptr,
        (u16*)(ws + o_qpk), (u16*)(ws + o_kpk), (u16*)(ws + o_vtpk),
        (u16*)(ws + o_kgf), (u16*)(ws + o_vgf), 3840, Dd, Dd, 0.125f);
    gather_glob_kernel<<<Bb * Hh, 256, 0, stream>>>((u16*)(ws + o_kpk), (u16*)(ws + o_vtpk), gposp, (u16*)(ws + o_kg), (u16*)(ws + o_vgt));
    gather_xg_kernel<<<Bb * Gg, 256, 0, stream>>>(xb, gposp, (u16*)(ws + o_xg));
    // global q projection (M=128 padded rows); 6 blocks -> no XCD swizzle
    gemm2_kernel<4, false><<<dim3(6, 1), 256, 0, stream>>>((u16*)(ws + o_xg), Wb + wb + 5 * DD, bqkvg + (size_t)l * 3 * Dd,
        nullptr, nullptr, (u16*)(ws + o_qg), nullptr, nullptr, nullptr, nullptr, Dd, Dd, Dd, 0.125f);
    // attention
    attn_local_kernel<<<LOCAL_NB, 256, 0, stream>>>((u16*)(ws + o_qpk), (u16*)(ws + o_kpk), (u16*)(ws + o_vtpk), (u16*)(ws + o_kg), (u16*)(ws + o_vgt), amask, (u16*)(ws + o_ctx));
    attn_globalq_kernel<<<Bb * Hh * NCH, 192, 0, stream>>>((u16*)(ws + o_qg), (u16*)(ws + o_kgf), (u16*)(ws + o_vgf), amask, (float*)(ws + o_part));
    attn_gmerge_kernel<<<Bb * Hh, 256, 0, stream>>>((float*)(ws + o_part), gposp, (u16*)(ws + o_ctx));
    // output projection (split-K x2) + LN   [kgf/vgf dead from here on]
    gemm2_kernel<0, true><<<dim3(6, 64, 2), 256, 0, stream>>>((u16*)(ws + o_ctx), Wb + wb + 6 * DD, bo + (size_t)l * Dd, accA, accB,
        nullptr, nullptr, nullptr, nullptr, nullptr, Dd, Dd, Dd / 2, 1.0f);
    add_ln3_kernel<<<Bb * Ss, 256, 0, stream>>>((float*)(ws + o_x), accA, accB, ln1 + (size_t)l * 2 * Dd, (float*)(ws + o_x), xb);
    // FFN
    gemm2_kernel<1, true><<<dim3(24, 64), 256, 0, stream>>>(xb, Wb + wb + 7 * DD, bff1 + (size_t)l * 4 * Dd, nullptr, nullptr,
        (u16*)(ws + o_f1b), nullptr, nullptr, nullptr, nullptr, 4 * Dd, Dd, Dd, 1.0f);
    gemm2_kernel<0, true><<<dim3(6, 64, 2), 256, 0, stream>>>((u16*)(ws + o_f1b), Wb + wb + 7 * DD + DF, bff2 + (size_t)l * Dd, accA, accB,
        nullptr, nullptr, nullptr, nullptr, nullptr, Dd, 4 * Dd, 2 * Dd, 1.0f);
    add_ln3_kernel<<<Bb * Ss, 256, 0, stream>>>((float*)(ws + o_x), accA, accB, ln2 + (size_t)l * 2 * Dd, (float*)(ws + o_x), xb);
  }

  cls_kernel<<<Bb * NSEPn, 64, 0, stream>>>((float*)(ws + o_x), clsW, clsb, gposp, out);
}

// Round 11
// 840.445 us; speedup vs baseline: 1.1098x; 1.0144x over previous
//
#include <hip/hip_runtime.h>

// ---------------------------------------------------------------------------
// Longformer (2-layer) forward, MI355X.
// R10: (a) attn_globalq ported to lane-local swapped-QK^T softmax (64-key
//      steps, ballot mask, fast path); (b) attn_local V-liveness split;
//      (c) split-K half-B written/read as bf16 (saves ~100 MB traffic).
// ---------------------------------------------------------------------------

#define Bb 2
#define Ss 4096
#define Dd 768
#define Hh 12
#define Gg 33
#define NSEPn 32
#define Ll 2
#define SPAD 4640   // S + 544 (PADL=256 left, 288 right)
#define PADL 256
#define NCLSn 5
#define NCH 16      // key chunks for global-q attention (256 keys each)
#define PARTF 1056  // floats per (bh,qt,chunk) partial: 16*64 o + 16 m + 16 l
#define PSTR 72     // Plds row stride in u16 (144B: 16B-aligned, bank-spread)

typedef unsigned short u16;
typedef __attribute__((ext_vector_type(8))) short bv8;   // 8 x bf16
typedef __attribute__((ext_vector_type(4))) short sv4;   // 4 x bf16
typedef __attribute__((ext_vector_type(4))) float f32x4;

__device__ __forceinline__ float bf2f(u16 u) {
  unsigned v = ((unsigned)u) << 16;
  return __builtin_bit_cast(float, v);
}
__device__ __forceinline__ u16 f2bf(float f) {
  unsigned u = __builtin_bit_cast(unsigned, f);
  u += 0x7fffu + ((u >> 16) & 1u);
  return (u16)(u >> 16);
}
__device__ __forceinline__ void glds16(const void* g, void* l) {
  __builtin_amdgcn_global_load_lds(
      (const __attribute__((address_space(1))) void*)g,
      (__attribute__((address_space(3))) void*)l, 16, 0, 0);
}

// ---------------- sep finding --------------------------------------------
__global__ void sep_find_kernel(const int* __restrict__ ids, int* __restrict__ cnt,
                                int* __restrict__ list) {
  int i = blockIdx.x * 256 + threadIdx.x;
  if (i >= Bb * Ss) return;
  int b = i >> 12;
  if (ids[i] == 2) {
    int idx = atomicAdd(&cnt[b], 1);
    if (idx < 64) list[b * 64 + idx] = i & (Ss - 1);
  }
}

__global__ void sep_sort_kernel(const int* __restrict__ cnt, const int* __restrict__ list,
                                int* __restrict__ gpos) {
  int b = blockIdx.x;
  int t = threadIdx.x;
  int n = cnt[b]; if (n > 64) n = 64;
  if (t < Gg) gpos[b * Gg + t] = (t == 0) ? 0 : (Ss - 1);
  __syncthreads();
  if (t < n) {
    int v = list[b * 64 + t];
    int rank = 0;
    for (int j = 0; j < n; ++j) rank += (list[b * 64 + j] < v) ? 1 : 0;
    if (rank < NSEPn) gpos[b * Gg + 1 + rank] = v;
  }
}

// ------- weight fp32 (K,N) -> bf16 (N,K), batched; src slice (z/grp)*sstr+z%grp
__global__ __launch_bounds__(256)
void wconv_kernel(const float* __restrict__ src0, u16* __restrict__ dst0,
                  int K, int N, int grp, int sstr, long unit, long WLs) {
  __shared__ float t[32][33];
  int z = blockIdx.z;
  const float* src = src0 + (size_t)((z / grp) * sstr + (z % grp)) * K * N;
  u16* dst = dst0 + (size_t)(z / grp) * WLs + (size_t)(z % grp) * unit;
  int n0 = blockIdx.x * 32, k0 = blockIdx.y * 32;
  int tx = threadIdx.x & 31, ty = threadIdx.x >> 5;  // ty 0..7
  #pragma unroll
  for (int i = 0; i < 4; ++i)
    t[ty + i * 8][tx] = src[(size_t)(k0 + ty + i * 8) * N + n0 + tx];
  __syncthreads();
  #pragma unroll
  for (int i = 0; i < 4; ++i)
    dst[(size_t)(n0 + ty + i * 8) * K + k0 + tx] = f2bf(t[tx][ty + i * 8]);
}

// ---------------- embedding + LN -------------------------------------------
__global__ __launch_bounds__(256)
void embed_ln_kernel(const int* __restrict__ ids, const float* __restrict__ we,
                     const float* __restrict__ pe, const float* __restrict__ te,
                     const float* __restrict__ lnp, float* __restrict__ x,
                     u16* __restrict__ xb) {
  int row = blockIdx.x;
  int s = row & (Ss - 1);
  int id = ids[row];
  int tid = threadIdx.x;
  float v[3]; float sm = 0.f, s2 = 0.f;
  #pragma unroll
  for (int i = 0; i < 3; ++i) {
    int c = tid + i * 256;
    float t = we[(size_t)id * Dd + c] + pe[(size_t)(s + 2) * Dd + c] + te[c];
    v[i] = t; sm += t; s2 += t * t;
  }
  __shared__ float r1[256], r2[256];
  r1[tid] = sm; r2[tid] = s2; __syncthreads();
  for (int o = 128; o; o >>= 1) {
    if (tid < o) { r1[tid] += r1[tid + o]; r2[tid] += r2[tid + o]; }
    __syncthreads();
  }
  float mean = r1[0] * (1.f / 768.f);
  float var  = r2[0] * (1.f / 768.f) - mean * mean;
  float rs = rsqrtf(var + 1e-5f);
  #pragma unroll
  for (int i = 0; i < 3; ++i) {
    int c = tid + i * 256;
    float o = (v[i] - mean) * rs * lnp[c] + lnp[Dd + c];
    x[(size_t)row * Dd + c] = o;
    xb[(size_t)row * Dd + c] = f2bf(o);
  }
}

// ---------------- residual(2 fp32 + 1 bf16) + LN ----------------------------
__global__ __launch_bounds__(256)
void add_ln3_kernel(const float* __restrict__ xin, const float* __restrict__ y0,
                    const u16* __restrict__ y1, const float* __restrict__ lnp,
                    float* __restrict__ xout, u16* __restrict__ xbout) {
  int row = blockIdx.x;
  int tid = threadIdx.x;
  float v[3]; float sm = 0.f, s2 = 0.f;
  #pragma unroll
  for (int i = 0; i < 3; ++i) {
    int c = tid + i * 256;
    size_t idx = (size_t)row * Dd + c;
    float t = xin[idx] + y0[idx] + bf2f(y1[idx]);
    v[i] = t; sm += t; s2 += t * t;
  }
  __shared__ float r1[256], r2[256];
  r1[tid] = sm; r2[tid] = s2; __syncthreads();
  for (int o = 128; o; o >>= 1) {
    if (tid < o) { r1[tid] += r1[tid + o]; r2[tid] += r2[tid + o]; }
    __syncthreads();
  }
  float mean = r1[0] * (1.f / 768.f);
  float var  = r2[0] * (1.f / 768.f) - mean * mean;
  float rs = rsqrtf(var + 1e-5f);
  #pragma unroll
  for (int i = 0; i < 3; ++i) {
    int c = tid + i * 256;
    float o = (v[i] - mean) * rs * lnp[c] + lnp[Dd + c];
    xout[(size_t)row * Dd + c] = o;
    xbout[(size_t)row * Dd + c] = f2bf(o);
  }
}

// ---------------- GEMM2: 128x128 2-buffer + T2 LDS swizzle + T1 XCD swizzle -
// MODE 0: split-K: z==0 -> fp32 outf (+bias); z==1 -> bf16 o0 (no bias)
// MODE 1: bf16 [M][N], exact gelu
// MODE 2: fused QKV+gKV: N=3840; secs: q pk / k pad / v^T pad / gk pk / gv^T
// MODE 4: bf16 [M][N] * scale
template <int MODE, bool XSWZ>
__global__ __launch_bounds__(256)
void gemm2_kernel(const u16* __restrict__ A, const u16* __restrict__ Bt,
                  const float* __restrict__ bias, float* __restrict__ outf,
                  u16* __restrict__ o0, u16* __restrict__ o1, u16* __restrict__ o2,
                  u16* __restrict__ o3, u16* __restrict__ o4,
                  int N, int Ks, int Kl, float scale) {
  __shared__ u16 la[2][128 * 32], lb[2][128 * 32];
  int tid = threadIdx.x;
  int wave = tid >> 6, lane = tid & 63;
  int wr = wave >> 1, wc = wave & 1;
  int lg = lane >> 4, lc = lane & 15;
  // T1: XCD-aware bijective remap of the x-y plane (requires NB % 8 == 0)
  int bx = blockIdx.x, by = blockIdx.y;
  if (XSWZ) {
    int gx = gridDim.x;
    int nlin = bx + gx * by;
    int NB = gx * gridDim.y;
    nlin = (nlin & 7) * (NB >> 3) + (nlin >> 3);
    bx = nlin % gx;
    by = nlin / gx;
  }
  int row0 = by * 128, col0 = bx * 128;
  int koff = blockIdx.z * Kl;

  // T2 swizzle: linear LDS dest; lane fetches logical granule (l&3)^((l>>3)&3)
  int sgr = (lane & 3) ^ ((lane >> 3) & 3);
  const u16* Ag = A + (size_t)(row0 + wave * 32 + (lane >> 2)) * Ks + sgr * 8 + koff;
  const u16* Bg = Bt + (size_t)(col0 + wave * 32 + (lane >> 2)) * Ks + sgr * 8 + koff;
  int wofs = wave * 1024;
  int gph = (lg ^ ((lc >> 1) & 3)) * 8;   // swizzled read granule offset (u16)

  f32x4 acc[4][4];
  #pragma unroll
  for (int m = 0; m < 4; ++m)
    #pragma unroll
    for (int n = 0; n < 4; ++n) acc[m][n] = (f32x4){0.f, 0.f, 0.f, 0.f};

  glds16(Ag, la[0] + wofs);
  glds16(Ag + (size_t)16 * Ks, la[0] + wofs + 512);
  glds16(Bg, lb[0] + wofs);
  glds16(Bg + (size_t)16 * Ks, lb[0] + wofs + 512);
  __syncthreads();

  int nk = Kl >> 5;
  for (int t = 0; t < nk; ++t) {
    int cur = t & 1;
    if (t + 1 < nk) {
      int k1 = (t + 1) << 5;
      glds16(Ag + k1, la[cur ^ 1] + wofs);
      glds16(Ag + (size_t)16 * Ks + k1, la[cur ^ 1] + wofs + 512);
      glds16(Bg + k1, lb[cur ^ 1] + wofs);
      glds16(Bg + (size_t)16 * Ks + k1, lb[cur ^ 1] + wofs + 512);
    }
    bv8 af[4], bf_[4];
    #pragma unroll
    for (int m = 0; m < 4; ++m)
      af[m] = *reinterpret_cast<const bv8*>(la[cur] + (wr * 64 + m * 16 + lc) * 32 + gph);
    #pragma unroll
    for (int n = 0; n < 4; ++n)
      bf_[n] = *reinterpret_cast<const bv8*>(lb[cur] + (wc * 64 + n * 16 + lc) * 32 + gph);
    __builtin_amdgcn_s_setprio(1);
    #pragma unroll
    for (int m = 0; m < 4; ++m)
      #pragma unroll
      for (int n = 0; n < 4; ++n)
        acc[m][n] = __builtin_amdgcn_mfma_f32_16x16x32_bf16(af[m], bf_[n], acc[m][n], 0, 0, 0);
    __builtin_amdgcn_s_setprio(0);
    __syncthreads();
  }

  #pragma unroll
  for (int m = 0; m < 4; ++m) {
    int grow0 = row0 + wr * 64 + m * 16 + lg * 4;
    #pragma unroll
    for (int n = 0; n < 4; ++n) {
      int gcol = col0 + wc * 64 + n * 16 + lc;
      float bvl = bias[gcol];
      if (MODE == 0) {
        if (blockIdx.z == 0) {
          #pragma unroll
          for (int r = 0; r < 4; ++r)
            outf[(size_t)(grow0 + r) * N + gcol] = acc[m][n][r] + bvl;
        } else {
          #pragma unroll
          for (int r = 0; r < 4; ++r)
            o0[(size_t)(grow0 + r) * N + gcol] = f2bf(acc[m][n][r]);
        }
      } else if (MODE == 1) {
        #pragma unroll
        for (int r = 0; r < 4; ++r) {
          float v = acc[m][n][r] + bvl;
          v = 0.5f * v * (1.0f + erff(v * 0.70710678118654752f));
          o0[(size_t)(grow0 + r) * N + gcol] = f2bf(v);
        }
      } else if (MODE == 4) {
        #pragma unroll
        for (int r = 0; r < 4; ++r)
          o0[(size_t)(grow0 + r) * N + gcol] = f2bf((acc[m][n][r] + bvl) * scale);
      } else if (MODE == 2) {
        int sec = (col0 >> 7) / 6;        // 0..4, block-uniform
        int colr = gcol - sec * 768;
        int hh = colr >> 6, d = colr & 63;
        int bb = grow0 >> 12, s = grow0 & (Ss - 1);
        size_t bhh = (size_t)(bb * Hh + hh);
        if (sec == 0) {
          #pragma unroll
          for (int r = 0; r < 4; ++r)
            o0[(bhh * Ss + s + r) * 64 + d] = f2bf((acc[m][n][r] + bvl) * scale);
        } else if (sec == 1) {
          #pragma unroll
          for (int r = 0; r < 4; ++r)
            o1[(bhh * SPAD + PADL + s + r) * 64 + d] = f2bf(acc[m][n][r] + bvl);
        } else if (sec == 2) {
          sv4 pk;
          #pragma unroll
          for (int r = 0; r < 4; ++r) pk[r] = (short)f2bf(acc[m][n][r] + bvl);
          *reinterpret_cast<sv4*>(o2 + (bhh * 64 + d) * SPAD + PADL + s) = pk;
        } else if (sec == 3) {
          #pragma unroll
          for (int r = 0; r < 4; ++r)
            o3[(bhh * Ss + s + r) * 64 + d] = f2bf(acc[m][n][r] + bvl);
        } else {
          sv4 pk;
          #pragma unroll
          for (int r = 0; r < 4; ++r) pk[r] = (short)f2bf(acc[m][n][r] + bvl);
          *reinterpret_cast<sv4*>(o4 + (bhh * 64 + d) * Ss + s) = pk;
        }
      }
    }
  }
}

// ---------------- gathers ---------------------------------------------------
__global__ __launch_bounds__(256)
void gather_glob_kernel(const u16* __restrict__ kpk, const u16* __restrict__ vtpk,
                        const int* __restrict__ gpos, u16* __restrict__ kg,
                        u16* __restrict__ vgt) {
  int bh = blockIdx.x;
  int b = bh / Hh;
  int tid = threadIdx.x;
  for (int idx = tid; idx < 64 * 64; idx += 256) {
    int g = idx >> 6, d = idx & 63;
    u16 kv = 0, vv = 0;
    if (g < Gg) {
      int p = gpos[b * Gg + g];
      kv = kpk[((size_t)bh * SPAD + PADL + p) * 64 + d];
      vv = vtpk[((size_t)bh * 64 + d) * SPAD + PADL + p];
    }
    kg[(size_t)bh * 4096 + idx] = kv;
    vgt[((size_t)bh * 64 + d) * 64 + g] = vv;
  }
}

__global__ __launch_bounds__(256)
void gather_xg_kernel(const u16* __restrict__ xb, const int* __restrict__ gpos,
                      u16* __restrict__ xg) {
  int rg = blockIdx.x;  // b*G+g
  int b = rg / Gg;
  int p = gpos[rg];
  int tid = threadIdx.x;
  for (int c = tid; c < Dd; c += 256)
    xg[(size_t)rg * Dd + c] = xb[((size_t)b * Ss + p) * Dd + c];
}

// ---------------- local (sliding window + global-key) attention -------------
#define LOCAL_NB (Bb * Hh * (Ss / 64))   // 1536 blocks, %8 == 0
__global__ __launch_bounds__(256)
void attn_local_kernel(const u16* __restrict__ qpk, const u16* __restrict__ kpk,
                       const u16* __restrict__ vtpk, const u16* __restrict__ kg,
                       const u16* __restrict__ vgt, const int* __restrict__ amask,
                       u16* __restrict__ ctx) {
  __shared__ u16 Plds[4][16 * PSTR];
  int bid = blockIdx.x;
  int swz = (bid & 7) * (LOCAL_NB / 8) + (bid >> 3);
  int qb = swz & 63;
  int bh = swz >> 6;
  int b = bh / Hh;
  int h = bh - b * Hh;
  int wv = threadIdx.x >> 6;
  int q0 = qb * 64 + wv * 16;
  int lane = threadIdx.x & 63;
  int lg = lane >> 4, lc = lane & 15;
  int lg4 = lg * 4;
  int q = q0 + lc;   // query owned by this lane for softmax state

  const u16* qbase = qpk + (((size_t)bh) * Ss + q0) * 64;
  bv8 aq0 = *reinterpret_cast<const bv8*>(qbase + (size_t)lc * 64 + lg * 8);
  bv8 aq1 = *reinterpret_cast<const bv8*>(qbase + (size_t)lc * 64 + 32 + lg * 8);

  f32x4 o[4];
  #pragma unroll
  for (int i = 0; i < 4; ++i) o[i] = (f32x4){0.f, 0.f, 0.f, 0.f};
  float mrun = -1e30f, lrun = 0.f;

  const u16* kgb = kg + ((size_t)bh) * 64 * 64;
  const u16* vgb = vgt + ((size_t)bh) * 64 * 64;
  const u16* kb = kpk + ((size_t)bh) * SPAD * 64;
  const u16* vb = vtpk + ((size_t)bh) * 64 * SPAD;
  const int* amb = amask + b * Ss;
  u16* P = &Plds[wv][0];

  // preload K frags for step 0 (global keys)
  bv8 kc[8];
  #pragma unroll
  for (int j = 0; j < 4; ++j) {
    const u16* kr = kgb + (size_t)(j * 16 + lc) * 64;
    kc[2 * j]     = *reinterpret_cast<const bv8*>(kr + lg * 8);
    kc[2 * j + 1] = *reinterpret_cast<const bv8*>(kr + 32 + lg * 8);
  }
  // prefetch amask word for step 1
  int amvN;
  { int ni = min(max(q0 - 256 + lane, 0), Ss - 1); amvN = amb[ni]; }

  for (int step = 0; step < 10; ++step) {
    bool isg = (step == 0);
    int ks = isg ? 0 : (q0 - 256 + (step - 1) * 64);
    int amvC = amvN;
    if (step < 9) { int ni = min(max(q0 - 256 + step * 64 + lane, 0), Ss - 1); amvN = amb[ni]; }

    // issue V loads group 0 (j2 = 0)
    bv8 vf0[4];
    #pragma unroll
    for (int nt = 0; nt < 4; ++nt) {
      const u16* vr = isg ? (vgb + (size_t)(nt * 16 + lc) * 64)
                          : (vb + (size_t)(nt * 16 + lc) * SPAD + PADL + ks);
      vf0[nt] = *reinterpret_cast<const bv8*>(vr + lg * 8);
    }
    // key-validity mask
    unsigned long long kmask;
    if (isg) {
      kmask = (1ull << Gg) - 1;
    } else {
      int kidx = ks + lane;
      kmask = __ballot((kidx >= 0) && (kidx < Ss) && (amvC > 0));
    }
    // QK^T (swapped operands): sc[j] = scores for keys ks+j*16+lg4..+3, query lc
    f32x4 sc[4];
    __builtin_amdgcn_s_setprio(1);
    #pragma unroll
    for (int j = 0; j < 4; ++j) {
      f32x4 z = (f32x4){0.f, 0.f, 0.f, 0.f};
      sc[j] = __builtin_amdgcn_mfma_f32_16x16x32_bf16(kc[2 * j], aq0, z, 0, 0, 0);
      sc[j] = __builtin_amdgcn_mfma_f32_16x16x32_bf16(kc[2 * j + 1], aq1, sc[j], 0, 0, 0);
    }
    __builtin_amdgcn_s_setprio(0);
    // issue V loads group 1 (j2 = 1)
    bv8 vf1[4];
    #pragma unroll
    for (int nt = 0; nt < 4; ++nt) {
      const u16* vr = isg ? (vgb + (size_t)(nt * 16 + lc) * 64 + 32)
                          : (vb + (size_t)(nt * 16 + lc) * SPAD + PADL + ks + 32);
      vf1[nt] = *reinterpret_cast<const bv8*>(vr + lg * 8);
    }
    // reload kc IN PLACE for next step (WAR on QK^T; hides under softmax+PV)
    if (step < 9) {
      int ksn = q0 - 256 + step * 64;
      #pragma unroll
      for (int j = 0; j < 4; ++j) {
        const u16* kr = kb + (size_t)(PADL + ksn + j * 16 + lc) * 64;
        kc[2 * j]     = *reinterpret_cast<const bv8*>(kr + lg * 8);
        kc[2 * j + 1] = *reinterpret_cast<const bv8*>(kr + 32 + lg * 8);
      }
    }
    // masking: steps 2..8 with full kmask are band-safe for all 16 queries
    float mloc = -1e30f;
    bool fast = (!isg) && (step >= 2) && (step <= 8) && (kmask == ~0ull);
    if (fast) {
      #pragma unroll
      for (int j = 0; j < 4; ++j)
        #pragma unroll
        for (int r = 0; r < 4; ++r) mloc = fmaxf(mloc, sc[j][r]);
    } else {
      #pragma unroll
      for (int j = 0; j < 4; ++j)
        #pragma unroll
        for (int r = 0; r < 4; ++r) {
          int kk = ks + j * 16 + lg4 + r;
          bool ok = (kmask >> (j * 16 + lg4 + r)) & 1;
          if (!isg) ok = ok && ((unsigned)(kk - q + 256) <= 512u);
          sc[j][r] = ok ? sc[j][r] : -1e9f;
          mloc = fmaxf(mloc, sc[j][r]);
        }
    }
    mloc = fmaxf(mloc, __shfl_xor(mloc, 16));
    mloc = fmaxf(mloc, __shfl_xor(mloc, 32));
    if (__any(mloc > mrun)) {
      float nm = fmaxf(mrun, mloc);
      float scal = __expf(mrun - nm);
      mrun = nm;
      lrun *= scal;
      #pragma unroll
      for (int r = 0; r < 4; ++r) {
        float sr = __shfl(scal, lg4 + r);  // scal of query lg4+r
        #pragma unroll
        for (int nt = 0; nt < 4; ++nt) o[nt][r] *= sr;
      }
    }
    float psum = 0.f;
    #pragma unroll
    for (int j = 0; j < 4; ++j) {
      sv4 pk;
      #pragma unroll
      for (int r = 0; r < 4; ++r) {
        float p = __expf(sc[j][r] - mrun);
        psum += p;
        pk[r] = (short)f2bf(p);
      }
      *reinterpret_cast<sv4*>(P + lc * PSTR + j * 16 + lg4) = pk;
    }
    psum += __shfl_xor(psum, 16);
    psum += __shfl_xor(psum, 32);
    lrun += psum;
    // PV with prefetched V frags
    __builtin_amdgcn_s_setprio(1);
    {
      bv8 ap = *reinterpret_cast<const bv8*>(P + lc * PSTR + lg * 8);
      #pragma unroll
      for (int nt = 0; nt < 4; ++nt)
        o[nt] = __builtin_amdgcn_mfma_f32_16x16x32_bf16(ap, vf0[nt], o[nt], 0, 0, 0);
      ap = *reinterpret_cast<const bv8*>(P + lc * PSTR + 32 + lg * 8);
      #pragma unroll
      for (int nt = 0; nt < 4; ++nt)
        o[nt] = __builtin_amdgcn_mfma_f32_16x16x32_bf16(ap, vf1[nt], o[nt], 0, 0, 0);
    }
    __builtin_amdgcn_s_setprio(0);
  }
  float inv = 1.0f / lrun;
  #pragma unroll
  for (int r = 0; r < 4; ++r) {
    float invr = __shfl(inv, lg4 + r);
    size_t rowoff = ((size_t)b * Ss + q0 + lg4 + r) * Dd + h * 64;
    #pragma unroll
    for (int nt = 0; nt < 4; ++nt)
      ctx[rowoff + nt * 16 + lc] = f2bf(o[nt][r] * invr);
  }
}

// ---------------- global-query attention: lane-local flash MFMA -------------
// grid bh*NCH; 3 waves; per chunk 4 steps of 64 keys; swapped QK^T so lane
// owns query lc (2 shuffles per reduce); no band mask (global queries).
__global__ __launch_bounds__(192)
void attn_globalq_kernel(const u16* __restrict__ qgb, const u16* __restrict__ kgf,
                         const u16* __restrict__ vgt, const int* __restrict__ amask,
                         float* __restrict__ part) {
  __shared__ u16 Plds[3][16 * PSTR];
  int blk = blockIdx.x;
  int ch = blk & (NCH - 1);
  int bh = blk / NCH;
  int b = bh / Hh, h = bh - b * Hh;
  int wv = threadIdx.x >> 6;  // q-tile 0..2
  int lane = threadIdx.x & 63;
  int lg = lane >> 4, lc = lane & 15;
  int lg4 = lg * 4;

  int qrow = wv * 16 + lc;
  bv8 aq0 = (bv8)0, aq1 = (bv8)0;
  if (qrow < Gg) {
    const u16* qr = qgb + (size_t)(b * Gg + qrow) * Dd + h * 64;
    aq0 = *reinterpret_cast<const bv8*>(qr + lg * 8);
    aq1 = *reinterpret_cast<const bv8*>(qr + 32 + lg * 8);
  }

  f32x4 o[4];
  #pragma unroll
  for (int i = 0; i < 4; ++i) o[i] = (f32x4){0.f, 0.f, 0.f, 0.f};
  float mrun = -1e30f, lrun = 0.f;

  const u16* kb = kgf + ((size_t)bh) * Ss * 64;
  const u16* vb = vgt + ((size_t)bh) * 64 * Ss;
  const int* amb = amask + b * Ss;
  int ks0 = ch * (Ss / NCH);
  u16* P = &Plds[wv][0];

  // preload K frags for step 0
  bv8 kc[8];
  #pragma unroll
  for (int j = 0; j < 4; ++j) {
    const u16* kr = kb + (size_t)(ks0 + j * 16 + lc) * 64;
    kc[2 * j]     = *reinterpret_cast<const bv8*>(kr + lg * 8);
    kc[2 * j + 1] = *reinterpret_cast<const bv8*>(kr + 32 + lg * 8);
  }

  for (int st = 0; st < 4; ++st) {
    int ks = ks0 + st * 64;
    // V loads
    bv8 vf0[4], vf1[4];
    #pragma unroll
    for (int nt = 0; nt < 4; ++nt) {
      const u16* vr = vb + (size_t)(nt * 16 + lc) * Ss + ks;
      vf0[nt] = *reinterpret_cast<const bv8*>(vr + lg * 8);
      vf1[nt] = *reinterpret_cast<const bv8*>(vr + 32 + lg * 8);
    }
    unsigned long long kmask = __ballot(amb[ks + lane] > 0);
    // QK^T swapped
    f32x4 sc[4];
    __builtin_amdgcn_s_setprio(1);
    #pragma unroll
    for (int j = 0; j < 4; ++j) {
      f32x4 z = (f32x4){0.f, 0.f, 0.f, 0.f};
      sc[j] = __builtin_amdgcn_mfma_f32_16x16x32_bf16(kc[2 * j], aq0, z, 0, 0, 0);
      sc[j] = __builtin_amdgcn_mfma_f32_16x16x32_bf16(kc[2 * j + 1], aq1, sc[j], 0, 0, 0);
    }
    __builtin_amdgcn_s_setprio(0);
    // reload kc for next step
    if (st < 3) {
      int ksn = ks0 + (st + 1) * 64;
      #pragma unroll
      for (int j = 0; j < 4; ++j) {
        const u16* kr = kb + (size_t)(ksn + j * 16 + lc) * 64;
        kc[2 * j]     = *reinterpret_cast<const bv8*>(kr + lg * 8);
        kc[2 * j + 1] = *reinterpret_cast<const bv8*>(kr + 32 + lg * 8);
      }
    }
    float mloc = -1e30f;
    if (kmask == ~0ull) {
      #pragma unroll
      for (int j = 0; j < 4; ++j)
        #pragma unroll
        for (int r = 0; r < 4; ++r) mloc = fmaxf(mloc, sc[j][r]);
    } else {
      #pragma unroll
      for (int j = 0; j < 4; ++j)
        #pragma unroll
        for (int r = 0; r < 4; ++r) {
          bool ok = (kmask >> (j * 16 + lg4 + r)) & 1;
          sc[j][r] = ok ? sc[j][r] : -1e9f;
          mloc = fmaxf(mloc, sc[j][r]);
        }
    }
    mloc = fmaxf(mloc, __shfl_xor(mloc, 16));
    mloc = fmaxf(mloc, __shfl_xor(mloc, 32));
    if (__any(mloc > mrun)) {
      float nm = fmaxf(mrun, mloc);
      float scal = __expf(mrun - nm);
      mrun = nm;
      lrun *= scal;
      #pragma unroll
      for (int r = 0; r < 4; ++r) {
        float sr = __shfl(scal, lg4 + r);
        #pragma unroll
        for (int nt = 0; nt < 4; ++nt) o[nt][r] *= sr;
      }
    }
    float psum = 0.f;
    #pragma unroll
    for (int j = 0; j < 4; ++j) {
      sv4 pk;
      #pragma unroll
      for (int r = 0; r < 4; ++r) {
        float p = __expf(sc[j][r] - mrun);
        psum += p;
        pk[r] = (short)f2bf(p);
      }
      *reinterpret_cast<sv4*>(P + lc * PSTR + j * 16 + lg4) = pk;
    }
    psum += __shfl_xor(psum, 16);
    psum += __shfl_xor(psum, 32);
    lrun += psum;
    __builtin_amdgcn_s_setprio(1);
    {
      bv8 ap = *reinterpret_cast<const bv8*>(P + lc * PSTR + lg * 8);
      #pragma unroll
      for (int nt = 0; nt < 4; ++nt)
        o[nt] = __builtin_amdgcn_mfma_f32_16x16x32_bf16(ap, vf0[nt], o[nt], 0, 0, 0);
      ap = *reinterpret_cast<const bv8*>(P + lc * PSTR + 32 + lg * 8);
      #pragma unroll
      for (int nt = 0; nt < 4; ++nt)
        o[nt] = __builtin_amdgcn_mfma_f32_16x16x32_bf16(ap, vf1[nt], o[nt], 0, 0, 0);
    }
    __builtin_amdgcn_s_setprio(0);
  }

  float* pb = part + ((size_t)(bh * 3 + wv) * NCH + ch) * PARTF;
  #pragma unroll
  for (int r = 0; r < 4; ++r) {
    int row = lg4 + r;
    #pragma unroll
    for (int nt = 0; nt < 4; ++nt)
      pb[row * 64 + nt * 16 + lc] = o[nt][r];
  }
  if (lg == 0) {
    pb[1024 + lc] = mrun;
    pb[1040 + lc] = lrun;
  }
}

// merge NCH chunk-partials and scatter into ctx rows at gpos
__global__ __launch_bounds__(256)
void attn_gmerge_kernel(const float* __restrict__ part, const int* __restrict__ gpos,
                        u16* __restrict__ ctx) {
  __shared__ float wgt[Gg][NCH];
  __shared__ float sinvl[Gg];
  int bh = blockIdx.x;
  int b = bh / Hh, h = bh - b * Hh;
  int tid = threadIdx.x;
  if (tid < Gg) {
    int qt = tid >> 4, rr = tid & 15;
    const float* pb = part + ((size_t)(bh * 3 + qt) * NCH) * PARTF;
    float mx = -1e30f;
    for (int c = 0; c < NCH; ++c) mx = fmaxf(mx, pb[c * PARTF + 1024 + rr]);
    float l = 0.f;
    for (int c = 0; c < NCH; ++c) {
      float w = __expf(pb[c * PARTF + 1024 + rr] - mx);
      wgt[tid][c] = w;
      l += w * pb[c * PARTF + 1040 + rr];
    }
    sinvl[tid] = 1.0f / l;
  }
  __syncthreads();
  for (int e = tid; e < Gg * 64; e += 256) {
    int row = e >> 6, d = e & 63;
    int qt = row >> 4, rr = row & 15;
    const float* pb = part + ((size_t)(bh * 3 + qt) * NCH) * PARTF + rr * 64 + d;
    float acc = 0.f;
    #pragma unroll
    for (int c = 0; c < NCH; ++c) acc += wgt[row][c] * pb[c * PARTF];
    int pos = gpos[b * Gg + row];
    ctx[((size_t)b * Ss + pos) * Dd + h * 64 + d] = f2bf(acc * sinvl[row]);
  }
}

// ---------------- classifier ------------------------------------------------
__global__ __launch_bounds__(64)
void cls_kernel(const float* __restrict__ x, const float* __restrict__ W,
                const float* __restrict__ bias, const int* __restrict__ gpos,
                float* __restrict__ out) {
  int r = blockIdx.x;  // b*32 + i
  int b = r >> 5, i = r & 31;
  int pos = gpos[b * Gg + 1 + i];
  int lane = threadIdx.x;
  const float* xr = x + ((size_t)b * Ss + pos) * Dd;
  float acc[NCLSn] = {0.f, 0.f, 0.f, 0.f, 0.f};
  for (int k = lane; k < Dd; k += 64) {
    float xv = xr[k];
    #pragma unroll
    for (int c = 0; c < NCLSn; ++c) acc[c] += xv * W[c * Dd + k];
  }
  #pragma unroll
  for (int c = 0; c < NCLSn; ++c) {
    #pragma unroll
    for (int off = 1; off < 64; off <<= 1) acc[c] += __shfl_xor(acc[c], off);
  }
  if (lane == 0) {
    #pragma unroll
    for (int c = 0; c < NCLSn; ++c) out[r * NCLSn + c] = acc[c] + bias[c];
  }
}

// ---------------------------------------------------------------------------
extern "C" void kernel_launch(void* const* d_in, const int* in_sizes, int n_in,
                              void* d_out, int out_size, void* d_ws, size_t ws_size,
                              hipStream_t stream) {
  const int* ids     = (const int*)d_in[0];
  const int* amask   = (const int*)d_in[1];
  const float* we    = (const float*)d_in[2];
  const float* pe    = (const float*)d_in[3];
  const float* te    = (const float*)d_in[4];
  const float* embln = (const float*)d_in[5];
  const float* Wqkv  = (const float*)d_in[6];
  const float* bqkv  = (const float*)d_in[7];
  const float* Wqkvg = (const float*)d_in[8];
  const float* bqkvg = (const float*)d_in[9];
  const float* Wo    = (const float*)d_in[10];
  const float* bo    = (const float*)d_in[11];
  const float* ln1   = (const float*)d_in[12];
  const float* Wff1  = (const float*)d_in[13];
  const float* bff1  = (const float*)d_in[14];
  const float* Wff2  = (const float*)d_in[15];
  const float* bff2  = (const float*)d_in[16];
  const float* ln2   = (const float*)d_in[17];
  const float* clsW  = (const float*)d_in[18];
  const float* clsb  = (const float*)d_in[19];
  float* out = (float*)d_out;

  char* ws = (char*)d_ws;
  size_t off = 0;
  auto alloc = [&](size_t bytes) { size_t o = off; off += (bytes + 255) & ~(size_t)255; return o; };

  const size_t DD = (size_t)Dd * Dd;        // 589824
  const size_t DF = (size_t)Dd * 4 * Dd;    // 2359296
  const size_t WL = 7 * DD + 2 * DF;        // elems per layer
  // Wb layout per layer: [q,k,v, gk,gv, gq, wo, ff1, ff2]

  size_t o_cnt  = alloc(Bb * 4);
  size_t o_list = alloc(Bb * 64 * 4);
  size_t o_gpos = alloc(Bb * Gg * 4);
  size_t o_bias = alloc((size_t)Ll * 3840 * 4);
  size_t o_w    = alloc(WL * Ll * 2);
  size_t o_x    = alloc((size_t)Bb * Ss * Dd * 4);
  size_t o_xb   = alloc((size_t)Bb * Ss * Dd * 2);
  // kgf/vgf first: their 25.17 MB doubles as split-K bf16 buffer B
  size_t o_kgf  = alloc((size_t)Bb * Hh * Ss * 64 * 2);
  size_t o_vgf  = alloc((size_t)Bb * Hh * Ss * 64 * 2);
  size_t o_accB = o_kgf;  // bf16 half-B: 8192*768*2 bytes fits in kgf alone
  size_t o_qpk  = alloc((size_t)Bb * Hh * Ss * 64 * 2);
  size_t o_kpk  = alloc((size_t)Bb * Hh * SPAD * 64 * 2);
  size_t o_vtpk = alloc((size_t)Bb * Hh * 64 * SPAD * 2);
  size_t o_kg   = alloc((size_t)Bb * Hh * 64 * 64 * 2);
  size_t o_vgt  = alloc((size_t)Bb * Hh * 64 * 64 * 2);
  size_t o_xg   = alloc((size_t)128 * Dd * 2);
  size_t o_qg   = alloc((size_t)128 * Dd * 2);
  size_t o_part = alloc((size_t)Bb * Hh * 3 * NCH * PARTF * 4);
  size_t o_f1b  = o_qpk;  // FFN hidden aliases the (dead-by-then) attention buffers
  {
    size_t f1b_bytes = (size_t)Bb * Ss * 4 * Dd * 2;
    if (off - o_qpk < f1b_bytes) off = o_qpk + ((f1b_bytes + 255) & ~(size_t)255);
  }
  size_t o_ctx = alloc((size_t)Bb * Ss * Dd * 2);
  size_t o_acc = alloc((size_t)Bb * Ss * Dd * 4);
  if (ws_size < off) return;  // workspace too small -> fail visibly

  u16* Wb = (u16*)(ws + o_w);
  int* gposp = (int*)(ws + o_gpos);
  float* accA = (float*)(ws + o_acc);
  u16* accB = (u16*)(ws + o_accB);

  (void)hipMemsetAsync(ws + o_cnt, 0, Bb * 4, stream);
  // zero padded K / V^T so first-call pads are finite (later calls: finite stale bf16)
  (void)hipMemsetAsync(ws + o_kpk, 0, (size_t)Bb * Hh * SPAD * 64 * 2, stream);
  (void)hipMemsetAsync(ws + o_vtpk, 0, (size_t)Bb * Hh * 64 * SPAD * 2, stream);
  (void)hipMemsetAsync(ws + o_xg, 0, (size_t)128 * Dd * 2, stream);

  // concat bias per layer: [bqkv(3x768) | bqkvg_k(768) | bqkvg_v(768)]
  for (int l = 0; l < Ll; ++l) {
    (void)hipMemcpyAsync(ws + o_bias + (size_t)l * 3840 * 4, bqkv + (size_t)l * 3 * Dd,
                         3 * Dd * 4, hipMemcpyDeviceToDevice, stream);
    (void)hipMemcpyAsync(ws + o_bias + (size_t)l * 3840 * 4 + 3 * Dd * 4,
                         bqkvg + (size_t)(l * 3 + 1) * Dd,
                         2 * Dd * 4, hipMemcpyDeviceToDevice, stream);
  }

  sep_find_kernel<<<(Bb * Ss + 255) / 256, 256, 0, stream>>>(ids, (int*)(ws + o_cnt), (int*)(ws + o_list));
  sep_sort_kernel<<<Bb, 64, 0, stream>>>((int*)(ws + o_cnt), (int*)(ws + o_list), gposp);

  // weight conversions (batched over z); Wb layout [q,k,v,gk,gv,gq,wo,ff1,ff2]
  wconv_kernel<<<dim3(24, 24, 6), 256, 0, stream>>>(Wqkv,       Wb,          Dd, Dd, 3, 3, (long)DD, (long)WL);
  wconv_kernel<<<dim3(24, 24, 2), 256, 0, stream>>>(Wqkvg + DD,     Wb + 3 * DD, Dd, Dd, 1, 3, 0L, (long)WL);  // gk
  wconv_kernel<<<dim3(24, 24, 2), 256, 0, stream>>>(Wqkvg + 2 * DD, Wb + 4 * DD, Dd, Dd, 1, 3, 0L, (long)WL);  // gv
  wconv_kernel<<<dim3(24, 24, 2), 256, 0, stream>>>(Wqkvg,          Wb + 5 * DD, Dd, Dd, 1, 3, 0L, (long)WL);  // gq
  wconv_kernel<<<dim3(24, 24, 2), 256, 0, stream>>>(Wo,         Wb + 6 * DD, Dd, Dd, 1, 1, 0L, (long)WL);
  wconv_kernel<<<dim3(96, 24, 2), 256, 0, stream>>>(Wff1,       Wb + 7 * DD, Dd, 4 * Dd, 1, 1, 0L, (long)WL);
  wconv_kernel<<<dim3(24, 96, 2), 256, 0, stream>>>(Wff2,       Wb + 7 * DD + DF, 4 * Dd, Dd, 1, 1, 0L, (long)WL);

  embed_ln_kernel<<<Bb * Ss, 256, 0, stream>>>(ids, we, pe, te, embln, (float*)(ws + o_x), (u16*)(ws + o_xb));

  for (int l = 0; l < Ll; ++l) {
    size_t wb = (size_t)l * WL;
    u16* xb = (u16*)(ws + o_xb);
    // fused QKV + global K/V projection (N=3840, 5 sections); grid 1920 %8==0
    gemm2_kernel<2, true><<<dim3(30, 64), 256, 0, stream>>>(xb, Wb + wb, (float*)(ws + o_bias) + (size_t)l * 3840,
        nullptr,
        (u16*)(ws + o_qpk), (u16*)(ws + o_kpk), (u16*)(ws + o_vtpk),
        (u16*)(ws + o_kgf), (u16*)(ws + o_vgf), 3840, Dd, Dd, 0.125f);
    gather_glob_kernel<<<Bb * Hh, 256, 0, stream>>>((u16*)(ws + o_kpk), (u16*)(ws + o_vtpk), gposp, (u16*)(ws + o_kg), (u16*)(ws + o_vgt));
    gather_xg_kernel<<<Bb * Gg, 256, 0, stream>>>(xb, gposp, (u16*)(ws + o_xg));
    // global q projection (M=128 padded rows); 6 blocks -> no XCD swizzle
    gemm2_kernel<4, false><<<dim3(6, 1), 256, 0, stream>>>((u16*)(ws + o_xg), Wb + wb + 5 * DD, bqkvg + (size_t)l * 3 * Dd,
        nullptr, (u16*)(ws + o_qg), nullptr, nullptr, nullptr, nullptr, Dd, Dd, Dd, 0.125f);
    // attention
    attn_local_kernel<<<LOCAL_NB, 256, 0, stream>>>((u16*)(ws + o_qpk), (u16*)(ws + o_kpk), (u16*)(ws + o_vtpk), (u16*)(ws + o_kg), (u16*)(ws + o_vgt), amask, (u16*)(ws + o_ctx));
    attn_globalq_kernel<<<Bb * Hh * NCH, 192, 0, stream>>>((u16*)(ws + o_qg), (u16*)(ws + o_kgf), (u16*)(ws + o_vgf), amask, (float*)(ws + o_part));
    attn_gmerge_kernel<<<Bb * Hh, 256, 0, stream>>>((float*)(ws + o_part), gposp, (u16*)(ws + o_ctx));
    // output projection (split-K x2, half-B bf16) + LN  [kgf/vgf dead now]
    gemm2_kernel<0, true><<<dim3(6, 64, 2), 256, 0, stream>>>((u16*)(ws + o_ctx), Wb + wb + 6 * DD, bo + (size_t)l * Dd, accA,
        accB, nullptr, nullptr, nullptr, nullptr, Dd, Dd, Dd / 2, 1.0f);
    add_ln3_kernel<<<Bb * Ss, 256, 0, stream>>>((float*)(ws + o_x), accA, accB, ln1 + (size_t)l * 2 * Dd, (float*)(ws + o_x), xb);
    // FFN
    gemm2_kernel<1, true><<<dim3(24, 64), 256, 0, stream>>>(xb, Wb + wb + 7 * DD, bff1 + (size_t)l * 4 * Dd, nullptr,
        (u16*)(ws + o_f1b), nullptr, nullptr, nullptr, nullptr, 4 * Dd, Dd, Dd, 1.0f);
    gemm2_kernel<0, true><<<dim3(6, 64, 2), 256, 0, stream>>>((u16*)(ws + o_f1b), Wb + wb + 7 * DD + DF, bff2 + (size_t)l * Dd, accA,
        accB, nullptr, nullptr, nullptr, nullptr, Dd, 4 * Dd, 2 * Dd, 1.0f);
    add_ln3_kernel<<<Bb * Ss, 256, 0, stream>>>((float*)(ws + o_x), accA, accB, ln2 + (size_t)l * 2 * Dd, (float*)(ws + o_x), xb);
  }

  cls_kernel<<<Bb * NSEPn, 64, 0, stream>>>((float*)(ws + o_x), clsW, clsb, gposp, out);
}

// Round 12
// 776.797 us; speedup vs baseline: 1.2007x; 1.0819x over previous
//
#include <hip/hip_runtime.h>

// ---------------------------------------------------------------------------
// Longformer (2-layer) forward, MI355X.
// R11: attn_local -> 2 q-tiles per wave, 2 waves/block (same 64q window, no
//      extra MFMA): per-step scalar overhead halves per query, 2x softmax ILP.
//      Defer-max (THR=8) in both attention kernels.
// ---------------------------------------------------------------------------

#define Bb 2
#define Ss 4096
#define Dd 768
#define Hh 12
#define Gg 33
#define NSEPn 32
#define Ll 2
#define SPAD 4640   // S + 544 (PADL=256 left, 288 right)
#define PADL 256
#define NCLSn 5
#define NCH 16      // key chunks for global-q attention (256 keys each)
#define PARTF 1056  // floats per (bh,qt,chunk) partial: 16*64 o + 16 m + 16 l
#define PSTR 72     // Plds row stride in u16 (144B: 16B-aligned, bank-spread)

typedef unsigned short u16;
typedef __attribute__((ext_vector_type(8))) short bv8;   // 8 x bf16
typedef __attribute__((ext_vector_type(4))) short sv4;   // 4 x bf16
typedef __attribute__((ext_vector_type(4))) float f32x4;

__device__ __forceinline__ float bf2f(u16 u) {
  unsigned v = ((unsigned)u) << 16;
  return __builtin_bit_cast(float, v);
}
__device__ __forceinline__ u16 f2bf(float f) {
  unsigned u = __builtin_bit_cast(unsigned, f);
  u += 0x7fffu + ((u >> 16) & 1u);
  return (u16)(u >> 16);
}
__device__ __forceinline__ void glds16(const void* g, void* l) {
  __builtin_amdgcn_global_load_lds(
      (const __attribute__((address_space(1))) void*)g,
      (__attribute__((address_space(3))) void*)l, 16, 0, 0);
}

// ---------------- sep finding --------------------------------------------
__global__ void sep_find_kernel(const int* __restrict__ ids, int* __restrict__ cnt,
                                int* __restrict__ list) {
  int i = blockIdx.x * 256 + threadIdx.x;
  if (i >= Bb * Ss) return;
  int b = i >> 12;
  if (ids[i] == 2) {
    int idx = atomicAdd(&cnt[b], 1);
    if (idx < 64) list[b * 64 + idx] = i & (Ss - 1);
  }
}

__global__ void sep_sort_kernel(const int* __restrict__ cnt, const int* __restrict__ list,
                                int* __restrict__ gpos) {
  int b = blockIdx.x;
  int t = threadIdx.x;
  int n = cnt[b]; if (n > 64) n = 64;
  if (t < Gg) gpos[b * Gg + t] = (t == 0) ? 0 : (Ss - 1);
  __syncthreads();
  if (t < n) {
    int v = list[b * 64 + t];
    int rank = 0;
    for (int j = 0; j < n; ++j) rank += (list[b * 64 + j] < v) ? 1 : 0;
    if (rank < NSEPn) gpos[b * Gg + 1 + rank] = v;
  }
}

// ------- weight fp32 (K,N) -> bf16 (N,K), batched; src slice (z/grp)*sstr+z%grp
__global__ __launch_bounds__(256)
void wconv_kernel(const float* __restrict__ src0, u16* __restrict__ dst0,
                  int K, int N, int grp, int sstr, long unit, long WLs) {
  __shared__ float t[32][33];
  int z = blockIdx.z;
  const float* src = src0 + (size_t)((z / grp) * sstr + (z % grp)) * K * N;
  u16* dst = dst0 + (size_t)(z / grp) * WLs + (size_t)(z % grp) * unit;
  int n0 = blockIdx.x * 32, k0 = blockIdx.y * 32;
  int tx = threadIdx.x & 31, ty = threadIdx.x >> 5;  // ty 0..7
  #pragma unroll
  for (int i = 0; i < 4; ++i)
    t[ty + i * 8][tx] = src[(size_t)(k0 + ty + i * 8) * N + n0 + tx];
  __syncthreads();
  #pragma unroll
  for (int i = 0; i < 4; ++i)
    dst[(size_t)(n0 + ty + i * 8) * K + k0 + tx] = f2bf(t[tx][ty + i * 8]);
}

// ---------------- embedding + LN -------------------------------------------
__global__ __launch_bounds__(256)
void embed_ln_kernel(const int* __restrict__ ids, const float* __restrict__ we,
                     const float* __restrict__ pe, const float* __restrict__ te,
                     const float* __restrict__ lnp, float* __restrict__ x,
                     u16* __restrict__ xb) {
  int row = blockIdx.x;
  int s = row & (Ss - 1);
  int id = ids[row];
  int tid = threadIdx.x;
  float v[3]; float sm = 0.f, s2 = 0.f;
  #pragma unroll
  for (int i = 0; i < 3; ++i) {
    int c = tid + i * 256;
    float t = we[(size_t)id * Dd + c] + pe[(size_t)(s + 2) * Dd + c] + te[c];
    v[i] = t; sm += t; s2 += t * t;
  }
  __shared__ float r1[256], r2[256];
  r1[tid] = sm; r2[tid] = s2; __syncthreads();
  for (int o = 128; o; o >>= 1) {
    if (tid < o) { r1[tid] += r1[tid + o]; r2[tid] += r2[tid + o]; }
    __syncthreads();
  }
  float mean = r1[0] * (1.f / 768.f);
  float var  = r2[0] * (1.f / 768.f) - mean * mean;
  float rs = rsqrtf(var + 1e-5f);
  #pragma unroll
  for (int i = 0; i < 3; ++i) {
    int c = tid + i * 256;
    float o = (v[i] - mean) * rs * lnp[c] + lnp[Dd + c];
    x[(size_t)row * Dd + c] = o;
    xb[(size_t)row * Dd + c] = f2bf(o);
  }
}

// ---------------- residual(2 fp32 + 1 bf16) + LN ----------------------------
__global__ __launch_bounds__(256)
void add_ln3_kernel(const float* __restrict__ xin, const float* __restrict__ y0,
                    const u16* __restrict__ y1, const float* __restrict__ lnp,
                    float* __restrict__ xout, u16* __restrict__ xbout) {
  int row = blockIdx.x;
  int tid = threadIdx.x;
  float v[3]; float sm = 0.f, s2 = 0.f;
  #pragma unroll
  for (int i = 0; i < 3; ++i) {
    int c = tid + i * 256;
    size_t idx = (size_t)row * Dd + c;
    float t = xin[idx] + y0[idx] + bf2f(y1[idx]);
    v[i] = t; sm += t; s2 += t * t;
  }
  __shared__ float r1[256], r2[256];
  r1[tid] = sm; r2[tid] = s2; __syncthreads();
  for (int o = 128; o; o >>= 1) {
    if (tid < o) { r1[tid] += r1[tid + o]; r2[tid] += r2[tid + o]; }
    __syncthreads();
  }
  float mean = r1[0] * (1.f / 768.f);
  float var  = r2[0] * (1.f / 768.f) - mean * mean;
  float rs = rsqrtf(var + 1e-5f);
  #pragma unroll
  for (int i = 0; i < 3; ++i) {
    int c = tid + i * 256;
    float o = (v[i] - mean) * rs * lnp[c] + lnp[Dd + c];
    xout[(size_t)row * Dd + c] = o;
    xbout[(size_t)row * Dd + c] = f2bf(o);
  }
}

// ---------------- GEMM2: 128x128 2-buffer + T2 LDS swizzle + T1 XCD swizzle -
// MODE 0: split-K: z==0 -> fp32 outf (+bias); z==1 -> bf16 o0 (no bias)
// MODE 1: bf16 [M][N], exact gelu
// MODE 2: fused QKV+gKV: N=3840; secs: q pk / k pad / v^T pad / gk pk / gv^T
// MODE 4: bf16 [M][N] * scale
template <int MODE, bool XSWZ>
__global__ __launch_bounds__(256)
void gemm2_kernel(const u16* __restrict__ A, const u16* __restrict__ Bt,
                  const float* __restrict__ bias, float* __restrict__ outf,
                  u16* __restrict__ o0, u16* __restrict__ o1, u16* __restrict__ o2,
                  u16* __restrict__ o3, u16* __restrict__ o4,
                  int N, int Ks, int Kl, float scale) {
  __shared__ u16 la[2][128 * 32], lb[2][128 * 32];
  int tid = threadIdx.x;
  int wave = tid >> 6, lane = tid & 63;
  int wr = wave >> 1, wc = wave & 1;
  int lg = lane >> 4, lc = lane & 15;
  // T1: XCD-aware bijective remap of the x-y plane (requires NB % 8 == 0)
  int bx = blockIdx.x, by = blockIdx.y;
  if (XSWZ) {
    int gx = gridDim.x;
    int nlin = bx + gx * by;
    int NB = gx * gridDim.y;
    nlin = (nlin & 7) * (NB >> 3) + (nlin >> 3);
    bx = nlin % gx;
    by = nlin / gx;
  }
  int row0 = by * 128, col0 = bx * 128;
  int koff = blockIdx.z * Kl;

  // T2 swizzle: linear LDS dest; lane fetches logical granule (l&3)^((l>>3)&3)
  int sgr = (lane & 3) ^ ((lane >> 3) & 3);
  const u16* Ag = A + (size_t)(row0 + wave * 32 + (lane >> 2)) * Ks + sgr * 8 + koff;
  const u16* Bg = Bt + (size_t)(col0 + wave * 32 + (lane >> 2)) * Ks + sgr * 8 + koff;
  int wofs = wave * 1024;
  int gph = (lg ^ ((lc >> 1) & 3)) * 8;   // swizzled read granule offset (u16)

  f32x4 acc[4][4];
  #pragma unroll
  for (int m = 0; m < 4; ++m)
    #pragma unroll
    for (int n = 0; n < 4; ++n) acc[m][n] = (f32x4){0.f, 0.f, 0.f, 0.f};

  glds16(Ag, la[0] + wofs);
  glds16(Ag + (size_t)16 * Ks, la[0] + wofs + 512);
  glds16(Bg, lb[0] + wofs);
  glds16(Bg + (size_t)16 * Ks, lb[0] + wofs + 512);
  __syncthreads();

  int nk = Kl >> 5;
  for (int t = 0; t < nk; ++t) {
    int cur = t & 1;
    if (t + 1 < nk) {
      int k1 = (t + 1) << 5;
      glds16(Ag + k1, la[cur ^ 1] + wofs);
      glds16(Ag + (size_t)16 * Ks + k1, la[cur ^ 1] + wofs + 512);
      glds16(Bg + k1, lb[cur ^ 1] + wofs);
      glds16(Bg + (size_t)16 * Ks + k1, lb[cur ^ 1] + wofs + 512);
    }
    bv8 af[4], bf_[4];
    #pragma unroll
    for (int m = 0; m < 4; ++m)
      af[m] = *reinterpret_cast<const bv8*>(la[cur] + (wr * 64 + m * 16 + lc) * 32 + gph);
    #pragma unroll
    for (int n = 0; n < 4; ++n)
      bf_[n] = *reinterpret_cast<const bv8*>(lb[cur] + (wc * 64 + n * 16 + lc) * 32 + gph);
    __builtin_amdgcn_s_setprio(1);
    #pragma unroll
    for (int m = 0; m < 4; ++m)
      #pragma unroll
      for (int n = 0; n < 4; ++n)
        acc[m][n] = __builtin_amdgcn_mfma_f32_16x16x32_bf16(af[m], bf_[n], acc[m][n], 0, 0, 0);
    __builtin_amdgcn_s_setprio(0);
    __syncthreads();
  }

  #pragma unroll
  for (int m = 0; m < 4; ++m) {
    int grow0 = row0 + wr * 64 + m * 16 + lg * 4;
    #pragma unroll
    for (int n = 0; n < 4; ++n) {
      int gcol = col0 + wc * 64 + n * 16 + lc;
      float bvl = bias[gcol];
      if (MODE == 0) {
        if (blockIdx.z == 0) {
          #pragma unroll
          for (int r = 0; r < 4; ++r)
            outf[(size_t)(grow0 + r) * N + gcol] = acc[m][n][r] + bvl;
        } else {
          #pragma unroll
          for (int r = 0; r < 4; ++r)
            o0[(size_t)(grow0 + r) * N + gcol] = f2bf(acc[m][n][r]);
        }
      } else if (MODE == 1) {
        #pragma unroll
        for (int r = 0; r < 4; ++r) {
          float v = acc[m][n][r] + bvl;
          v = 0.5f * v * (1.0f + erff(v * 0.70710678118654752f));
          o0[(size_t)(grow0 + r) * N + gcol] = f2bf(v);
        }
      } else if (MODE == 4) {
        #pragma unroll
        for (int r = 0; r < 4; ++r)
          o0[(size_t)(grow0 + r) * N + gcol] = f2bf((acc[m][n][r] + bvl) * scale);
      } else if (MODE == 2) {
        int sec = (col0 >> 7) / 6;        // 0..4, block-uniform
        int colr = gcol - sec * 768;
        int hh = colr >> 6, d = colr & 63;
        int bb = grow0 >> 12, s = grow0 & (Ss - 1);
        size_t bhh = (size_t)(bb * Hh + hh);
        if (sec == 0) {
          #pragma unroll
          for (int r = 0; r < 4; ++r)
            o0[(bhh * Ss + s + r) * 64 + d] = f2bf((acc[m][n][r] + bvl) * scale);
        } else if (sec == 1) {
          #pragma unroll
          for (int r = 0; r < 4; ++r)
            o1[(bhh * SPAD + PADL + s + r) * 64 + d] = f2bf(acc[m][n][r] + bvl);
        } else if (sec == 2) {
          sv4 pk;
          #pragma unroll
          for (int r = 0; r < 4; ++r) pk[r] = (short)f2bf(acc[m][n][r] + bvl);
          *reinterpret_cast<sv4*>(o2 + (bhh * 64 + d) * SPAD + PADL + s) = pk;
        } else if (sec == 3) {
          #pragma unroll
          for (int r = 0; r < 4; ++r)
            o3[(bhh * Ss + s + r) * 64 + d] = f2bf(acc[m][n][r] + bvl);
        } else {
          sv4 pk;
          #pragma unroll
          for (int r = 0; r < 4; ++r) pk[r] = (short)f2bf(acc[m][n][r] + bvl);
          *reinterpret_cast<sv4*>(o4 + (bhh * 64 + d) * Ss + s) = pk;
        }
      }
    }
  }
}

// ---------------- gathers ---------------------------------------------------
__global__ __launch_bounds__(256)
void gather_glob_kernel(const u16* __restrict__ kpk, const u16* __restrict__ vtpk,
                        const int* __restrict__ gpos, u16* __restrict__ kg,
                        u16* __restrict__ vgt) {
  int bh = blockIdx.x;
  int b = bh / Hh;
  int tid = threadIdx.x;
  for (int idx = tid; idx < 64 * 64; idx += 256) {
    int g = idx >> 6, d = idx & 63;
    u16 kv = 0, vv = 0;
    if (g < Gg) {
      int p = gpos[b * Gg + g];
      kv = kpk[((size_t)bh * SPAD + PADL + p) * 64 + d];
      vv = vtpk[((size_t)bh * 64 + d) * SPAD + PADL + p];
    }
    kg[(size_t)bh * 4096 + idx] = kv;
    vgt[((size_t)bh * 64 + d) * 64 + g] = vv;
  }
}

__global__ __launch_bounds__(256)
void gather_xg_kernel(const u16* __restrict__ xb, const int* __restrict__ gpos,
                      u16* __restrict__ xg) {
  int rg = blockIdx.x;  // b*G+g
  int b = rg / Gg;
  int p = gpos[rg];
  int tid = threadIdx.x;
  for (int c = tid; c < Dd; c += 256)
    xg[(size_t)rg * Dd + c] = xb[((size_t)b * Ss + p) * Dd + c];
}

// ---------------- local (sliding window + global-key) attention -------------
// 2 waves/block, 2 q-tiles/wave (64 queries/block). Swapped QK^T, ballot mask,
// defer-max (THR=8). Per-step scalar overhead amortized over 32 queries/wave.
#define LOCAL_NB (Bb * Hh * (Ss / 64))   // 1536 blocks, %8 == 0
__global__ __launch_bounds__(128)
void attn_local_kernel(const u16* __restrict__ qpk, const u16* __restrict__ kpk,
                       const u16* __restrict__ vtpk, const u16* __restrict__ kg,
                       const u16* __restrict__ vgt, const int* __restrict__ amask,
                       u16* __restrict__ ctx) {
  __shared__ u16 Plds[4][16 * PSTR];
  int bid = blockIdx.x;
  int swz = (bid & 7) * (LOCAL_NB / 8) + (bid >> 3);
  int qb = swz & 63;
  int bh = swz >> 6;
  int b = bh / Hh;
  int h = bh - b * Hh;
  int wv = threadIdx.x >> 6;       // 0..1
  int q0 = qb * 64;                // block window base
  int qA = q0 + wv * 32;           // tile A rows qA..qA+15; tile B +16
  int lane = threadIdx.x & 63;
  int lg = lane >> 4, lc = lane & 15;
  int lg4 = lg * 4;
  int qa = qA + lc, qbq = qA + 16 + lc;   // this lane's queries (A, B)

  const u16* qrowA = qpk + ((size_t)bh * Ss + qA + lc) * 64;
  bv8 aqA0 = *reinterpret_cast<const bv8*>(qrowA + lg * 8);
  bv8 aqA1 = *reinterpret_cast<const bv8*>(qrowA + 32 + lg * 8);
  const u16* qrowB = qrowA + 16 * 64;
  bv8 aqB0 = *reinterpret_cast<const bv8*>(qrowB + lg * 8);
  bv8 aqB1 = *reinterpret_cast<const bv8*>(qrowB + 32 + lg * 8);

  f32x4 oA[4], oB[4];
  #pragma unroll
  for (int i = 0; i < 4; ++i) { oA[i] = (f32x4){0.f,0.f,0.f,0.f}; oB[i] = (f32x4){0.f,0.f,0.f,0.f}; }
  float mrunA = -1e30f, lrunA = 0.f, mrunB = -1e30f, lrunB = 0.f;

  const u16* kgb = kg + ((size_t)bh) * 64 * 64;
  const u16* vgb = vgt + ((size_t)bh) * 64 * 64;
  const u16* kb = kpk + ((size_t)bh) * SPAD * 64;
  const u16* vb = vtpk + ((size_t)bh) * 64 * SPAD;
  const int* amb = amask + b * Ss;
  u16* PA = &Plds[wv * 2][0];
  u16* PB = &Plds[wv * 2 + 1][0];

  // preload K frags for step 0 (global keys)
  bv8 kc[8];
  #pragma unroll
  for (int j = 0; j < 4; ++j) {
    const u16* kr = kgb + (size_t)(j * 16 + lc) * 64;
    kc[2 * j]     = *reinterpret_cast<const bv8*>(kr + lg * 8);
    kc[2 * j + 1] = *reinterpret_cast<const bv8*>(kr + 32 + lg * 8);
  }
  // prefetch amask word for step 1
  int amvN;
  { int ni = min(max(q0 - 256 + lane, 0), Ss - 1); amvN = amb[ni]; }

  for (int step = 0; step < 10; ++step) {
    bool isg = (step == 0);
    int ks = isg ? 0 : (q0 - 256 + (step - 1) * 64);
    int amvC = amvN;
    if (step < 9) { int ni = min(max(q0 - 256 + step * 64 + lane, 0), Ss - 1); amvN = amb[ni]; }

    // V loads (shared by both tiles)
    bv8 vf0[4], vf1[4];
    #pragma unroll
    for (int nt = 0; nt < 4; ++nt) {
      const u16* vr = isg ? (vgb + (size_t)(nt * 16 + lc) * 64)
                          : (vb + (size_t)(nt * 16 + lc) * SPAD + PADL + ks);
      vf0[nt] = *reinterpret_cast<const bv8*>(vr + lg * 8);
      vf1[nt] = *reinterpret_cast<const bv8*>(vr + 32 + lg * 8);
    }
    // key-validity mask
    unsigned long long kmask;
    if (isg) {
      kmask = (1ull << Gg) - 1;
    } else {
      int kidx = ks + lane;
      kmask = __ballot((kidx >= 0) && (kidx < Ss) && (amvC > 0));
    }
    // QK^T swapped: scX[j] = scores for keys ks+j*16+lg4..+3, query (tile, lc)
    f32x4 scA[4], scB[4];
    __builtin_amdgcn_s_setprio(1);
    #pragma unroll
    for (int j = 0; j < 4; ++j) {
      f32x4 z = (f32x4){0.f, 0.f, 0.f, 0.f};
      scA[j] = __builtin_amdgcn_mfma_f32_16x16x32_bf16(kc[2 * j], aqA0, z, 0, 0, 0);
      scA[j] = __builtin_amdgcn_mfma_f32_16x16x32_bf16(kc[2 * j + 1], aqA1, scA[j], 0, 0, 0);
      scB[j] = __builtin_amdgcn_mfma_f32_16x16x32_bf16(kc[2 * j], aqB0, z, 0, 0, 0);
      scB[j] = __builtin_amdgcn_mfma_f32_16x16x32_bf16(kc[2 * j + 1], aqB1, scB[j], 0, 0, 0);
    }
    __builtin_amdgcn_s_setprio(0);
    // reload kc IN PLACE for next step (WAR; hides under softmax+PV)
    if (step < 9) {
      int ksn = q0 - 256 + step * 64;
      #pragma unroll
      for (int j = 0; j < 4; ++j) {
        const u16* kr = kb + (size_t)(PADL + ksn + j * 16 + lc) * 64;
        kc[2 * j]     = *reinterpret_cast<const bv8*>(kr + lg * 8);
        kc[2 * j + 1] = *reinterpret_cast<const bv8*>(kr + 32 + lg * 8);
      }
    }
    // masking: steps 2..8 with full kmask are band-safe for all 64 queries
    bool fast = (!isg) && (step >= 2) && (step <= 8) && (kmask == ~0ull);
    float mlocA = -1e30f, mlocB = -1e30f;
    if (fast) {
      #pragma unroll
      for (int j = 0; j < 4; ++j)
        #pragma unroll
        for (int r = 0; r < 4; ++r) {
          mlocA = fmaxf(mlocA, scA[j][r]);
          mlocB = fmaxf(mlocB, scB[j][r]);
        }
    } else {
      #pragma unroll
      for (int j = 0; j < 4; ++j)
        #pragma unroll
        for (int r = 0; r < 4; ++r) {
          int kk = ks + j * 16 + lg4 + r;
          bool okk = (kmask >> (j * 16 + lg4 + r)) & 1;
          bool okA = okk, okB = okk;
          if (!isg) {
            okA = okA && ((unsigned)(kk - qa + 256) <= 512u);
            okB = okB && ((unsigned)(kk - qbq + 256) <= 512u);
          }
          scA[j][r] = okA ? scA[j][r] : -1e9f;
          scB[j][r] = okB ? scB[j][r] : -1e9f;
          mlocA = fmaxf(mlocA, scA[j][r]);
          mlocB = fmaxf(mlocB, scB[j][r]);
        }
    }
    mlocA = fmaxf(mlocA, __shfl_xor(mlocA, 16));
    mlocA = fmaxf(mlocA, __shfl_xor(mlocA, 32));
    mlocB = fmaxf(mlocB, __shfl_xor(mlocB, 16));
    mlocB = fmaxf(mlocB, __shfl_xor(mlocB, 32));
    // defer-max: only rescale when max grows by > 8 for some query
    if (__any(mlocA > mrunA + 8.f)) {
      float nm = fmaxf(mrunA, mlocA);
      float scal = __expf(mrunA - nm);
      mrunA = nm;
      lrunA *= scal;
      #pragma unroll
      for (int r = 0; r < 4; ++r) {
        float sr = __shfl(scal, lg4 + r);
        #pragma unroll
        for (int nt = 0; nt < 4; ++nt) oA[nt][r] *= sr;
      }
    }
    if (__any(mlocB > mrunB + 8.f)) {
      float nm = fmaxf(mrunB, mlocB);
      float scal = __expf(mrunB - nm);
      mrunB = nm;
      lrunB *= scal;
      #pragma unroll
      for (int r = 0; r < 4; ++r) {
        float sr = __shfl(scal, lg4 + r);
        #pragma unroll
        for (int nt = 0; nt < 4; ++nt) oB[nt][r] *= sr;
      }
    }
    float psumA = 0.f, psumB = 0.f;
    #pragma unroll
    for (int j = 0; j < 4; ++j) {
      sv4 pkA, pkB;
      #pragma unroll
      for (int r = 0; r < 4; ++r) {
        float pA = __expf(scA[j][r] - mrunA);
        float pB = __expf(scB[j][r] - mrunB);
        psumA += pA; psumB += pB;
        pkA[r] = (short)f2bf(pA);
        pkB[r] = (short)f2bf(pB);
      }
      *reinterpret_cast<sv4*>(PA + lc * PSTR + j * 16 + lg4) = pkA;
      *reinterpret_cast<sv4*>(PB + lc * PSTR + j * 16 + lg4) = pkB;
    }
    psumA += __shfl_xor(psumA, 16);
    psumA += __shfl_xor(psumA, 32);
    psumB += __shfl_xor(psumB, 16);
    psumB += __shfl_xor(psumB, 32);
    lrunA += psumA;
    lrunB += psumB;
    // PV (V frags shared between tiles)
    __builtin_amdgcn_s_setprio(1);
    {
      bv8 apA = *reinterpret_cast<const bv8*>(PA + lc * PSTR + lg * 8);
      bv8 apB = *reinterpret_cast<const bv8*>(PB + lc * PSTR + lg * 8);
      #pragma unroll
      for (int nt = 0; nt < 4; ++nt) {
        oA[nt] = __builtin_amdgcn_mfma_f32_16x16x32_bf16(apA, vf0[nt], oA[nt], 0, 0, 0);
        oB[nt] = __builtin_amdgcn_mfma_f32_16x16x32_bf16(apB, vf0[nt], oB[nt], 0, 0, 0);
      }
      apA = *reinterpret_cast<const bv8*>(PA + lc * PSTR + 32 + lg * 8);
      apB = *reinterpret_cast<const bv8*>(PB + lc * PSTR + 32 + lg * 8);
      #pragma unroll
      for (int nt = 0; nt < 4; ++nt) {
        oA[nt] = __builtin_amdgcn_mfma_f32_16x16x32_bf16(apA, vf1[nt], oA[nt], 0, 0, 0);
        oB[nt] = __builtin_amdgcn_mfma_f32_16x16x32_bf16(apB, vf1[nt], oB[nt], 0, 0, 0);
      }
    }
    __builtin_amdgcn_s_setprio(0);
  }
  float invA = 1.0f / lrunA, invB = 1.0f / lrunB;
  #pragma unroll
  for (int r = 0; r < 4; ++r) {
    float invrA = __shfl(invA, lg4 + r);
    float invrB = __shfl(invB, lg4 + r);
    size_t rowA = ((size_t)b * Ss + qA + lg4 + r) * Dd + h * 64;
    size_t rowB = rowA + (size_t)16 * Dd;
    #pragma unroll
    for (int nt = 0; nt < 4; ++nt) {
      ctx[rowA + nt * 16 + lc] = f2bf(oA[nt][r] * invrA);
      ctx[rowB + nt * 16 + lc] = f2bf(oB[nt][r] * invrB);
    }
  }
}

// ---------------- global-query attention: lane-local flash MFMA -------------
__global__ __launch_bounds__(192)
void attn_globalq_kernel(const u16* __restrict__ qgb, const u16* __restrict__ kgf,
                         const u16* __restrict__ vgt, const int* __restrict__ amask,
                         float* __restrict__ part) {
  __shared__ u16 Plds[3][16 * PSTR];
  int blk = blockIdx.x;
  int ch = blk & (NCH - 1);
  int bh = blk / NCH;
  int b = bh / Hh, h = bh - b * Hh;
  int wv = threadIdx.x >> 6;  // q-tile 0..2
  int lane = threadIdx.x & 63;
  int lg = lane >> 4, lc = lane & 15;
  int lg4 = lg * 4;

  int qrow = wv * 16 + lc;
  bv8 aq0 = (bv8)0, aq1 = (bv8)0;
  if (qrow < Gg) {
    const u16* qr = qgb + (size_t)(b * Gg + qrow) * Dd + h * 64;
    aq0 = *reinterpret_cast<const bv8*>(qr + lg * 8);
    aq1 = *reinterpret_cast<const bv8*>(qr + 32 + lg * 8);
  }

  f32x4 o[4];
  #pragma unroll
  for (int i = 0; i < 4; ++i) o[i] = (f32x4){0.f, 0.f, 0.f, 0.f};
  float mrun = -1e30f, lrun = 0.f;

  const u16* kb = kgf + ((size_t)bh) * Ss * 64;
  const u16* vb = vgt + ((size_t)bh) * 64 * Ss;
  const int* amb = amask + b * Ss;
  int ks0 = ch * (Ss / NCH);
  u16* P = &Plds[wv][0];

  // preload K frags for step 0
  bv8 kc[8];
  #pragma unroll
  for (int j = 0; j < 4; ++j) {
    const u16* kr = kb + (size_t)(ks0 + j * 16 + lc) * 64;
    kc[2 * j]     = *reinterpret_cast<const bv8*>(kr + lg * 8);
    kc[2 * j + 1] = *reinterpret_cast<const bv8*>(kr + 32 + lg * 8);
  }

  for (int st = 0; st < 4; ++st) {
    int ks = ks0 + st * 64;
    // V loads
    bv8 vf0[4], vf1[4];
    #pragma unroll
    for (int nt = 0; nt < 4; ++nt) {
      const u16* vr = vb + (size_t)(nt * 16 + lc) * Ss + ks;
      vf0[nt] = *reinterpret_cast<const bv8*>(vr + lg * 8);
      vf1[nt] = *reinterpret_cast<const bv8*>(vr + 32 + lg * 8);
    }
    unsigned long long kmask = __ballot(amb[ks + lane] > 0);
    // QK^T swapped
    f32x4 sc[4];
    __builtin_amdgcn_s_setprio(1);
    #pragma unroll
    for (int j = 0; j < 4; ++j) {
      f32x4 z = (f32x4){0.f, 0.f, 0.f, 0.f};
      sc[j] = __builtin_amdgcn_mfma_f32_16x16x32_bf16(kc[2 * j], aq0, z, 0, 0, 0);
      sc[j] = __builtin_amdgcn_mfma_f32_16x16x32_bf16(kc[2 * j + 1], aq1, sc[j], 0, 0, 0);
    }
    __builtin_amdgcn_s_setprio(0);
    // reload kc for next step
    if (st < 3) {
      int ksn = ks0 + (st + 1) * 64;
      #pragma unroll
      for (int j = 0; j < 4; ++j) {
        const u16* kr = kb + (size_t)(ksn + j * 16 + lc) * 64;
        kc[2 * j]     = *reinterpret_cast<const bv8*>(kr + lg * 8);
        kc[2 * j + 1] = *reinterpret_cast<const bv8*>(kr + 32 + lg * 8);
      }
    }
    float mloc = -1e30f;
    if (kmask == ~0ull) {
      #pragma unroll
      for (int j = 0; j < 4; ++j)
        #pragma unroll
        for (int r = 0; r < 4; ++r) mloc = fmaxf(mloc, sc[j][r]);
    } else {
      #pragma unroll
      for (int j = 0; j < 4; ++j)
        #pragma unroll
        for (int r = 0; r < 4; ++r) {
          bool ok = (kmask >> (j * 16 + lg4 + r)) & 1;
          sc[j][r] = ok ? sc[j][r] : -1e9f;
          mloc = fmaxf(mloc, sc[j][r]);
        }
    }
    mloc = fmaxf(mloc, __shfl_xor(mloc, 16));
    mloc = fmaxf(mloc, __shfl_xor(mloc, 32));
    if (__any(mloc > mrun + 8.f)) {
      float nm = fmaxf(mrun, mloc);
      float scal = __expf(mrun - nm);
      mrun = nm;
      lrun *= scal;
      #pragma unroll
      for (int r = 0; r < 4; ++r) {
        float sr = __shfl(scal, lg4 + r);
        #pragma unroll
        for (int nt = 0; nt < 4; ++nt) o[nt][r] *= sr;
      }
    }
    float psum = 0.f;
    #pragma unroll
    for (int j = 0; j < 4; ++j) {
      sv4 pk;
      #pragma unroll
      for (int r = 0; r < 4; ++r) {
        float p = __expf(sc[j][r] - mrun);
        psum += p;
        pk[r] = (short)f2bf(p);
      }
      *reinterpret_cast<sv4*>(P + lc * PSTR + j * 16 + lg4) = pk;
    }
    psum += __shfl_xor(psum, 16);
    psum += __shfl_xor(psum, 32);
    lrun += psum;
    __builtin_amdgcn_s_setprio(1);
    {
      bv8 ap = *reinterpret_cast<const bv8*>(P + lc * PSTR + lg * 8);
      #pragma unroll
      for (int nt = 0; nt < 4; ++nt)
        o[nt] = __builtin_amdgcn_mfma_f32_16x16x32_bf16(ap, vf0[nt], o[nt], 0, 0, 0);
      ap = *reinterpret_cast<const bv8*>(P + lc * PSTR + 32 + lg * 8);
      #pragma unroll
      for (int nt = 0; nt < 4; ++nt)
        o[nt] = __builtin_amdgcn_mfma_f32_16x16x32_bf16(ap, vf1[nt], o[nt], 0, 0, 0);
    }
    __builtin_amdgcn_s_setprio(0);
  }

  float* pb = part + ((size_t)(bh * 3 + wv) * NCH + ch) * PARTF;
  #pragma unroll
  for (int r = 0; r < 4; ++r) {
    int row = lg4 + r;
    #pragma unroll
    for (int nt = 0; nt < 4; ++nt)
      pb[row * 64 + nt * 16 + lc] = o[nt][r];
  }
  if (lg == 0) {
    pb[1024 + lc] = mrun;
    pb[1040 + lc] = lrun;
  }
}

// merge NCH chunk-partials and scatter into ctx rows at gpos
__global__ __launch_bounds__(256)
void attn_gmerge_kernel(const float* __restrict__ part, const int* __restrict__ gpos,
                        u16* __restrict__ ctx) {
  __shared__ float wgt[Gg][NCH];
  __shared__ float sinvl[Gg];
  int bh = blockIdx.x;
  int b = bh / Hh, h = bh - b * Hh;
  int tid = threadIdx.x;
  if (tid < Gg) {
    int qt = tid >> 4, rr = tid & 15;
    const float* pb = part + ((size_t)(bh * 3 + qt) * NCH) * PARTF;
    float mx = -1e30f;
    for (int c = 0; c < NCH; ++c) mx = fmaxf(mx, pb[c * PARTF + 1024 + rr]);
    float l = 0.f;
    for (int c = 0; c < NCH; ++c) {
      float w = __expf(pb[c * PARTF + 1024 + rr] - mx);
      wgt[tid][c] = w;
      l += w * pb[c * PARTF + 1040 + rr];
    }
    sinvl[tid] = 1.0f / l;
  }
  __syncthreads();
  for (int e = tid; e < Gg * 64; e += 256) {
    int row = e >> 6, d = e & 63;
    int qt = row >> 4, rr = row & 15;
    const float* pb = part + ((size_t)(bh * 3 + qt) * NCH) * PARTF + rr * 64 + d;
    float acc = 0.f;
    #pragma unroll
    for (int c = 0; c < NCH; ++c) acc += wgt[row][c] * pb[c * PARTF];
    int pos = gpos[b * Gg + row];
    ctx[((size_t)b * Ss + pos) * Dd + h * 64 + d] = f2bf(acc * sinvl[row]);
  }
}

// ---------------- classifier ------------------------------------------------
__global__ __launch_bounds__(64)
void cls_kernel(const float* __restrict__ x, const float* __restrict__ W,
                const float* __restrict__ bias, const int* __restrict__ gpos,
                float* __restrict__ out) {
  int r = blockIdx.x;  // b*32 + i
  int b = r >> 5, i = r & 31;
  int pos = gpos[b * Gg + 1 + i];
  int lane = threadIdx.x;
  const float* xr = x + ((size_t)b * Ss + pos) * Dd;
  float acc[NCLSn] = {0.f, 0.f, 0.f, 0.f, 0.f};
  for (int k = lane; k < Dd; k += 64) {
    float xv = xr[k];
    #pragma unroll
    for (int c = 0; c < NCLSn; ++c) acc[c] += xv * W[c * Dd + k];
  }
  #pragma unroll
  for (int c = 0; c < NCLSn; ++c) {
    #pragma unroll
    for (int off = 1; off < 64; off <<= 1) acc[c] += __shfl_xor(acc[c], off);
  }
  if (lane == 0) {
    #pragma unroll
    for (int c = 0; c < NCLSn; ++c) out[r * NCLSn + c] = acc[c] + bias[c];
  }
}

// ---------------------------------------------------------------------------
extern "C" void kernel_launch(void* const* d_in, const int* in_sizes, int n_in,
                              void* d_out, int out_size, void* d_ws, size_t ws_size,
                              hipStream_t stream) {
  const int* ids     = (const int*)d_in[0];
  const int* amask   = (const int*)d_in[1];
  const float* we    = (const float*)d_in[2];
  const float* pe    = (const float*)d_in[3];
  const float* te    = (const float*)d_in[4];
  const float* embln = (const float*)d_in[5];
  const float* Wqkv  = (const float*)d_in[6];
  const float* bqkv  = (const float*)d_in[7];
  const float* Wqkvg = (const float*)d_in[8];
  const float* bqkvg = (const float*)d_in[9];
  const float* Wo    = (const float*)d_in[10];
  const float* bo    = (const float*)d_in[11];
  const float* ln1   = (const float*)d_in[12];
  const float* Wff1  = (const float*)d_in[13];
  const float* bff1  = (const float*)d_in[14];
  const float* Wff2  = (const float*)d_in[15];
  const float* bff2  = (const float*)d_in[16];
  const float* ln2   = (const float*)d_in[17];
  const float* clsW  = (const float*)d_in[18];
  const float* clsb  = (const float*)d_in[19];
  float* out = (float*)d_out;

  char* ws = (char*)d_ws;
  size_t off = 0;
  auto alloc = [&](size_t bytes) { size_t o = off; off += (bytes + 255) & ~(size_t)255; return o; };

  const size_t DD = (size_t)Dd * Dd;        // 589824
  const size_t DF = (size_t)Dd * 4 * Dd;    // 2359296
  const size_t WL = 7 * DD + 2 * DF;        // elems per layer
  // Wb layout per layer: [q,k,v, gk,gv, gq, wo, ff1, ff2]

  size_t o_cnt  = alloc(Bb * 4);
  size_t o_list = alloc(Bb * 64 * 4);
  size_t o_gpos = alloc(Bb * Gg * 4);
  size_t o_bias = alloc((size_t)Ll * 3840 * 4);
  size_t o_w    = alloc(WL * Ll * 2);
  size_t o_x    = alloc((size_t)Bb * Ss * Dd * 4);
  size_t o_xb   = alloc((size_t)Bb * Ss * Dd * 2);
  // kgf/vgf first: their 25.17 MB doubles as split-K bf16 buffer B
  size_t o_kgf  = alloc((size_t)Bb * Hh * Ss * 64 * 2);
  size_t o_vgf  = alloc((size_t)Bb * Hh * Ss * 64 * 2);
  size_t o_accB = o_kgf;  // bf16 half-B: 8192*768*2 bytes fits in kgf alone
  size_t o_qpk  = alloc((size_t)Bb * Hh * Ss * 64 * 2);
  size_t o_kpk  = alloc((size_t)Bb * Hh * SPAD * 64 * 2);
  size_t o_vtpk = alloc((size_t)Bb * Hh * 64 * SPAD * 2);
  size_t o_kg   = alloc((size_t)Bb * Hh * 64 * 64 * 2);
  size_t o_vgt  = alloc((size_t)Bb * Hh * 64 * 64 * 2);
  size_t o_xg   = alloc((size_t)128 * Dd * 2);
  size_t o_qg   = alloc((size_t)128 * Dd * 2);
  size_t o_part = alloc((size_t)Bb * Hh * 3 * NCH * PARTF * 4);
  size_t o_f1b  = o_qpk;  // FFN hidden aliases the (dead-by-then) attention buffers
  {
    size_t f1b_bytes = (size_t)Bb * Ss * 4 * Dd * 2;
    if (off - o_qpk < f1b_bytes) off = o_qpk + ((f1b_bytes + 255) & ~(size_t)255);
  }
  size_t o_ctx = alloc((size_t)Bb * Ss * Dd * 2);
  size_t o_acc = alloc((size_t)Bb * Ss * Dd * 4);
  if (ws_size < off) return;  // workspace too small -> fail visibly

  u16* Wb = (u16*)(ws + o_w);
  int* gposp = (int*)(ws + o_gpos);
  float* accA = (float*)(ws + o_acc);
  u16* accB = (u16*)(ws + o_accB);

  (void)hipMemsetAsync(ws + o_cnt, 0, Bb * 4, stream);
  // zero padded K / V^T so first-call pads are finite (later calls: finite stale bf16)
  (void)hipMemsetAsync(ws + o_kpk, 0, (size_t)Bb * Hh * SPAD * 64 * 2, stream);
  (void)hipMemsetAsync(ws + o_vtpk, 0, (size_t)Bb * Hh * 64 * SPAD * 2, stream);
  (void)hipMemsetAsync(ws + o_xg, 0, (size_t)128 * Dd * 2, stream);

  // concat bias per layer: [bqkv(3x768) | bqkvg_k(768) | bqkvg_v(768)]
  for (int l = 0; l < Ll; ++l) {
    (void)hipMemcpyAsync(ws + o_bias + (size_t)l * 3840 * 4, bqkv + (size_t)l * 3 * Dd,
                         3 * Dd * 4, hipMemcpyDeviceToDevice, stream);
    (void)hipMemcpyAsync(ws + o_bias + (size_t)l * 3840 * 4 + 3 * Dd * 4,
                         bqkvg + (size_t)(l * 3 + 1) * Dd,
                         2 * Dd * 4, hipMemcpyDeviceToDevice, stream);
  }

  sep_find_kernel<<<(Bb * Ss + 255) / 256, 256, 0, stream>>>(ids, (int*)(ws + o_cnt), (int*)(ws + o_list));
  sep_sort_kernel<<<Bb, 64, 0, stream>>>((int*)(ws + o_cnt), (int*)(ws + o_list), gposp);

  // weight conversions (batched over z); Wb layout [q,k,v,gk,gv,gq,wo,ff1,ff2]
  wconv_kernel<<<dim3(24, 24, 6), 256, 0, stream>>>(Wqkv,       Wb,          Dd, Dd, 3, 3, (long)DD, (long)WL);
  wconv_kernel<<<dim3(24, 24, 2), 256, 0, stream>>>(Wqkvg + DD,     Wb + 3 * DD, Dd, Dd, 1, 3, 0L, (long)WL);  // gk
  wconv_kernel<<<dim3(24, 24, 2), 256, 0, stream>>>(Wqkvg + 2 * DD, Wb + 4 * DD, Dd, Dd, 1, 3, 0L, (long)WL);  // gv
  wconv_kernel<<<dim3(24, 24, 2), 256, 0, stream>>>(Wqkvg,          Wb + 5 * DD, Dd, Dd, 1, 3, 0L, (long)WL);  // gq
  wconv_kernel<<<dim3(24, 24, 2), 256, 0, stream>>>(Wo,         Wb + 6 * DD, Dd, Dd, 1, 1, 0L, (long)WL);
  wconv_kernel<<<dim3(96, 24, 2), 256, 0, stream>>>(Wff1,       Wb + 7 * DD, Dd, 4 * Dd, 1, 1, 0L, (long)WL);
  wconv_kernel<<<dim3(24, 96, 2), 256, 0, stream>>>(Wff2,       Wb + 7 * DD + DF, 4 * Dd, Dd, 1, 1, 0L, (long)WL);

  embed_ln_kernel<<<Bb * Ss, 256, 0, stream>>>(ids, we, pe, te, embln, (float*)(ws + o_x), (u16*)(ws + o_xb));

  for (int l = 0; l < Ll; ++l) {
    size_t wb = (size_t)l * WL;
    u16* xb = (u16*)(ws + o_xb);
    // fused QKV + global K/V projection (N=3840, 5 sections); grid 1920 %8==0
    gemm2_kernel<2, true><<<dim3(30, 64), 256, 0, stream>>>(xb, Wb + wb, (float*)(ws + o_bias) + (size_t)l * 3840,
        nullptr,
        (u16*)(ws + o_qpk), (u16*)(ws + o_kpk), (u16*)(ws + o_vtpk),
        (u16*)(ws + o_kgf), (u16*)(ws + o_vgf), 3840, Dd, Dd, 0.125f);
    gather_glob_kernel<<<Bb * Hh, 256, 0, stream>>>((u16*)(ws + o_kpk), (u16*)(ws + o_vtpk), gposp, (u16*)(ws + o_kg), (u16*)(ws + o_vgt));
    gather_xg_kernel<<<Bb * Gg, 256, 0, stream>>>(xb, gposp, (u16*)(ws + o_xg));
    // global q projection (M=128 padded rows); 6 blocks -> no XCD swizzle
    gemm2_kernel<4, false><<<dim3(6, 1), 256, 0, stream>>>((u16*)(ws + o_xg), Wb + wb + 5 * DD, bqkvg + (size_t)l * 3 * Dd,
        nullptr, (u16*)(ws + o_qg), nullptr, nullptr, nullptr, nullptr, Dd, Dd, Dd, 0.125f);
    // attention
    attn_local_kernel<<<LOCAL_NB, 128, 0, stream>>>((u16*)(ws + o_qpk), (u16*)(ws + o_kpk), (u16*)(ws + o_vtpk), (u16*)(ws + o_kg), (u16*)(ws + o_vgt), amask, (u16*)(ws + o_ctx));
    attn_globalq_kernel<<<Bb * Hh * NCH, 192, 0, stream>>>((u16*)(ws + o_qg), (u16*)(ws + o_kgf), (u16*)(ws + o_vgf), amask, (float*)(ws + o_part));
    attn_gmerge_kernel<<<Bb * Hh, 256, 0, stream>>>((float*)(ws + o_part), gposp, (u16*)(ws + o_ctx));
    // output projection (split-K x2, half-B bf16) + LN  [kgf/vgf dead now]
    gemm2_kernel<0, true><<<dim3(6, 64, 2), 256, 0, stream>>>((u16*)(ws + o_ctx), Wb + wb + 6 * DD, bo + (size_t)l * Dd, accA,
        accB, nullptr, nullptr, nullptr, nullptr, Dd, Dd, Dd / 2, 1.0f);
    add_ln3_kernel<<<Bb * Ss, 256, 0, stream>>>((float*)(ws + o_x), accA, accB, ln1 + (size_t)l * 2 * Dd, (float*)(ws + o_x), xb);
    // FFN
    gemm2_kernel<1, true><<<dim3(24, 64), 256, 0, stream>>>(xb, Wb + wb + 7 * DD, bff1 + (size_t)l * 4 * Dd, nullptr,
        (u16*)(ws + o_f1b), nullptr, nullptr, nullptr, nullptr, 4 * Dd, Dd, Dd, 1.0f);
    gemm2_kernel<0, true><<<dim3(6, 64, 2), 256, 0, stream>>>((u16*)(ws + o_f1b), Wb + wb + 7 * DD + DF, bff2 + (size_t)l * Dd, accA,
        accB, nullptr, nullptr, nullptr, nullptr, Dd, 4 * Dd, 2 * Dd, 1.0f);
    add_ln3_kernel<<<Bb * Ss, 256, 0, stream>>>((float*)(ws + o_x), accA, accB, ln2 + (size_t)l * 2 * Dd, (float*)(ws + o_x), xb);
  }

  cls_kernel<<<Bb * NSEPn, 64, 0, stream>>>((float*)(ws + o_x), clsW, clsb, gposp, out);
}

// Round 13
// 760.686 us; speedup vs baseline: 1.2262x; 1.0212x over previous
//
#include <hip/hip_runtime.h>

// ---------------------------------------------------------------------------
// Longformer (2-layer) forward, MI355X.
// R12: replace per-call hipMemsetAsync (28.5MB -> showed as 87us/603MB fill
//      dispatch) + bias-concat memcpies with one tiny setup_kernel that
//      zeroes ONLY the K/V pad regions (3.3MB) and builds the bias buffer.
// ---------------------------------------------------------------------------

#define Bb 2
#define Ss 4096
#define Dd 768
#define Hh 12
#define Gg 33
#define NSEPn 32
#define Ll 2
#define SPAD 4640   // S + 544 (PADL=256 left, 288 right)
#define PADL 256
#define NCLSn 5
#define NCH 16      // key chunks for global-q attention (256 keys each)
#define PARTF 1056  // floats per (bh,qt,chunk) partial: 16*64 o + 16 m + 16 l
#define PSTR 72     // Plds row stride in u16 (144B: 16B-aligned, bank-spread)

typedef unsigned short u16;
typedef __attribute__((ext_vector_type(8))) short bv8;   // 8 x bf16
typedef __attribute__((ext_vector_type(4))) short sv4;   // 4 x bf16
typedef __attribute__((ext_vector_type(4))) float f32x4;

__device__ __forceinline__ float bf2f(u16 u) {
  unsigned v = ((unsigned)u) << 16;
  return __builtin_bit_cast(float, v);
}
__device__ __forceinline__ u16 f2bf(float f) {
  unsigned u = __builtin_bit_cast(unsigned, f);
  u += 0x7fffu + ((u >> 16) & 1u);
  return (u16)(u >> 16);
}
__device__ __forceinline__ void glds16(const void* g, void* l) {
  __builtin_amdgcn_global_load_lds(
      (const __attribute__((address_space(1))) void*)g,
      (__attribute__((address_space(3))) void*)l, 16, 0, 0);
}

// ---------------- setup: cnt=0, K/V pad rows = 0, bias concat ---------------
__global__ __launch_bounds__(256)
void setup_kernel(int* __restrict__ cnt, u16* __restrict__ kpk,
                  u16* __restrict__ vtpk, const float* __restrict__ bqkv,
                  const float* __restrict__ bqkvg, float* __restrict__ biasc) {
  int tid = blockIdx.x * 256 + threadIdx.x;
  if (tid < Bb) cnt[tid] = 0;
  if (tid < Ll * 3840) {
    int l = tid / 3840, c = tid - l * 3840;
    float v = (c < 2304) ? bqkv[l * 2304 + c]
                         : bqkvg[(l * 3 + 1) * Dd + (c - 2304)];
    biasc[tid] = v;
  }
  const int PADW = SPAD - Ss;                 // 544 pad rows per bh
  const int total = Bb * Hh * PADW * 64;      // 835584 elems per buffer
  for (int i = tid; i < total; i += gridDim.x * 256) {
    int bh = i / (PADW * 64);
    int rem = i - bh * (PADW * 64);
    int prow = rem >> 6, d = rem & 63;
    int row = (prow < PADL) ? prow : (Ss + prow);  // [0,PADL) U [PADL+Ss,SPAD)
    kpk[((size_t)bh * SPAD + row) * 64 + d] = 0;
    vtpk[((size_t)bh * 64 + d) * SPAD + row] = 0;
  }
}

// ---------------- sep finding --------------------------------------------
__global__ void sep_find_kernel(const int* __restrict__ ids, int* __restrict__ cnt,
                                int* __restrict__ list) {
  int i = blockIdx.x * 256 + threadIdx.x;
  if (i >= Bb * Ss) return;
  int b = i >> 12;
  if (ids[i] == 2) {
    int idx = atomicAdd(&cnt[b], 1);
    if (idx < 64) list[b * 64 + idx] = i & (Ss - 1);
  }
}

__global__ void sep_sort_kernel(const int* __restrict__ cnt, const int* __restrict__ list,
                                int* __restrict__ gpos) {
  int b = blockIdx.x;
  int t = threadIdx.x;
  int n = cnt[b]; if (n > 64) n = 64;
  if (t < Gg) gpos[b * Gg + t] = (t == 0) ? 0 : (Ss - 1);
  __syncthreads();
  if (t < n) {
    int v = list[b * 64 + t];
    int rank = 0;
    for (int j = 0; j < n; ++j) rank += (list[b * 64 + j] < v) ? 1 : 0;
    if (rank < NSEPn) gpos[b * Gg + 1 + rank] = v;
  }
}

// ------- weight fp32 (K,N) -> bf16 (N,K), batched; src slice (z/grp)*sstr+z%grp
__global__ __launch_bounds__(256)
void wconv_kernel(const float* __restrict__ src0, u16* __restrict__ dst0,
                  int K, int N, int grp, int sstr, long unit, long WLs) {
  __shared__ float t[32][33];
  int z = blockIdx.z;
  const float* src = src0 + (size_t)((z / grp) * sstr + (z % grp)) * K * N;
  u16* dst = dst0 + (size_t)(z / grp) * WLs + (size_t)(z % grp) * unit;
  int n0 = blockIdx.x * 32, k0 = blockIdx.y * 32;
  int tx = threadIdx.x & 31, ty = threadIdx.x >> 5;  // ty 0..7
  #pragma unroll
  for (int i = 0; i < 4; ++i)
    t[ty + i * 8][tx] = src[(size_t)(k0 + ty + i * 8) * N + n0 + tx];
  __syncthreads();
  #pragma unroll
  for (int i = 0; i < 4; ++i)
    dst[(size_t)(n0 + ty + i * 8) * K + k0 + tx] = f2bf(t[tx][ty + i * 8]);
}

// ---------------- embedding + LN -------------------------------------------
__global__ __launch_bounds__(256)
void embed_ln_kernel(const int* __restrict__ ids, const float* __restrict__ we,
                     const float* __restrict__ pe, const float* __restrict__ te,
                     const float* __restrict__ lnp, float* __restrict__ x,
                     u16* __restrict__ xb) {
  int row = blockIdx.x;
  int s = row & (Ss - 1);
  int id = ids[row];
  int tid = threadIdx.x;
  float v[3]; float sm = 0.f, s2 = 0.f;
  #pragma unroll
  for (int i = 0; i < 3; ++i) {
    int c = tid + i * 256;
    float t = we[(size_t)id * Dd + c] + pe[(size_t)(s + 2) * Dd + c] + te[c];
    v[i] = t; sm += t; s2 += t * t;
  }
  __shared__ float r1[256], r2[256];
  r1[tid] = sm; r2[tid] = s2; __syncthreads();
  for (int o = 128; o; o >>= 1) {
    if (tid < o) { r1[tid] += r1[tid + o]; r2[tid] += r2[tid + o]; }
    __syncthreads();
  }
  float mean = r1[0] * (1.f / 768.f);
  float var  = r2[0] * (1.f / 768.f) - mean * mean;
  float rs = rsqrtf(var + 1e-5f);
  #pragma unroll
  for (int i = 0; i < 3; ++i) {
    int c = tid + i * 256;
    float o = (v[i] - mean) * rs * lnp[c] + lnp[Dd + c];
    x[(size_t)row * Dd + c] = o;
    xb[(size_t)row * Dd + c] = f2bf(o);
  }
}

// ---------------- residual(2 fp32 + 1 bf16) + LN ----------------------------
__global__ __launch_bounds__(256)
void add_ln3_kernel(const float* __restrict__ xin, const float* __restrict__ y0,
                    const u16* __restrict__ y1, const float* __restrict__ lnp,
                    float* __restrict__ xout, u16* __restrict__ xbout) {
  int row = blockIdx.x;
  int tid = threadIdx.x;
  float v[3]; float sm = 0.f, s2 = 0.f;
  #pragma unroll
  for (int i = 0; i < 3; ++i) {
    int c = tid + i * 256;
    size_t idx = (size_t)row * Dd + c;
    float t = xin[idx] + y0[idx] + bf2f(y1[idx]);
    v[i] = t; sm += t; s2 += t * t;
  }
  __shared__ float r1[256], r2[256];
  r1[tid] = sm; r2[tid] = s2; __syncthreads();
  for (int o = 128; o; o >>= 1) {
    if (tid < o) { r1[tid] += r1[tid + o]; r2[tid] += r2[tid + o]; }
    __syncthreads();
  }
  float mean = r1[0] * (1.f / 768.f);
  float var  = r2[0] * (1.f / 768.f) - mean * mean;
  float rs = rsqrtf(var + 1e-5f);
  #pragma unroll
  for (int i = 0; i < 3; ++i) {
    int c = tid + i * 256;
    float o = (v[i] - mean) * rs * lnp[c] + lnp[Dd + c];
    xout[(size_t)row * Dd + c] = o;
    xbout[(size_t)row * Dd + c] = f2bf(o);
  }
}

// ---------------- GEMM2: 128x128 2-buffer + T2 LDS swizzle + T1 XCD swizzle -
// MODE 0: split-K: z==0 -> fp32 outf (+bias); z==1 -> bf16 o0 (no bias)
// MODE 1: bf16 [M][N], exact gelu
// MODE 2: fused QKV+gKV: N=3840; secs: q pk / k pad / v^T pad / gk pk / gv^T
// MODE 4: bf16 [M][N] * scale
template <int MODE, bool XSWZ>
__global__ __launch_bounds__(256)
void gemm2_kernel(const u16* __restrict__ A, const u16* __restrict__ Bt,
                  const float* __restrict__ bias, float* __restrict__ outf,
                  u16* __restrict__ o0, u16* __restrict__ o1, u16* __restrict__ o2,
                  u16* __restrict__ o3, u16* __restrict__ o4,
                  int N, int Ks, int Kl, float scale) {
  __shared__ u16 la[2][128 * 32], lb[2][128 * 32];
  int tid = threadIdx.x;
  int wave = tid >> 6, lane = tid & 63;
  int wr = wave >> 1, wc = wave & 1;
  int lg = lane >> 4, lc = lane & 15;
  // T1: XCD-aware bijective remap of the x-y plane (requires NB % 8 == 0)
  int bx = blockIdx.x, by = blockIdx.y;
  if (XSWZ) {
    int gx = gridDim.x;
    int nlin = bx + gx * by;
    int NB = gx * gridDim.y;
    nlin = (nlin & 7) * (NB >> 3) + (nlin >> 3);
    bx = nlin % gx;
    by = nlin / gx;
  }
  int row0 = by * 128, col0 = bx * 128;
  int koff = blockIdx.z * Kl;

  // T2 swizzle: linear LDS dest; lane fetches logical granule (l&3)^((l>>3)&3)
  int sgr = (lane & 3) ^ ((lane >> 3) & 3);
  const u16* Ag = A + (size_t)(row0 + wave * 32 + (lane >> 2)) * Ks + sgr * 8 + koff;
  const u16* Bg = Bt + (size_t)(col0 + wave * 32 + (lane >> 2)) * Ks + sgr * 8 + koff;
  int wofs = wave * 1024;
  int gph = (lg ^ ((lc >> 1) & 3)) * 8;   // swizzled read granule offset (u16)

  f32x4 acc[4][4];
  #pragma unroll
  for (int m = 0; m < 4; ++m)
    #pragma unroll
    for (int n = 0; n < 4; ++n) acc[m][n] = (f32x4){0.f, 0.f, 0.f, 0.f};

  glds16(Ag, la[0] + wofs);
  glds16(Ag + (size_t)16 * Ks, la[0] + wofs + 512);
  glds16(Bg, lb[0] + wofs);
  glds16(Bg + (size_t)16 * Ks, lb[0] + wofs + 512);
  __syncthreads();

  int nk = Kl >> 5;
  for (int t = 0; t < nk; ++t) {
    int cur = t & 1;
    if (t + 1 < nk) {
      int k1 = (t + 1) << 5;
      glds16(Ag + k1, la[cur ^ 1] + wofs);
      glds16(Ag + (size_t)16 * Ks + k1, la[cur ^ 1] + wofs + 512);
      glds16(Bg + k1, lb[cur ^ 1] + wofs);
      glds16(Bg + (size_t)16 * Ks + k1, lb[cur ^ 1] + wofs + 512);
    }
    bv8 af[4], bf_[4];
    #pragma unroll
    for (int m = 0; m < 4; ++m)
      af[m] = *reinterpret_cast<const bv8*>(la[cur] + (wr * 64 + m * 16 + lc) * 32 + gph);
    #pragma unroll
    for (int n = 0; n < 4; ++n)
      bf_[n] = *reinterpret_cast<const bv8*>(lb[cur] + (wc * 64 + n * 16 + lc) * 32 + gph);
    __builtin_amdgcn_s_setprio(1);
    #pragma unroll
    for (int m = 0; m < 4; ++m)
      #pragma unroll
      for (int n = 0; n < 4; ++n)
        acc[m][n] = __builtin_amdgcn_mfma_f32_16x16x32_bf16(af[m], bf_[n], acc[m][n], 0, 0, 0);
    __builtin_amdgcn_s_setprio(0);
    __syncthreads();
  }

  #pragma unroll
  for (int m = 0; m < 4; ++m) {
    int grow0 = row0 + wr * 64 + m * 16 + lg * 4;
    #pragma unroll
    for (int n = 0; n < 4; ++n) {
      int gcol = col0 + wc * 64 + n * 16 + lc;
      float bvl = bias[gcol];
      if (MODE == 0) {
        if (blockIdx.z == 0) {
          #pragma unroll
          for (int r = 0; r < 4; ++r)
            outf[(size_t)(grow0 + r) * N + gcol] = acc[m][n][r] + bvl;
        } else {
          #pragma unroll
          for (int r = 0; r < 4; ++r)
            o0[(size_t)(grow0 + r) * N + gcol] = f2bf(acc[m][n][r]);
        }
      } else if (MODE == 1) {
        #pragma unroll
        for (int r = 0; r < 4; ++r) {
          float v = acc[m][n][r] + bvl;
          v = 0.5f * v * (1.0f + erff(v * 0.70710678118654752f));
          o0[(size_t)(grow0 + r) * N + gcol] = f2bf(v);
        }
      } else if (MODE == 4) {
        #pragma unroll
        for (int r = 0; r < 4; ++r)
          o0[(size_t)(grow0 + r) * N + gcol] = f2bf((acc[m][n][r] + bvl) * scale);
      } else if (MODE == 2) {
        int sec = (col0 >> 7) / 6;        // 0..4, block-uniform
        int colr = gcol - sec * 768;
        int hh = colr >> 6, d = colr & 63;
        int bb = grow0 >> 12, s = grow0 & (Ss - 1);
        size_t bhh = (size_t)(bb * Hh + hh);
        if (sec == 0) {
          #pragma unroll
          for (int r = 0; r < 4; ++r)
            o0[(bhh * Ss + s + r) * 64 + d] = f2bf((acc[m][n][r] + bvl) * scale);
        } else if (sec == 1) {
          #pragma unroll
          for (int r = 0; r < 4; ++r)
            o1[(bhh * SPAD + PADL + s + r) * 64 + d] = f2bf(acc[m][n][r] + bvl);
        } else if (sec == 2) {
          sv4 pk;
          #pragma unroll
          for (int r = 0; r < 4; ++r) pk[r] = (short)f2bf(acc[m][n][r] + bvl);
          *reinterpret_cast<sv4*>(o2 + (bhh * 64 + d) * SPAD + PADL + s) = pk;
        } else if (sec == 3) {
          #pragma unroll
          for (int r = 0; r < 4; ++r)
            o3[(bhh * Ss + s + r) * 64 + d] = f2bf(acc[m][n][r] + bvl);
        } else {
          sv4 pk;
          #pragma unroll
          for (int r = 0; r < 4; ++r) pk[r] = (short)f2bf(acc[m][n][r] + bvl);
          *reinterpret_cast<sv4*>(o4 + (bhh * 64 + d) * Ss + s) = pk;
        }
      }
    }
  }
}

// ---------------- gathers ---------------------------------------------------
__global__ __launch_bounds__(256)
void gather_glob_kernel(const u16* __restrict__ kpk, const u16* __restrict__ vtpk,
                        const int* __restrict__ gpos, u16* __restrict__ kg,
                        u16* __restrict__ vgt) {
  int bh = blockIdx.x;
  int b = bh / Hh;
  int tid = threadIdx.x;
  for (int idx = tid; idx < 64 * 64; idx += 256) {
    int g = idx >> 6, d = idx & 63;
    u16 kv = 0, vv = 0;
    if (g < Gg) {
      int p = gpos[b * Gg + g];
      kv = kpk[((size_t)bh * SPAD + PADL + p) * 64 + d];
      vv = vtpk[((size_t)bh * 64 + d) * SPAD + PADL + p];
    }
    kg[(size_t)bh * 4096 + idx] = kv;
    vgt[((size_t)bh * 64 + d) * 64 + g] = vv;
  }
}

__global__ __launch_bounds__(256)
void gather_xg_kernel(const u16* __restrict__ xb, const int* __restrict__ gpos,
                      u16* __restrict__ xg) {
  int rg = blockIdx.x;  // b*G+g
  int b = rg / Gg;
  int p = gpos[rg];
  int tid = threadIdx.x;
  for (int c = tid; c < Dd; c += 256)
    xg[(size_t)rg * Dd + c] = xb[((size_t)b * Ss + p) * Dd + c];
}

// ---------------- local (sliding window + global-key) attention -------------
// 2 waves/block, 2 q-tiles/wave (64 queries/block). Swapped QK^T, ballot mask,
// defer-max (THR=8). Per-step scalar overhead amortized over 32 queries/wave.
#define LOCAL_NB (Bb * Hh * (Ss / 64))   // 1536 blocks, %8 == 0
__global__ __launch_bounds__(128)
void attn_local_kernel(const u16* __restrict__ qpk, const u16* __restrict__ kpk,
                       const u16* __restrict__ vtpk, const u16* __restrict__ kg,
                       const u16* __restrict__ vgt, const int* __restrict__ amask,
                       u16* __restrict__ ctx) {
  __shared__ u16 Plds[4][16 * PSTR];
  int bid = blockIdx.x;
  int swz = (bid & 7) * (LOCAL_NB / 8) + (bid >> 3);
  int qb = swz & 63;
  int bh = swz >> 6;
  int b = bh / Hh;
  int h = bh - b * Hh;
  int wv = threadIdx.x >> 6;       // 0..1
  int q0 = qb * 64;                // block window base
  int qA = q0 + wv * 32;           // tile A rows qA..qA+15; tile B +16
  int lane = threadIdx.x & 63;
  int lg = lane >> 4, lc = lane & 15;
  int lg4 = lg * 4;
  int qa = qA + lc, qbq = qA + 16 + lc;   // this lane's queries (A, B)

  const u16* qrowA = qpk + ((size_t)bh * Ss + qA + lc) * 64;
  bv8 aqA0 = *reinterpret_cast<const bv8*>(qrowA + lg * 8);
  bv8 aqA1 = *reinterpret_cast<const bv8*>(qrowA + 32 + lg * 8);
  const u16* qrowB = qrowA + 16 * 64;
  bv8 aqB0 = *reinterpret_cast<const bv8*>(qrowB + lg * 8);
  bv8 aqB1 = *reinterpret_cast<const bv8*>(qrowB + 32 + lg * 8);

  f32x4 oA[4], oB[4];
  #pragma unroll
  for (int i = 0; i < 4; ++i) { oA[i] = (f32x4){0.f,0.f,0.f,0.f}; oB[i] = (f32x4){0.f,0.f,0.f,0.f}; }
  float mrunA = -1e30f, lrunA = 0.f, mrunB = -1e30f, lrunB = 0.f;

  const u16* kgb = kg + ((size_t)bh) * 64 * 64;
  const u16* vgb = vgt + ((size_t)bh) * 64 * 64;
  const u16* kb = kpk + ((size_t)bh) * SPAD * 64;
  const u16* vb = vtpk + ((size_t)bh) * 64 * SPAD;
  const int* amb = amask + b * Ss;
  u16* PA = &Plds[wv * 2][0];
  u16* PB = &Plds[wv * 2 + 1][0];

  // preload K frags for step 0 (global keys)
  bv8 kc[8];
  #pragma unroll
  for (int j = 0; j < 4; ++j) {
    const u16* kr = kgb + (size_t)(j * 16 + lc) * 64;
    kc[2 * j]     = *reinterpret_cast<const bv8*>(kr + lg * 8);
    kc[2 * j + 1] = *reinterpret_cast<const bv8*>(kr + 32 + lg * 8);
  }
  // prefetch amask word for step 1
  int amvN;
  { int ni = min(max(q0 - 256 + lane, 0), Ss - 1); amvN = amb[ni]; }

  for (int step = 0; step < 10; ++step) {
    bool isg = (step == 0);
    int ks = isg ? 0 : (q0 - 256 + (step - 1) * 64);
    int amvC = amvN;
    if (step < 9) { int ni = min(max(q0 - 256 + step * 64 + lane, 0), Ss - 1); amvN = amb[ni]; }

    // V loads (shared by both tiles)
    bv8 vf0[4], vf1[4];
    #pragma unroll
    for (int nt = 0; nt < 4; ++nt) {
      const u16* vr = isg ? (vgb + (size_t)(nt * 16 + lc) * 64)
                          : (vb + (size_t)(nt * 16 + lc) * SPAD + PADL + ks);
      vf0[nt] = *reinterpret_cast<const bv8*>(vr + lg * 8);
      vf1[nt] = *reinterpret_cast<const bv8*>(vr + 32 + lg * 8);
    }
    // key-validity mask
    unsigned long long kmask;
    if (isg) {
      kmask = (1ull << Gg) - 1;
    } else {
      int kidx = ks + lane;
      kmask = __ballot((kidx >= 0) && (kidx < Ss) && (amvC > 0));
    }
    // QK^T swapped: scX[j] = scores for keys ks+j*16+lg4..+3, query (tile, lc)
    f32x4 scA[4], scB[4];
    __builtin_amdgcn_s_setprio(1);
    #pragma unroll
    for (int j = 0; j < 4; ++j) {
      f32x4 z = (f32x4){0.f, 0.f, 0.f, 0.f};
      scA[j] = __builtin_amdgcn_mfma_f32_16x16x32_bf16(kc[2 * j], aqA0, z, 0, 0, 0);
      scA[j] = __builtin_amdgcn_mfma_f32_16x16x32_bf16(kc[2 * j + 1], aqA1, scA[j], 0, 0, 0);
      scB[j] = __builtin_amdgcn_mfma_f32_16x16x32_bf16(kc[2 * j], aqB0, z, 0, 0, 0);
      scB[j] = __builtin_amdgcn_mfma_f32_16x16x32_bf16(kc[2 * j + 1], aqB1, scB[j], 0, 0, 0);
    }
    __builtin_amdgcn_s_setprio(0);
    // reload kc IN PLACE for next step (WAR; hides under softmax+PV)
    if (step < 9) {
      int ksn = q0 - 256 + step * 64;
      #pragma unroll
      for (int j = 0; j < 4; ++j) {
        const u16* kr = kb + (size_t)(PADL + ksn + j * 16 + lc) * 64;
        kc[2 * j]     = *reinterpret_cast<const bv8*>(kr + lg * 8);
        kc[2 * j + 1] = *reinterpret_cast<const bv8*>(kr + 32 + lg * 8);
      }
    }
    // masking: steps 2..8 with full kmask are band-safe for all 64 queries
    bool fast = (!isg) && (step >= 2) && (step <= 8) && (kmask == ~0ull);
    float mlocA = -1e30f, mlocB = -1e30f;
    if (fast) {
      #pragma unroll
      for (int j = 0; j < 4; ++j)
        #pragma unroll
        for (int r = 0; r < 4; ++r) {
          mlocA = fmaxf(mlocA, scA[j][r]);
          mlocB = fmaxf(mlocB, scB[j][r]);
        }
    } else {
      #pragma unroll
      for (int j = 0; j < 4; ++j)
        #pragma unroll
        for (int r = 0; r < 4; ++r) {
          int kk = ks + j * 16 + lg4 + r;
          bool okk = (kmask >> (j * 16 + lg4 + r)) & 1;
          bool okA = okk, okB = okk;
          if (!isg) {
            okA = okA && ((unsigned)(kk - qa + 256) <= 512u);
            okB = okB && ((unsigned)(kk - qbq + 256) <= 512u);
          }
          scA[j][r] = okA ? scA[j][r] : -1e9f;
          scB[j][r] = okB ? scB[j][r] : -1e9f;
          mlocA = fmaxf(mlocA, scA[j][r]);
          mlocB = fmaxf(mlocB, scB[j][r]);
        }
    }
    mlocA = fmaxf(mlocA, __shfl_xor(mlocA, 16));
    mlocA = fmaxf(mlocA, __shfl_xor(mlocA, 32));
    mlocB = fmaxf(mlocB, __shfl_xor(mlocB, 16));
    mlocB = fmaxf(mlocB, __shfl_xor(mlocB, 32));
    // defer-max: only rescale when max grows by > 8 for some query
    if (__any(mlocA > mrunA + 8.f)) {
      float nm = fmaxf(mrunA, mlocA);
      float scal = __expf(mrunA - nm);
      mrunA = nm;
      lrunA *= scal;
      #pragma unroll
      for (int r = 0; r < 4; ++r) {
        float sr = __shfl(scal, lg4 + r);
        #pragma unroll
        for (int nt = 0; nt < 4; ++nt) oA[nt][r] *= sr;
      }
    }
    if (__any(mlocB > mrunB + 8.f)) {
      float nm = fmaxf(mrunB, mlocB);
      float scal = __expf(mrunB - nm);
      mrunB = nm;
      lrunB *= scal;
      #pragma unroll
      for (int r = 0; r < 4; ++r) {
        float sr = __shfl(scal, lg4 + r);
        #pragma unroll
        for (int nt = 0; nt < 4; ++nt) oB[nt][r] *= sr;
      }
    }
    float psumA = 0.f, psumB = 0.f;
    #pragma unroll
    for (int j = 0; j < 4; ++j) {
      sv4 pkA, pkB;
      #pragma unroll
      for (int r = 0; r < 4; ++r) {
        float pA = __expf(scA[j][r] - mrunA);
        float pB = __expf(scB[j][r] - mrunB);
        psumA += pA; psumB += pB;
        pkA[r] = (short)f2bf(pA);
        pkB[r] = (short)f2bf(pB);
      }
      *reinterpret_cast<sv4*>(PA + lc * PSTR + j * 16 + lg4) = pkA;
      *reinterpret_cast<sv4*>(PB + lc * PSTR + j * 16 + lg4) = pkB;
    }
    psumA += __shfl_xor(psumA, 16);
    psumA += __shfl_xor(psumA, 32);
    psumB += __shfl_xor(psumB, 16);
    psumB += __shfl_xor(psumB, 32);
    lrunA += psumA;
    lrunB += psumB;
    // PV (V frags shared between tiles)
    __builtin_amdgcn_s_setprio(1);
    {
      bv8 apA = *reinterpret_cast<const bv8*>(PA + lc * PSTR + lg * 8);
      bv8 apB = *reinterpret_cast<const bv8*>(PB + lc * PSTR + lg * 8);
      #pragma unroll
      for (int nt = 0; nt < 4; ++nt) {
        oA[nt] = __builtin_amdgcn_mfma_f32_16x16x32_bf16(apA, vf0[nt], oA[nt], 0, 0, 0);
        oB[nt] = __builtin_amdgcn_mfma_f32_16x16x32_bf16(apB, vf0[nt], oB[nt], 0, 0, 0);
      }
      apA = *reinterpret_cast<const bv8*>(PA + lc * PSTR + 32 + lg * 8);
      apB = *reinterpret_cast<const bv8*>(PB + lc * PSTR + 32 + lg * 8);
      #pragma unroll
      for (int nt = 0; nt < 4; ++nt) {
        oA[nt] = __builtin_amdgcn_mfma_f32_16x16x32_bf16(apA, vf1[nt], oA[nt], 0, 0, 0);
        oB[nt] = __builtin_amdgcn_mfma_f32_16x16x32_bf16(apB, vf1[nt], oB[nt], 0, 0, 0);
      }
    }
    __builtin_amdgcn_s_setprio(0);
  }
  float invA = 1.0f / lrunA, invB = 1.0f / lrunB;
  #pragma unroll
  for (int r = 0; r < 4; ++r) {
    float invrA = __shfl(invA, lg4 + r);
    float invrB = __shfl(invB, lg4 + r);
    size_t rowA = ((size_t)b * Ss + qA + lg4 + r) * Dd + h * 64;
    size_t rowB = rowA + (size_t)16 * Dd;
    #pragma unroll
    for (int nt = 0; nt < 4; ++nt) {
      ctx[rowA + nt * 16 + lc] = f2bf(oA[nt][r] * invrA);
      ctx[rowB + nt * 16 + lc] = f2bf(oB[nt][r] * invrB);
    }
  }
}

// ---------------- global-query attention: lane-local flash MFMA -------------
__global__ __launch_bounds__(192)
void attn_globalq_kernel(const u16* __restrict__ qgb, const u16* __restrict__ kgf,
                         const u16* __restrict__ vgt, const int* __restrict__ amask,
                         float* __restrict__ part) {
  __shared__ u16 Plds[3][16 * PSTR];
  int blk = blockIdx.x;
  int ch = blk & (NCH - 1);
  int bh = blk / NCH;
  int b = bh / Hh, h = bh - b * Hh;
  int wv = threadIdx.x >> 6;  // q-tile 0..2
  int lane = threadIdx.x & 63;
  int lg = lane >> 4, lc = lane & 15;
  int lg4 = lg * 4;

  int qrow = wv * 16 + lc;
  bv8 aq0 = (bv8)0, aq1 = (bv8)0;
  if (qrow < Gg) {
    const u16* qr = qgb + (size_t)(b * Gg + qrow) * Dd + h * 64;
    aq0 = *reinterpret_cast<const bv8*>(qr + lg * 8);
    aq1 = *reinterpret_cast<const bv8*>(qr + 32 + lg * 8);
  }

  f32x4 o[4];
  #pragma unroll
  for (int i = 0; i < 4; ++i) o[i] = (f32x4){0.f, 0.f, 0.f, 0.f};
  float mrun = -1e30f, lrun = 0.f;

  const u16* kb = kgf + ((size_t)bh) * Ss * 64;
  const u16* vb = vgt + ((size_t)bh) * 64 * Ss;
  const int* amb = amask + b * Ss;
  int ks0 = ch * (Ss / NCH);
  u16* P = &Plds[wv][0];

  // preload K frags for step 0
  bv8 kc[8];
  #pragma unroll
  for (int j = 0; j < 4; ++j) {
    const u16* kr = kb + (size_t)(ks0 + j * 16 + lc) * 64;
    kc[2 * j]     = *reinterpret_cast<const bv8*>(kr + lg * 8);
    kc[2 * j + 1] = *reinterpret_cast<const bv8*>(kr + 32 + lg * 8);
  }

  for (int st = 0; st < 4; ++st) {
    int ks = ks0 + st * 64;
    // V loads
    bv8 vf0[4], vf1[4];
    #pragma unroll
    for (int nt = 0; nt < 4; ++nt) {
      const u16* vr = vb + (size_t)(nt * 16 + lc) * Ss + ks;
      vf0[nt] = *reinterpret_cast<const bv8*>(vr + lg * 8);
      vf1[nt] = *reinterpret_cast<const bv8*>(vr + 32 + lg * 8);
    }
    unsigned long long kmask = __ballot(amb[ks + lane] > 0);
    // QK^T swapped
    f32x4 sc[4];
    __builtin_amdgcn_s_setprio(1);
    #pragma unroll
    for (int j = 0; j < 4; ++j) {
      f32x4 z = (f32x4){0.f, 0.f, 0.f, 0.f};
      sc[j] = __builtin_amdgcn_mfma_f32_16x16x32_bf16(kc[2 * j], aq0, z, 0, 0, 0);
      sc[j] = __builtin_amdgcn_mfma_f32_16x16x32_bf16(kc[2 * j + 1], aq1, sc[j], 0, 0, 0);
    }
    __builtin_amdgcn_s_setprio(0);
    // reload kc for next step
    if (st < 3) {
      int ksn = ks0 + (st + 1) * 64;
      #pragma unroll
      for (int j = 0; j < 4; ++j) {
        const u16* kr = kb + (size_t)(ksn + j * 16 + lc) * 64;
        kc[2 * j]     = *reinterpret_cast<const bv8*>(kr + lg * 8);
        kc[2 * j + 1] = *reinterpret_cast<const bv8*>(kr + 32 + lg * 8);
      }
    }
    float mloc = -1e30f;
    if (kmask == ~0ull) {
      #pragma unroll
      for (int j = 0; j < 4; ++j)
        #pragma unroll
        for (int r = 0; r < 4; ++r) mloc = fmaxf(mloc, sc[j][r]);
    } else {
      #pragma unroll
      for (int j = 0; j < 4; ++j)
        #pragma unroll
        for (int r = 0; r < 4; ++r) {
          bool ok = (kmask >> (j * 16 + lg4 + r)) & 1;
          sc[j][r] = ok ? sc[j][r] : -1e9f;
          mloc = fmaxf(mloc, sc[j][r]);
        }
    }
    mloc = fmaxf(mloc, __shfl_xor(mloc, 16));
    mloc = fmaxf(mloc, __shfl_xor(mloc, 32));
    if (__any(mloc > mrun + 8.f)) {
      float nm = fmaxf(mrun, mloc);
      float scal = __expf(mrun - nm);
      mrun = nm;
      lrun *= scal;
      #pragma unroll
      for (int r = 0; r < 4; ++r) {
        float sr = __shfl(scal, lg4 + r);
        #pragma unroll
        for (int nt = 0; nt < 4; ++nt) o[nt][r] *= sr;
      }
    }
    float psum = 0.f;
    #pragma unroll
    for (int j = 0; j < 4; ++j) {
      sv4 pk;
      #pragma unroll
      for (int r = 0; r < 4; ++r) {
        float p = __expf(sc[j][r] - mrun);
        psum += p;
        pk[r] = (short)f2bf(p);
      }
      *reinterpret_cast<sv4*>(P + lc * PSTR + j * 16 + lg4) = pk;
    }
    psum += __shfl_xor(psum, 16);
    psum += __shfl_xor(psum, 32);
    lrun += psum;
    __builtin_amdgcn_s_setprio(1);
    {
      bv8 ap = *reinterpret_cast<const bv8*>(P + lc * PSTR + lg * 8);
      #pragma unroll
      for (int nt = 0; nt < 4; ++nt)
        o[nt] = __builtin_amdgcn_mfma_f32_16x16x32_bf16(ap, vf0[nt], o[nt], 0, 0, 0);
      ap = *reinterpret_cast<const bv8*>(P + lc * PSTR + 32 + lg * 8);
      #pragma unroll
      for (int nt = 0; nt < 4; ++nt)
        o[nt] = __builtin_amdgcn_mfma_f32_16x16x32_bf16(ap, vf1[nt], o[nt], 0, 0, 0);
    }
    __builtin_amdgcn_s_setprio(0);
  }

  float* pb = part + ((size_t)(bh * 3 + wv) * NCH + ch) * PARTF;
  #pragma unroll
  for (int r = 0; r < 4; ++r) {
    int row = lg4 + r;
    #pragma unroll
    for (int nt = 0; nt < 4; ++nt)
      pb[row * 64 + nt * 16 + lc] = o[nt][r];
  }
  if (lg == 0) {
    pb[1024 + lc] = mrun;
    pb[1040 + lc] = lrun;
  }
}

// merge NCH chunk-partials and scatter into ctx rows at gpos
__global__ __launch_bounds__(256)
void attn_gmerge_kernel(const float* __restrict__ part, const int* __restrict__ gpos,
                        u16* __restrict__ ctx) {
  __shared__ float wgt[Gg][NCH];
  __shared__ float sinvl[Gg];
  int bh = blockIdx.x;
  int b = bh / Hh, h = bh - b * Hh;
  int tid = threadIdx.x;
  if (tid < Gg) {
    int qt = tid >> 4, rr = tid & 15;
    const float* pb = part + ((size_t)(bh * 3 + qt) * NCH) * PARTF;
    float mx = -1e30f;
    for (int c = 0; c < NCH; ++c) mx = fmaxf(mx, pb[c * PARTF + 1024 + rr]);
    float l = 0.f;
    for (int c = 0; c < NCH; ++c) {
      float w = __expf(pb[c * PARTF + 1024 + rr] - mx);
      wgt[tid][c] = w;
      l += w * pb[c * PARTF + 1040 + rr];
    }
    sinvl[tid] = 1.0f / l;
  }
  __syncthreads();
  for (int e = tid; e < Gg * 64; e += 256) {
    int row = e >> 6, d = e & 63;
    int qt = row >> 4, rr = row & 15;
    const float* pb = part + ((size_t)(bh * 3 + qt) * NCH) * PARTF + rr * 64 + d;
    float acc = 0.f;
    #pragma unroll
    for (int c = 0; c < NCH; ++c) acc += wgt[row][c] * pb[c * PARTF];
    int pos = gpos[b * Gg + row];
    ctx[((size_t)b * Ss + pos) * Dd + h * 64 + d] = f2bf(acc * sinvl[row]);
  }
}

// ---------------- classifier ------------------------------------------------
__global__ __launch_bounds__(64)
void cls_kernel(const float* __restrict__ x, const float* __restrict__ W,
                const float* __restrict__ bias, const int* __restrict__ gpos,
                float* __restrict__ out) {
  int r = blockIdx.x;  // b*32 + i
  int b = r >> 5, i = r & 31;
  int pos = gpos[b * Gg + 1 + i];
  int lane = threadIdx.x;
  const float* xr = x + ((size_t)b * Ss + pos) * Dd;
  float acc[NCLSn] = {0.f, 0.f, 0.f, 0.f, 0.f};
  for (int k = lane; k < Dd; k += 64) {
    float xv = xr[k];
    #pragma unroll
    for (int c = 0; c < NCLSn; ++c) acc[c] += xv * W[c * Dd + k];
  }
  #pragma unroll
  for (int c = 0; c < NCLSn; ++c) {
    #pragma unroll
    for (int off = 1; off < 64; off <<= 1) acc[c] += __shfl_xor(acc[c], off);
  }
  if (lane == 0) {
    #pragma unroll
    for (int c = 0; c < NCLSn; ++c) out[r * NCLSn + c] = acc[c] + bias[c];
  }
}

// ---------------------------------------------------------------------------
extern "C" void kernel_launch(void* const* d_in, const int* in_sizes, int n_in,
                              void* d_out, int out_size, void* d_ws, size_t ws_size,
                              hipStream_t stream) {
  const int* ids     = (const int*)d_in[0];
  const int* amask   = (const int*)d_in[1];
  const float* we    = (const float*)d_in[2];
  const float* pe    = (const float*)d_in[3];
  const float* te    = (const float*)d_in[4];
  const float* embln = (const float*)d_in[5];
  const float* Wqkv  = (const float*)d_in[6];
  const float* bqkv  = (const float*)d_in[7];
  const float* Wqkvg = (const float*)d_in[8];
  const float* bqkvg = (const float*)d_in[9];
  const float* Wo    = (const float*)d_in[10];
  const float* bo    = (const float*)d_in[11];
  const float* ln1   = (const float*)d_in[12];
  const float* Wff1  = (const float*)d_in[13];
  const float* bff1  = (const float*)d_in[14];
  const float* Wff2  = (const float*)d_in[15];
  const float* bff2  = (const float*)d_in[16];
  const float* ln2   = (const float*)d_in[17];
  const float* clsW  = (const float*)d_in[18];
  const float* clsb  = (const float*)d_in[19];
  float* out = (float*)d_out;

  char* ws = (char*)d_ws;
  size_t off = 0;
  auto alloc = [&](size_t bytes) { size_t o = off; off += (bytes + 255) & ~(size_t)255; return o; };

  const size_t DD = (size_t)Dd * Dd;        // 589824
  const size_t DF = (size_t)Dd * 4 * Dd;    // 2359296
  const size_t WL = 7 * DD + 2 * DF;        // elems per layer
  // Wb layout per layer: [q,k,v, gk,gv, gq, wo, ff1, ff2]

  size_t o_cnt  = alloc(Bb * 4);
  size_t o_list = alloc(Bb * 64 * 4);
  size_t o_gpos = alloc(Bb * Gg * 4);
  size_t o_bias = alloc((size_t)Ll * 3840 * 4);
  size_t o_w    = alloc(WL * Ll * 2);
  size_t o_x    = alloc((size_t)Bb * Ss * Dd * 4);
  size_t o_xb   = alloc((size_t)Bb * Ss * Dd * 2);
  // kgf/vgf first: their 25.17 MB doubles as split-K bf16 buffer B
  size_t o_kgf  = alloc((size_t)Bb * Hh * Ss * 64 * 2);
  size_t o_vgf  = alloc((size_t)Bb * Hh * Ss * 64 * 2);
  size_t o_accB = o_kgf;  // bf16 half-B: 8192*768*2 bytes fits in kgf alone
  size_t o_qpk  = alloc((size_t)Bb * Hh * Ss * 64 * 2);
  size_t o_kpk  = alloc((size_t)Bb * Hh * SPAD * 64 * 2);
  size_t o_vtpk = alloc((size_t)Bb * Hh * 64 * SPAD * 2);
  size_t o_kg   = alloc((size_t)Bb * Hh * 64 * 64 * 2);
  size_t o_vgt  = alloc((size_t)Bb * Hh * 64 * 64 * 2);
  size_t o_xg   = alloc((size_t)128 * Dd * 2);
  size_t o_qg   = alloc((size_t)128 * Dd * 2);
  size_t o_part = alloc((size_t)Bb * Hh * 3 * NCH * PARTF * 4);
  size_t o_f1b  = o_qpk;  // FFN hidden aliases the (dead-by-then) attention buffers
  {
    size_t f1b_bytes = (size_t)Bb * Ss * 4 * Dd * 2;
    if (off - o_qpk < f1b_bytes) off = o_qpk + ((f1b_bytes + 255) & ~(size_t)255);
  }
  size_t o_ctx = alloc((size_t)Bb * Ss * Dd * 2);
  size_t o_acc = alloc((size_t)Bb * Ss * Dd * 4);
  if (ws_size < off) return;  // workspace too small -> fail visibly

  u16* Wb = (u16*)(ws + o_w);
  int* gposp = (int*)(ws + o_gpos);
  float* accA = (float*)(ws + o_acc);
  u16* accB = (u16*)(ws + o_accB);

  // setup: cnt=0, K/V pads=0 (3.3MB, pads only need to be finite), bias concat
  setup_kernel<<<512, 256, 0, stream>>>((int*)(ws + o_cnt), (u16*)(ws + o_kpk),
      (u16*)(ws + o_vtpk), bqkv, bqkvg, (float*)(ws + o_bias));

  sep_find_kernel<<<(Bb * Ss + 255) / 256, 256, 0, stream>>>(ids, (int*)(ws + o_cnt), (int*)(ws + o_list));
  sep_sort_kernel<<<Bb, 64, 0, stream>>>((int*)(ws + o_cnt), (int*)(ws + o_list), gposp);

  // weight conversions (batched over z); Wb layout [q,k,v,gk,gv,gq,wo,ff1,ff2]
  wconv_kernel<<<dim3(24, 24, 6), 256, 0, stream>>>(Wqkv,       Wb,          Dd, Dd, 3, 3, (long)DD, (long)WL);
  wconv_kernel<<<dim3(24, 24, 2), 256, 0, stream>>>(Wqkvg + DD,     Wb + 3 * DD, Dd, Dd, 1, 3, 0L, (long)WL);  // gk
  wconv_kernel<<<dim3(24, 24, 2), 256, 0, stream>>>(Wqkvg + 2 * DD, Wb + 4 * DD, Dd, Dd, 1, 3, 0L, (long)WL);  // gv
  wconv_kernel<<<dim3(24, 24, 2), 256, 0, stream>>>(Wqkvg,          Wb + 5 * DD, Dd, Dd, 1, 3, 0L, (long)WL);  // gq
  wconv_kernel<<<dim3(24, 24, 2), 256, 0, stream>>>(Wo,         Wb + 6 * DD, Dd, Dd, 1, 1, 0L, (long)WL);
  wconv_kernel<<<dim3(96, 24, 2), 256, 0, stream>>>(Wff1,       Wb + 7 * DD, Dd, 4 * Dd, 1, 1, 0L, (long)WL);
  wconv_kernel<<<dim3(24, 96, 2), 256, 0, stream>>>(Wff2,       Wb + 7 * DD + DF, 4 * Dd, Dd, 1, 1, 0L, (long)WL);

  embed_ln_kernel<<<Bb * Ss, 256, 0, stream>>>(ids, we, pe, te, embln, (float*)(ws + o_x), (u16*)(ws + o_xb));

  for (int l = 0; l < Ll; ++l) {
    size_t wb = (size_t)l * WL;
    u16* xb = (u16*)(ws + o_xb);
    // fused QKV + global K/V projection (N=3840, 5 sections); grid 1920 %8==0
    gemm2_kernel<2, true><<<dim3(30, 64), 256, 0, stream>>>(xb, Wb + wb, (float*)(ws + o_bias) + (size_t)l * 3840,
        nullptr,
        (u16*)(ws + o_qpk), (u16*)(ws + o_kpk), (u16*)(ws + o_vtpk),
        (u16*)(ws + o_kgf), (u16*)(ws + o_vgf), 3840, Dd, Dd, 0.125f);
    gather_glob_kernel<<<Bb * Hh, 256, 0, stream>>>((u16*)(ws + o_kpk), (u16*)(ws + o_vtpk), gposp, (u16*)(ws + o_kg), (u16*)(ws + o_vgt));
    gather_xg_kernel<<<Bb * Gg, 256, 0, stream>>>(xb, gposp, (u16*)(ws + o_xg));
    // global q projection (M=128 padded rows); 6 blocks -> no XCD swizzle
    gemm2_kernel<4, false><<<dim3(6, 1), 256, 0, stream>>>((u16*)(ws + o_xg), Wb + wb + 5 * DD, bqkvg + (size_t)l * 3 * Dd,
        nullptr, (u16*)(ws + o_qg), nullptr, nullptr, nullptr, nullptr, Dd, Dd, Dd, 0.125f);
    // attention
    attn_local_kernel<<<LOCAL_NB, 128, 0, stream>>>((u16*)(ws + o_qpk), (u16*)(ws + o_kpk), (u16*)(ws + o_vtpk), (u16*)(ws + o_kg), (u16*)(ws + o_vgt), amask, (u16*)(ws + o_ctx));
    attn_globalq_kernel<<<Bb * Hh * NCH, 192, 0, stream>>>((u16*)(ws + o_qg), (u16*)(ws + o_kgf), (u16*)(ws + o_vgf), amask, (float*)(ws + o_part));
    attn_gmerge_kernel<<<Bb * Hh, 256, 0, stream>>>((float*)(ws + o_part), gposp, (u16*)(ws + o_ctx));
    // output projection (split-K x2, half-B bf16) + LN  [kgf/vgf dead now]
    gemm2_kernel<0, true><<<dim3(6, 64, 2), 256, 0, stream>>>((u16*)(ws + o_ctx), Wb + wb + 6 * DD, bo + (size_t)l * Dd, accA,
        accB, nullptr, nullptr, nullptr, nullptr, Dd, Dd, Dd / 2, 1.0f);
    add_ln3_kernel<<<Bb * Ss, 256, 0, stream>>>((float*)(ws + o_x), accA, accB, ln1 + (size_t)l * 2 * Dd, (float*)(ws + o_x), xb);
    // FFN
    gemm2_kernel<1, true><<<dim3(24, 64), 256, 0, stream>>>(xb, Wb + wb + 7 * DD, bff1 + (size_t)l * 4 * Dd, nullptr,
        (u16*)(ws + o_f1b), nullptr, nullptr, nullptr, nullptr, 4 * Dd, Dd, Dd, 1.0f);
    gemm2_kernel<0, true><<<dim3(6, 64, 2), 256, 0, stream>>>((u16*)(ws + o_f1b), Wb + wb + 7 * DD + DF, bff2 + (size_t)l * Dd, accA,
        accB, nullptr, nullptr, nullptr, nullptr, Dd, 4 * Dd, 2 * Dd, 1.0f);
    add_ln3_kernel<<<Bb * Ss, 256, 0, stream>>>((float*)(ws + o_x), accA, accB, ln2 + (size_t)l * 2 * Dd, (float*)(ws + o_x), xb);
  }

  cls_kernel<<<Bb * NSEPn, 64, 0, stream>>>((float*)(ws + o_x), clsW, clsb, gposp, out);
}

// Round 14
// 715.162 us; speedup vs baseline: 1.3042x; 1.0637x over previous
//
#include <hip/hip_runtime.h>

// ---------------------------------------------------------------------------
// Longformer (2-layer) forward, MI355X.
// R13: all-bf16 residual stream (x dropped; xb is the in-place carrier),
//      split-K outputs both bf16, embed/cls on bf16, gathers merged.
// ---------------------------------------------------------------------------

#define Bb 2
#define Ss 4096
#define Dd 768
#define Hh 12
#define Gg 33
#define NSEPn 32
#define Ll 2
#define SPAD 4640   // S + 544 (PADL=256 left, 288 right)
#define PADL 256
#define NCLSn 5
#define NCH 16      // key chunks for global-q attention (256 keys each)
#define PARTF 1056  // floats per (bh,qt,chunk) partial: 16*64 o + 16 m + 16 l
#define PSTR 72     // Plds row stride in u16 (144B: 16B-aligned, bank-spread)

typedef unsigned short u16;
typedef __attribute__((ext_vector_type(8))) short bv8;   // 8 x bf16
typedef __attribute__((ext_vector_type(4))) short sv4;   // 4 x bf16
typedef __attribute__((ext_vector_type(4))) float f32x4;

__device__ __forceinline__ float bf2f(u16 u) {
  unsigned v = ((unsigned)u) << 16;
  return __builtin_bit_cast(float, v);
}
__device__ __forceinline__ u16 f2bf(float f) {
  unsigned u = __builtin_bit_cast(unsigned, f);
  u += 0x7fffu + ((u >> 16) & 1u);
  return (u16)(u >> 16);
}
__device__ __forceinline__ void glds16(const void* g, void* l) {
  __builtin_amdgcn_global_load_lds(
      (const __attribute__((address_space(1))) void*)g,
      (__attribute__((address_space(3))) void*)l, 16, 0, 0);
}

// ---------------- setup: cnt=0, K/V pad rows = 0, bias concat ---------------
__global__ __launch_bounds__(256)
void setup_kernel(int* __restrict__ cnt, u16* __restrict__ kpk,
                  u16* __restrict__ vtpk, const float* __restrict__ bqkv,
                  const float* __restrict__ bqkvg, float* __restrict__ biasc) {
  int tid = blockIdx.x * 256 + threadIdx.x;
  if (tid < Bb) cnt[tid] = 0;
  if (tid < Ll * 3840) {
    int l = tid / 3840, c = tid - l * 3840;
    float v = (c < 2304) ? bqkv[l * 2304 + c]
                         : bqkvg[(l * 3 + 1) * Dd + (c - 2304)];
    biasc[tid] = v;
  }
  const int PADW = SPAD - Ss;                 // 544 pad rows per bh
  const int total = Bb * Hh * PADW * 64;      // 835584 elems per buffer
  for (int i = tid; i < total; i += gridDim.x * 256) {
    int bh = i / (PADW * 64);
    int rem = i - bh * (PADW * 64);
    int prow = rem >> 6, d = rem & 63;
    int row = (prow < PADL) ? prow : (Ss + prow);  // [0,PADL) U [PADL+Ss,SPAD)
    kpk[((size_t)bh * SPAD + row) * 64 + d] = 0;
    vtpk[((size_t)bh * 64 + d) * SPAD + row] = 0;
  }
}

// ---------------- sep finding --------------------------------------------
__global__ void sep_find_kernel(const int* __restrict__ ids, int* __restrict__ cnt,
                                int* __restrict__ list) {
  int i = blockIdx.x * 256 + threadIdx.x;
  if (i >= Bb * Ss) return;
  int b = i >> 12;
  if (ids[i] == 2) {
    int idx = atomicAdd(&cnt[b], 1);
    if (idx < 64) list[b * 64 + idx] = i & (Ss - 1);
  }
}

__global__ void sep_sort_kernel(const int* __restrict__ cnt, const int* __restrict__ list,
                                int* __restrict__ gpos) {
  int b = blockIdx.x;
  int t = threadIdx.x;
  int n = cnt[b]; if (n > 64) n = 64;
  if (t < Gg) gpos[b * Gg + t] = (t == 0) ? 0 : (Ss - 1);
  __syncthreads();
  if (t < n) {
    int v = list[b * 64 + t];
    int rank = 0;
    for (int j = 0; j < n; ++j) rank += (list[b * 64 + j] < v) ? 1 : 0;
    if (rank < NSEPn) gpos[b * Gg + 1 + rank] = v;
  }
}

// ------- weight fp32 (K,N) -> bf16 (N,K), batched; src slice (z/grp)*sstr+z%grp
__global__ __launch_bounds__(256)
void wconv_kernel(const float* __restrict__ src0, u16* __restrict__ dst0,
                  int K, int N, int grp, int sstr, long unit, long WLs) {
  __shared__ float t[32][33];
  int z = blockIdx.z;
  const float* src = src0 + (size_t)((z / grp) * sstr + (z % grp)) * K * N;
  u16* dst = dst0 + (size_t)(z / grp) * WLs + (size_t)(z % grp) * unit;
  int n0 = blockIdx.x * 32, k0 = blockIdx.y * 32;
  int tx = threadIdx.x & 31, ty = threadIdx.x >> 5;  // ty 0..7
  #pragma unroll
  for (int i = 0; i < 4; ++i)
    t[ty + i * 8][tx] = src[(size_t)(k0 + ty + i * 8) * N + n0 + tx];
  __syncthreads();
  #pragma unroll
  for (int i = 0; i < 4; ++i)
    dst[(size_t)(n0 + ty + i * 8) * K + k0 + tx] = f2bf(t[tx][ty + i * 8]);
}

// ---------------- embedding + LN (bf16 out only) ----------------------------
__global__ __launch_bounds__(256)
void embed_ln_kernel(const int* __restrict__ ids, const float* __restrict__ we,
                     const float* __restrict__ pe, const float* __restrict__ te,
                     const float* __restrict__ lnp, u16* __restrict__ xb) {
  int row = blockIdx.x;
  int s = row & (Ss - 1);
  int id = ids[row];
  int tid = threadIdx.x;
  float v[3]; float sm = 0.f, s2 = 0.f;
  #pragma unroll
  for (int i = 0; i < 3; ++i) {
    int c = tid + i * 256;
    float t = we[(size_t)id * Dd + c] + pe[(size_t)(s + 2) * Dd + c] + te[c];
    v[i] = t; sm += t; s2 += t * t;
  }
  __shared__ float r1[256], r2[256];
  r1[tid] = sm; r2[tid] = s2; __syncthreads();
  for (int o = 128; o; o >>= 1) {
    if (tid < o) { r1[tid] += r1[tid + o]; r2[tid] += r2[tid + o]; }
    __syncthreads();
  }
  float mean = r1[0] * (1.f / 768.f);
  float var  = r2[0] * (1.f / 768.f) - mean * mean;
  float rs = rsqrtf(var + 1e-5f);
  #pragma unroll
  for (int i = 0; i < 3; ++i) {
    int c = tid + i * 256;
    float o = (v[i] - mean) * rs * lnp[c] + lnp[Dd + c];
    xb[(size_t)row * Dd + c] = f2bf(o);
  }
}

// ------ residual (in-place bf16 carrier + 2 bf16 halves) + LN ---------------
// in-place safe: all reads precede first __syncthreads; rows block-exclusive.
__global__ __launch_bounds__(256)
void add_ln3_kernel(u16* __restrict__ xio, const u16* __restrict__ y0,
                    const u16* __restrict__ y1, const float* __restrict__ lnp) {
  int row = blockIdx.x;
  int tid = threadIdx.x;
  float v[3]; float sm = 0.f, s2 = 0.f;
  #pragma unroll
  for (int i = 0; i < 3; ++i) {
    int c = tid + i * 256;
    size_t idx = (size_t)row * Dd + c;
    float t = bf2f(xio[idx]) + bf2f(y0[idx]) + bf2f(y1[idx]);
    v[i] = t; sm += t; s2 += t * t;
  }
  __shared__ float r1[256], r2[256];
  r1[tid] = sm; r2[tid] = s2; __syncthreads();
  for (int o = 128; o; o >>= 1) {
    if (tid < o) { r1[tid] += r1[tid + o]; r2[tid] += r2[tid + o]; }
    __syncthreads();
  }
  float mean = r1[0] * (1.f / 768.f);
  float var  = r2[0] * (1.f / 768.f) - mean * mean;
  float rs = rsqrtf(var + 1e-5f);
  #pragma unroll
  for (int i = 0; i < 3; ++i) {
    int c = tid + i * 256;
    float o = (v[i] - mean) * rs * lnp[c] + lnp[Dd + c];
    xio[(size_t)row * Dd + c] = f2bf(o);
  }
}

// ---------------- GEMM2: 128x128 2-buffer + T2 LDS swizzle + T1 XCD swizzle -
// MODE 0: split-K: z==0 -> bf16 o0 (+bias); z==1 -> bf16 o1 (no bias)
// MODE 1: bf16 [M][N], exact gelu
// MODE 2: fused QKV+gKV: N=3840; secs: q pk / k pad / v^T pad / gk pk / gv^T
// MODE 4: bf16 [M][N] * scale
template <int MODE, bool XSWZ>
__global__ __launch_bounds__(256)
void gemm2_kernel(const u16* __restrict__ A, const u16* __restrict__ Bt,
                  const float* __restrict__ bias,
                  u16* __restrict__ o0, u16* __restrict__ o1, u16* __restrict__ o2,
                  u16* __restrict__ o3, u16* __restrict__ o4,
                  int N, int Ks, int Kl, float scale) {
  __shared__ u16 la[2][128 * 32], lb[2][128 * 32];
  int tid = threadIdx.x;
  int wave = tid >> 6, lane = tid & 63;
  int wr = wave >> 1, wc = wave & 1;
  int lg = lane >> 4, lc = lane & 15;
  // T1: XCD-aware bijective remap of the x-y plane (requires NB % 8 == 0)
  int bx = blockIdx.x, by = blockIdx.y;
  if (XSWZ) {
    int gx = gridDim.x;
    int nlin = bx + gx * by;
    int NB = gx * gridDim.y;
    nlin = (nlin & 7) * (NB >> 3) + (nlin >> 3);
    bx = nlin % gx;
    by = nlin / gx;
  }
  int row0 = by * 128, col0 = bx * 128;
  int koff = blockIdx.z * Kl;

  // T2 swizzle: linear LDS dest; lane fetches logical granule (l&3)^((l>>3)&3)
  int sgr = (lane & 3) ^ ((lane >> 3) & 3);
  const u16* Ag = A + (size_t)(row0 + wave * 32 + (lane >> 2)) * Ks + sgr * 8 + koff;
  const u16* Bg = Bt + (size_t)(col0 + wave * 32 + (lane >> 2)) * Ks + sgr * 8 + koff;
  int wofs = wave * 1024;
  int gph = (lg ^ ((lc >> 1) & 3)) * 8;   // swizzled read granule offset (u16)

  f32x4 acc[4][4];
  #pragma unroll
  for (int m = 0; m < 4; ++m)
    #pragma unroll
    for (int n = 0; n < 4; ++n) acc[m][n] = (f32x4){0.f, 0.f, 0.f, 0.f};

  glds16(Ag, la[0] + wofs);
  glds16(Ag + (size_t)16 * Ks, la[0] + wofs + 512);
  glds16(Bg, lb[0] + wofs);
  glds16(Bg + (size_t)16 * Ks, lb[0] + wofs + 512);
  __syncthreads();

  int nk = Kl >> 5;
  for (int t = 0; t < nk; ++t) {
    int cur = t & 1;
    if (t + 1 < nk) {
      int k1 = (t + 1) << 5;
      glds16(Ag + k1, la[cur ^ 1] + wofs);
      glds16(Ag + (size_t)16 * Ks + k1, la[cur ^ 1] + wofs + 512);
      glds16(Bg + k1, lb[cur ^ 1] + wofs);
      glds16(Bg + (size_t)16 * Ks + k1, lb[cur ^ 1] + wofs + 512);
    }
    bv8 af[4], bf_[4];
    #pragma unroll
    for (int m = 0; m < 4; ++m)
      af[m] = *reinterpret_cast<const bv8*>(la[cur] + (wr * 64 + m * 16 + lc) * 32 + gph);
    #pragma unroll
    for (int n = 0; n < 4; ++n)
      bf_[n] = *reinterpret_cast<const bv8*>(lb[cur] + (wc * 64 + n * 16 + lc) * 32 + gph);
    __builtin_amdgcn_s_setprio(1);
    #pragma unroll
    for (int m = 0; m < 4; ++m)
      #pragma unroll
      for (int n = 0; n < 4; ++n)
        acc[m][n] = __builtin_amdgcn_mfma_f32_16x16x32_bf16(af[m], bf_[n], acc[m][n], 0, 0, 0);
    __builtin_amdgcn_s_setprio(0);
    __syncthreads();
  }

  #pragma unroll
  for (int m = 0; m < 4; ++m) {
    int grow0 = row0 + wr * 64 + m * 16 + lg * 4;
    #pragma unroll
    for (int n = 0; n < 4; ++n) {
      int gcol = col0 + wc * 64 + n * 16 + lc;
      float bvl = bias[gcol];
      if (MODE == 0) {
        u16* od = blockIdx.z ? o1 : o0;
        float badd = blockIdx.z ? 0.f : bvl;
        #pragma unroll
        for (int r = 0; r < 4; ++r)
          od[(size_t)(grow0 + r) * N + gcol] = f2bf(acc[m][n][r] + badd);
      } else if (MODE == 1) {
        #pragma unroll
        for (int r = 0; r < 4; ++r) {
          float v = acc[m][n][r] + bvl;
          v = 0.5f * v * (1.0f + erff(v * 0.70710678118654752f));
          o0[(size_t)(grow0 + r) * N + gcol] = f2bf(v);
        }
      } else if (MODE == 4) {
        #pragma unroll
        for (int r = 0; r < 4; ++r)
          o0[(size_t)(grow0 + r) * N + gcol] = f2bf((acc[m][n][r] + bvl) * scale);
      } else if (MODE == 2) {
        int sec = (col0 >> 7) / 6;        // 0..4, block-uniform
        int colr = gcol - sec * 768;
        int hh = colr >> 6, d = colr & 63;
        int bb = grow0 >> 12, s = grow0 & (Ss - 1);
        size_t bhh = (size_t)(bb * Hh + hh);
        if (sec == 0) {
          #pragma unroll
          for (int r = 0; r < 4; ++r)
            o0[(bhh * Ss + s + r) * 64 + d] = f2bf((acc[m][n][r] + bvl) * scale);
        } else if (sec == 1) {
          #pragma unroll
          for (int r = 0; r < 4; ++r)
            o1[(bhh * SPAD + PADL + s + r) * 64 + d] = f2bf(acc[m][n][r] + bvl);
        } else if (sec == 2) {
          sv4 pk;
          #pragma unroll
          for (int r = 0; r < 4; ++r) pk[r] = (short)f2bf(acc[m][n][r] + bvl);
          *reinterpret_cast<sv4*>(o2 + (bhh * 64 + d) * SPAD + PADL + s) = pk;
        } else if (sec == 3) {
          #pragma unroll
          for (int r = 0; r < 4; ++r)
            o3[(bhh * Ss + s + r) * 64 + d] = f2bf(acc[m][n][r] + bvl);
        } else {
          sv4 pk;
          #pragma unroll
          for (int r = 0; r < 4; ++r) pk[r] = (short)f2bf(acc[m][n][r] + bvl);
          *reinterpret_cast<sv4*>(o4 + (bhh * 64 + d) * Ss + s) = pk;
        }
      }
    }
  }
}

// ---------------- gathers (merged: glob K/V + xg) ---------------------------
__global__ __launch_bounds__(256)
void gather_kernel(const u16* __restrict__ kpk, const u16* __restrict__ vtpk,
                   const u16* __restrict__ xb, const int* __restrict__ gpos,
                   u16* __restrict__ kg, u16* __restrict__ vgt,
                   u16* __restrict__ xg) {
  int blk = blockIdx.x;
  int tid = threadIdx.x;
  if (blk < Bb * Hh) {
    int bh = blk;
    int b = bh / Hh;
    for (int idx = tid; idx < 64 * 64; idx += 256) {
      int g = idx >> 6, d = idx & 63;
      u16 kv = 0, vv = 0;
      if (g < Gg) {
        int p = gpos[b * Gg + g];
        kv = kpk[((size_t)bh * SPAD + PADL + p) * 64 + d];
        vv = vtpk[((size_t)bh * 64 + d) * SPAD + PADL + p];
      }
      kg[(size_t)bh * 4096 + idx] = kv;
      vgt[((size_t)bh * 64 + d) * 64 + g] = vv;
    }
  } else {
    int rg = blk - Bb * Hh;   // b*G+g
    int b = rg / Gg;
    int p = gpos[rg];
    for (int c = tid; c < Dd; c += 256)
      xg[(size_t)rg * Dd + c] = xb[((size_t)b * Ss + p) * Dd + c];
  }
}

// ---------------- local (sliding window + global-key) attention -------------
// 2 waves/block, 2 q-tiles/wave (64 queries/block). Swapped QK^T, ballot mask,
// defer-max (THR=8). Per-step scalar overhead amortized over 32 queries/wave.
#define LOCAL_NB (Bb * Hh * (Ss / 64))   // 1536 blocks, %8 == 0
__global__ __launch_bounds__(128)
void attn_local_kernel(const u16* __restrict__ qpk, const u16* __restrict__ kpk,
                       const u16* __restrict__ vtpk, const u16* __restrict__ kg,
                       const u16* __restrict__ vgt, const int* __restrict__ amask,
                       u16* __restrict__ ctx) {
  __shared__ u16 Plds[4][16 * PSTR];
  int bid = blockIdx.x;
  int swz = (bid & 7) * (LOCAL_NB / 8) + (bid >> 3);
  int qb = swz & 63;
  int bh = swz >> 6;
  int b = bh / Hh;
  int h = bh - b * Hh;
  int wv = threadIdx.x >> 6;       // 0..1
  int q0 = qb * 64;                // block window base
  int qA = q0 + wv * 32;           // tile A rows qA..qA+15; tile B +16
  int lane = threadIdx.x & 63;
  int lg = lane >> 4, lc = lane & 15;
  int lg4 = lg * 4;
  int qa = qA + lc, qbq = qA + 16 + lc;   // this lane's queries (A, B)

  const u16* qrowA = qpk + ((size_t)bh * Ss + qA + lc) * 64;
  bv8 aqA0 = *reinterpret_cast<const bv8*>(qrowA + lg * 8);
  bv8 aqA1 = *reinterpret_cast<const bv8*>(qrowA + 32 + lg * 8);
  const u16* qrowB = qrowA + 16 * 64;
  bv8 aqB0 = *reinterpret_cast<const bv8*>(qrowB + lg * 8);
  bv8 aqB1 = *reinterpret_cast<const bv8*>(qrowB + 32 + lg * 8);

  f32x4 oA[4], oB[4];
  #pragma unroll
  for (int i = 0; i < 4; ++i) { oA[i] = (f32x4){0.f,0.f,0.f,0.f}; oB[i] = (f32x4){0.f,0.f,0.f,0.f}; }
  float mrunA = -1e30f, lrunA = 0.f, mrunB = -1e30f, lrunB = 0.f;

  const u16* kgb = kg + ((size_t)bh) * 64 * 64;
  const u16* vgb = vgt + ((size_t)bh) * 64 * 64;
  const u16* kb = kpk + ((size_t)bh) * SPAD * 64;
  const u16* vb = vtpk + ((size_t)bh) * 64 * SPAD;
  const int* amb = amask + b * Ss;
  u16* PA = &Plds[wv * 2][0];
  u16* PB = &Plds[wv * 2 + 1][0];

  // preload K frags for step 0 (global keys)
  bv8 kc[8];
  #pragma unroll
  for (int j = 0; j < 4; ++j) {
    const u16* kr = kgb + (size_t)(j * 16 + lc) * 64;
    kc[2 * j]     = *reinterpret_cast<const bv8*>(kr + lg * 8);
    kc[2 * j + 1] = *reinterpret_cast<const bv8*>(kr + 32 + lg * 8);
  }
  // prefetch amask word for step 1
  int amvN;
  { int ni = min(max(q0 - 256 + lane, 0), Ss - 1); amvN = amb[ni]; }

  for (int step = 0; step < 10; ++step) {
    bool isg = (step == 0);
    int ks = isg ? 0 : (q0 - 256 + (step - 1) * 64);
    int amvC = amvN;
    if (step < 9) { int ni = min(max(q0 - 256 + step * 64 + lane, 0), Ss - 1); amvN = amb[ni]; }

    // V loads (shared by both tiles)
    bv8 vf0[4], vf1[4];
    #pragma unroll
    for (int nt = 0; nt < 4; ++nt) {
      const u16* vr = isg ? (vgb + (size_t)(nt * 16 + lc) * 64)
                          : (vb + (size_t)(nt * 16 + lc) * SPAD + PADL + ks);
      vf0[nt] = *reinterpret_cast<const bv8*>(vr + lg * 8);
      vf1[nt] = *reinterpret_cast<const bv8*>(vr + 32 + lg * 8);
    }
    // key-validity mask
    unsigned long long kmask;
    if (isg) {
      kmask = (1ull << Gg) - 1;
    } else {
      int kidx = ks + lane;
      kmask = __ballot((kidx >= 0) && (kidx < Ss) && (amvC > 0));
    }
    // QK^T swapped: scX[j] = scores for keys ks+j*16+lg4..+3, query (tile, lc)
    f32x4 scA[4], scB[4];
    __builtin_amdgcn_s_setprio(1);
    #pragma unroll
    for (int j = 0; j < 4; ++j) {
      f32x4 z = (f32x4){0.f, 0.f, 0.f, 0.f};
      scA[j] = __builtin_amdgcn_mfma_f32_16x16x32_bf16(kc[2 * j], aqA0, z, 0, 0, 0);
      scA[j] = __builtin_amdgcn_mfma_f32_16x16x32_bf16(kc[2 * j + 1], aqA1, scA[j], 0, 0, 0);
      scB[j] = __builtin_amdgcn_mfma_f32_16x16x32_bf16(kc[2 * j], aqB0, z, 0, 0, 0);
      scB[j] = __builtin_amdgcn_mfma_f32_16x16x32_bf16(kc[2 * j + 1], aqB1, scB[j], 0, 0, 0);
    }
    __builtin_amdgcn_s_setprio(0);
    // reload kc IN PLACE for next step (WAR; hides under softmax+PV)
    if (step < 9) {
      int ksn = q0 - 256 + step * 64;
      #pragma unroll
      for (int j = 0; j < 4; ++j) {
        const u16* kr = kb + (size_t)(PADL + ksn + j * 16 + lc) * 64;
        kc[2 * j]     = *reinterpret_cast<const bv8*>(kr + lg * 8);
        kc[2 * j + 1] = *reinterpret_cast<const bv8*>(kr + 32 + lg * 8);
      }
    }
    // masking: steps 2..8 with full kmask are band-safe for all 64 queries
    bool fast = (!isg) && (step >= 2) && (step <= 8) && (kmask == ~0ull);
    float mlocA = -1e30f, mlocB = -1e30f;
    if (fast) {
      #pragma unroll
      for (int j = 0; j < 4; ++j)
        #pragma unroll
        for (int r = 0; r < 4; ++r) {
          mlocA = fmaxf(mlocA, scA[j][r]);
          mlocB = fmaxf(mlocB, scB[j][r]);
        }
    } else {
      #pragma unroll
      for (int j = 0; j < 4; ++j)
        #pragma unroll
        for (int r = 0; r < 4; ++r) {
          int kk = ks + j * 16 + lg4 + r;
          bool okk = (kmask >> (j * 16 + lg4 + r)) & 1;
          bool okA = okk, okB = okk;
          if (!isg) {
            okA = okA && ((unsigned)(kk - qa + 256) <= 512u);
            okB = okB && ((unsigned)(kk - qbq + 256) <= 512u);
          }
          scA[j][r] = okA ? scA[j][r] : -1e9f;
          scB[j][r] = okB ? scB[j][r] : -1e9f;
          mlocA = fmaxf(mlocA, scA[j][r]);
          mlocB = fmaxf(mlocB, scB[j][r]);
        }
    }
    mlocA = fmaxf(mlocA, __shfl_xor(mlocA, 16));
    mlocA = fmaxf(mlocA, __shfl_xor(mlocA, 32));
    mlocB = fmaxf(mlocB, __shfl_xor(mlocB, 16));
    mlocB = fmaxf(mlocB, __shfl_xor(mlocB, 32));
    // defer-max: only rescale when max grows by > 8 for some query
    if (__any(mlocA > mrunA + 8.f)) {
      float nm = fmaxf(mrunA, mlocA);
      float scal = __expf(mrunA - nm);
      mrunA = nm;
      lrunA *= scal;
      #pragma unroll
      for (int r = 0; r < 4; ++r) {
        float sr = __shfl(scal, lg4 + r);
        #pragma unroll
        for (int nt = 0; nt < 4; ++nt) oA[nt][r] *= sr;
      }
    }
    if (__any(mlocB > mrunB + 8.f)) {
      float nm = fmaxf(mrunB, mlocB);
      float scal = __expf(mrunB - nm);
      mrunB = nm;
      lrunB *= scal;
      #pragma unroll
      for (int r = 0; r < 4; ++r) {
        float sr = __shfl(scal, lg4 + r);
        #pragma unroll
        for (int nt = 0; nt < 4; ++nt) oB[nt][r] *= sr;
      }
    }
    float psumA = 0.f, psumB = 0.f;
    #pragma unroll
    for (int j = 0; j < 4; ++j) {
      sv4 pkA, pkB;
      #pragma unroll
      for (int r = 0; r < 4; ++r) {
        float pA = __expf(scA[j][r] - mrunA);
        float pB = __expf(scB[j][r] - mrunB);
        psumA += pA; psumB += pB;
        pkA[r] = (short)f2bf(pA);
        pkB[r] = (short)f2bf(pB);
      }
      *reinterpret_cast<sv4*>(PA + lc * PSTR + j * 16 + lg4) = pkA;
      *reinterpret_cast<sv4*>(PB + lc * PSTR + j * 16 + lg4) = pkB;
    }
    psumA += __shfl_xor(psumA, 16);
    psumA += __shfl_xor(psumA, 32);
    psumB += __shfl_xor(psumB, 16);
    psumB += __shfl_xor(psumB, 32);
    lrunA += psumA;
    lrunB += psumB;
    // PV (V frags shared between tiles)
    __builtin_amdgcn_s_setprio(1);
    {
      bv8 apA = *reinterpret_cast<const bv8*>(PA + lc * PSTR + lg * 8);
      bv8 apB = *reinterpret_cast<const bv8*>(PB + lc * PSTR + lg * 8);
      #pragma unroll
      for (int nt = 0; nt < 4; ++nt) {
        oA[nt] = __builtin_amdgcn_mfma_f32_16x16x32_bf16(apA, vf0[nt], oA[nt], 0, 0, 0);
        oB[nt] = __builtin_amdgcn_mfma_f32_16x16x32_bf16(apB, vf0[nt], oB[nt], 0, 0, 0);
      }
      apA = *reinterpret_cast<const bv8*>(PA + lc * PSTR + 32 + lg * 8);
      apB = *reinterpret_cast<const bv8*>(PB + lc * PSTR + 32 + lg * 8);
      #pragma unroll
      for (int nt = 0; nt < 4; ++nt) {
        oA[nt] = __builtin_amdgcn_mfma_f32_16x16x32_bf16(apA, vf1[nt], oA[nt], 0, 0, 0);
        oB[nt] = __builtin_amdgcn_mfma_f32_16x16x32_bf16(apB, vf1[nt], oB[nt], 0, 0, 0);
      }
    }
    __builtin_amdgcn_s_setprio(0);
  }
  float invA = 1.0f / lrunA, invB = 1.0f / lrunB;
  #pragma unroll
  for (int r = 0; r < 4; ++r) {
    float invrA = __shfl(invA, lg4 + r);
    float invrB = __shfl(invB, lg4 + r);
    size_t rowA = ((size_t)b * Ss + qA + lg4 + r) * Dd + h * 64;
    size_t rowB = rowA + (size_t)16 * Dd;
    #pragma unroll
    for (int nt = 0; nt < 4; ++nt) {
      ctx[rowA + nt * 16 + lc] = f2bf(oA[nt][r] * invrA);
      ctx[rowB + nt * 16 + lc] = f2bf(oB[nt][r] * invrB);
    }
  }
}

// ---------------- global-query attention: lane-local flash MFMA -------------
__global__ __launch_bounds__(192)
void attn_globalq_kernel(const u16* __restrict__ qgb, const u16* __restrict__ kgf,
                         const u16* __restrict__ vgt, const int* __restrict__ amask,
                         float* __restrict__ part) {
  __shared__ u16 Plds[3][16 * PSTR];
  int blk = blockIdx.x;
  int ch = blk & (NCH - 1);
  int bh = blk / NCH;
  int b = bh / Hh, h = bh - b * Hh;
  int wv = threadIdx.x >> 6;  // q-tile 0..2
  int lane = threadIdx.x & 63;
  int lg = lane >> 4, lc = lane & 15;
  int lg4 = lg * 4;

  int qrow = wv * 16 + lc;
  bv8 aq0 = (bv8)0, aq1 = (bv8)0;
  if (qrow < Gg) {
    const u16* qr = qgb + (size_t)(b * Gg + qrow) * Dd + h * 64;
    aq0 = *reinterpret_cast<const bv8*>(qr + lg * 8);
    aq1 = *reinterpret_cast<const bv8*>(qr + 32 + lg * 8);
  }

  f32x4 o[4];
  #pragma unroll
  for (int i = 0; i < 4; ++i) o[i] = (f32x4){0.f, 0.f, 0.f, 0.f};
  float mrun = -1e30f, lrun = 0.f;

  const u16* kb = kgf + ((size_t)bh) * Ss * 64;
  const u16* vb = vgt + ((size_t)bh) * 64 * Ss;
  const int* amb = amask + b * Ss;
  int ks0 = ch * (Ss / NCH);
  u16* P = &Plds[wv][0];

  // preload K frags for step 0
  bv8 kc[8];
  #pragma unroll
  for (int j = 0; j < 4; ++j) {
    const u16* kr = kb + (size_t)(ks0 + j * 16 + lc) * 64;
    kc[2 * j]     = *reinterpret_cast<const bv8*>(kr + lg * 8);
    kc[2 * j + 1] = *reinterpret_cast<const bv8*>(kr + 32 + lg * 8);
  }

  for (int st = 0; st < 4; ++st) {
    int ks = ks0 + st * 64;
    // V loads
    bv8 vf0[4], vf1[4];
    #pragma unroll
    for (int nt = 0; nt < 4; ++nt) {
      const u16* vr = vb + (size_t)(nt * 16 + lc) * Ss + ks;
      vf0[nt] = *reinterpret_cast<const bv8*>(vr + lg * 8);
      vf1[nt] = *reinterpret_cast<const bv8*>(vr + 32 + lg * 8);
    }
    unsigned long long kmask = __ballot(amb[ks + lane] > 0);
    // QK^T swapped
    f32x4 sc[4];
    __builtin_amdgcn_s_setprio(1);
    #pragma unroll
    for (int j = 0; j < 4; ++j) {
      f32x4 z = (f32x4){0.f, 0.f, 0.f, 0.f};
      sc[j] = __builtin_amdgcn_mfma_f32_16x16x32_bf16(kc[2 * j], aq0, z, 0, 0, 0);
      sc[j] = __builtin_amdgcn_mfma_f32_16x16x32_bf16(kc[2 * j + 1], aq1, sc[j], 0, 0, 0);
    }
    __builtin_amdgcn_s_setprio(0);
    // reload kc for next step
    if (st < 3) {
      int ksn = ks0 + (st + 1) * 64;
      #pragma unroll
      for (int j = 0; j < 4; ++j) {
        const u16* kr = kb + (size_t)(ksn + j * 16 + lc) * 64;
        kc[2 * j]     = *reinterpret_cast<const bv8*>(kr + lg * 8);
        kc[2 * j + 1] = *reinterpret_cast<const bv8*>(kr + 32 + lg * 8);
      }
    }
    float mloc = -1e30f;
    if (kmask == ~0ull) {
      #pragma unroll
      for (int j = 0; j < 4; ++j)
        #pragma unroll
        for (int r = 0; r < 4; ++r) mloc = fmaxf(mloc, sc[j][r]);
    } else {
      #pragma unroll
      for (int j = 0; j < 4; ++j)
        #pragma unroll
        for (int r = 0; r < 4; ++r) {
          bool ok = (kmask >> (j * 16 + lg4 + r)) & 1;
          sc[j][r] = ok ? sc[j][r] : -1e9f;
          mloc = fmaxf(mloc, sc[j][r]);
        }
    }
    mloc = fmaxf(mloc, __shfl_xor(mloc, 16));
    mloc = fmaxf(mloc, __shfl_xor(mloc, 32));
    if (__any(mloc > mrun + 8.f)) {
      float nm = fmaxf(mrun, mloc);
      float scal = __expf(mrun - nm);
      mrun = nm;
      lrun *= scal;
      #pragma unroll
      for (int r = 0; r < 4; ++r) {
        float sr = __shfl(scal, lg4 + r);
        #pragma unroll
        for (int nt = 0; nt < 4; ++nt) o[nt][r] *= sr;
      }
    }
    float psum = 0.f;
    #pragma unroll
    for (int j = 0; j < 4; ++j) {
      sv4 pk;
      #pragma unroll
      for (int r = 0; r < 4; ++r) {
        float p = __expf(sc[j][r] - mrun);
        psum += p;
        pk[r] = (short)f2bf(p);
      }
      *reinterpret_cast<sv4*>(P + lc * PSTR + j * 16 + lg4) = pk;
    }
    psum += __shfl_xor(psum, 16);
    psum += __shfl_xor(psum, 32);
    lrun += psum;
    __builtin_amdgcn_s_setprio(1);
    {
      bv8 ap = *reinterpret_cast<const bv8*>(P + lc * PSTR + lg * 8);
      #pragma unroll
      for (int nt = 0; nt < 4; ++nt)
        o[nt] = __builtin_amdgcn_mfma_f32_16x16x32_bf16(ap, vf0[nt], o[nt], 0, 0, 0);
      ap = *reinterpret_cast<const bv8*>(P + lc * PSTR + 32 + lg * 8);
      #pragma unroll
      for (int nt = 0; nt < 4; ++nt)
        o[nt] = __builtin_amdgcn_mfma_f32_16x16x32_bf16(ap, vf1[nt], o[nt], 0, 0, 0);
    }
    __builtin_amdgcn_s_setprio(0);
  }

  float* pb = part + ((size_t)(bh * 3 + wv) * NCH + ch) * PARTF;
  #pragma unroll
  for (int r = 0; r < 4; ++r) {
    int row = lg4 + r;
    #pragma unroll
    for (int nt = 0; nt < 4; ++nt)
      pb[row * 64 + nt * 16 + lc] = o[nt][r];
  }
  if (lg == 0) {
    pb[1024 + lc] = mrun;
    pb[1040 + lc] = lrun;
  }
}

// merge NCH chunk-partials and scatter into ctx rows at gpos
__global__ __launch_bounds__(256)
void attn_gmerge_kernel(const float* __restrict__ part, const int* __restrict__ gpos,
                        u16* __restrict__ ctx) {
  __shared__ float wgt[Gg][NCH];
  __shared__ float sinvl[Gg];
  int bh = blockIdx.x;
  int b = bh / Hh, h = bh - b * Hh;
  int tid = threadIdx.x;
  if (tid < Gg) {
    int qt = tid >> 4, rr = tid & 15;
    const float* pb = part + ((size_t)(bh * 3 + qt) * NCH) * PARTF;
    float mx = -1e30f;
    for (int c = 0; c < NCH; ++c) mx = fmaxf(mx, pb[c * PARTF + 1024 + rr]);
    float l = 0.f;
    for (int c = 0; c < NCH; ++c) {
      float w = __expf(pb[c * PARTF + 1024 + rr] - mx);
      wgt[tid][c] = w;
      l += w * pb[c * PARTF + 1040 + rr];
    }
    sinvl[tid] = 1.0f / l;
  }
  __syncthreads();
  for (int e = tid; e < Gg * 64; e += 256) {
    int row = e >> 6, d = e & 63;
    int qt = row >> 4, rr = row & 15;
    const float* pb = part + ((size_t)(bh * 3 + qt) * NCH) * PARTF + rr * 64 + d;
    float acc = 0.f;
    #pragma unroll
    for (int c = 0; c < NCH; ++c) acc += wgt[row][c] * pb[c * PARTF];
    int pos = gpos[b * Gg + row];
    ctx[((size_t)b * Ss + pos) * Dd + h * 64 + d] = f2bf(acc * sinvl[row]);
  }
}

// ---------------- classifier (bf16 x) ---------------------------------------
__global__ __launch_bounds__(64)
void cls_kernel(const u16* __restrict__ x, const float* __restrict__ W,
                const float* __restrict__ bias, const int* __restrict__ gpos,
                float* __restrict__ out) {
  int r = blockIdx.x;  // b*32 + i
  int b = r >> 5, i = r & 31;
  int pos = gpos[b * Gg + 1 + i];
  int lane = threadIdx.x;
  const u16* xr = x + ((size_t)b * Ss + pos) * Dd;
  float acc[NCLSn] = {0.f, 0.f, 0.f, 0.f, 0.f};
  for (int k = lane; k < Dd; k += 64) {
    float xv = bf2f(xr[k]);
    #pragma unroll
    for (int c = 0; c < NCLSn; ++c) acc[c] += xv * W[c * Dd + k];
  }
  #pragma unroll
  for (int c = 0; c < NCLSn; ++c) {
    #pragma unroll
    for (int off = 1; off < 64; off <<= 1) acc[c] += __shfl_xor(acc[c], off);
  }
  if (lane == 0) {
    #pragma unroll
    for (int c = 0; c < NCLSn; ++c) out[r * NCLSn + c] = acc[c] + bias[c];
  }
}

// ---------------------------------------------------------------------------
extern "C" void kernel_launch(void* const* d_in, const int* in_sizes, int n_in,
                              void* d_out, int out_size, void* d_ws, size_t ws_size,
                              hipStream_t stream) {
  const int* ids     = (const int*)d_in[0];
  const int* amask   = (const int*)d_in[1];
  const float* we    = (const float*)d_in[2];
  const float* pe    = (const float*)d_in[3];
  const float* te    = (const float*)d_in[4];
  const float* embln = (const float*)d_in[5];
  const float* Wqkv  = (const float*)d_in[6];
  const float* bqkv  = (const float*)d_in[7];
  const float* Wqkvg = (const float*)d_in[8];
  const float* bqkvg = (const float*)d_in[9];
  const float* Wo    = (const float*)d_in[10];
  const float* bo    = (const float*)d_in[11];
  const float* ln1   = (const float*)d_in[12];
  const float* Wff1  = (const float*)d_in[13];
  const float* bff1  = (const float*)d_in[14];
  const float* Wff2  = (const float*)d_in[15];
  const float* bff2  = (const float*)d_in[16];
  const float* ln2   = (const float*)d_in[17];
  const float* clsW  = (const float*)d_in[18];
  const float* clsb  = (const float*)d_in[19];
  float* out = (float*)d_out;

  char* ws = (char*)d_ws;
  size_t off = 0;
  auto alloc = [&](size_t bytes) { size_t o = off; off += (bytes + 255) & ~(size_t)255; return o; };

  const size_t DD = (size_t)Dd * Dd;        // 589824
  const size_t DF = (size_t)Dd * 4 * Dd;    // 2359296
  const size_t WL = 7 * DD + 2 * DF;        // elems per layer
  // Wb layout per layer: [q,k,v, gk,gv, gq, wo, ff1, ff2]

  size_t o_cnt  = alloc(Bb * 4);
  size_t o_list = alloc(Bb * 64 * 4);
  size_t o_gpos = alloc(Bb * Gg * 4);
  size_t o_bias = alloc((size_t)Ll * 3840 * 4);
  size_t o_w    = alloc(WL * Ll * 2);
  size_t o_xb   = alloc((size_t)Bb * Ss * Dd * 2);
  // kgf/vgf first: kgf doubles as split-K bf16 buffer B (dead by Wo/FF2)
  size_t o_kgf  = alloc((size_t)Bb * Hh * Ss * 64 * 2);
  size_t o_vgf  = alloc((size_t)Bb * Hh * Ss * 64 * 2);
  size_t o_accB = o_kgf;  // bf16 half-B: 8192*768*2 bytes fits in kgf alone
  size_t o_accA = o_vgf;  // bf16 half-A: same size, vgf also dead by Wo/FF2
  size_t o_qpk  = alloc((size_t)Bb * Hh * Ss * 64 * 2);
  size_t o_kpk  = alloc((size_t)Bb * Hh * SPAD * 64 * 2);
  size_t o_vtpk = alloc((size_t)Bb * Hh * 64 * SPAD * 2);
  size_t o_kg   = alloc((size_t)Bb * Hh * 64 * 64 * 2);
  size_t o_vgt  = alloc((size_t)Bb * Hh * 64 * 64 * 2);
  size_t o_xg   = alloc((size_t)128 * Dd * 2);
  size_t o_qg   = alloc((size_t)128 * Dd * 2);
  size_t o_part = alloc((size_t)Bb * Hh * 3 * NCH * PARTF * 4);
  size_t o_f1b  = o_qpk;  // FFN hidden aliases the (dead-by-then) attention buffers
  {
    size_t f1b_bytes = (size_t)Bb * Ss * 4 * Dd * 2;
    if (off - o_qpk < f1b_bytes) off = o_qpk + ((f1b_bytes + 255) & ~(size_t)255);
  }
  size_t o_ctx = alloc((size_t)Bb * Ss * Dd * 2);
  if (ws_size < off) return;  // workspace too small -> fail visibly

  u16* Wb = (u16*)(ws + o_w);
  int* gposp = (int*)(ws + o_gpos);
  u16* xb = (u16*)(ws + o_xb);
  u16* accA = (u16*)(ws + o_accA);
  u16* accB = (u16*)(ws + o_accB);

  // setup: cnt=0, K/V pads=0 (3.3MB, pads only need to be finite), bias concat
  setup_kernel<<<512, 256, 0, stream>>>((int*)(ws + o_cnt), (u16*)(ws + o_kpk),
      (u16*)(ws + o_vtpk), bqkv, bqkvg, (float*)(ws + o_bias));

  sep_find_kernel<<<(Bb * Ss + 255) / 256, 256, 0, stream>>>(ids, (int*)(ws + o_cnt), (int*)(ws + o_list));
  sep_sort_kernel<<<Bb, 64, 0, stream>>>((int*)(ws + o_cnt), (int*)(ws + o_list), gposp);

  // weight conversions (batched over z); Wb layout [q,k,v,gk,gv,gq,wo,ff1,ff2]
  wconv_kernel<<<dim3(24, 24, 6), 256, 0, stream>>>(Wqkv,       Wb,          Dd, Dd, 3, 3, (long)DD, (long)WL);
  wconv_kernel<<<dim3(24, 24, 2), 256, 0, stream>>>(Wqkvg + DD,     Wb + 3 * DD, Dd, Dd, 1, 3, 0L, (long)WL);  // gk
  wconv_kernel<<<dim3(24, 24, 2), 256, 0, stream>>>(Wqkvg + 2 * DD, Wb + 4 * DD, Dd, Dd, 1, 3, 0L, (long)WL);  // gv
  wconv_kernel<<<dim3(24, 24, 2), 256, 0, stream>>>(Wqkvg,          Wb + 5 * DD, Dd, Dd, 1, 3, 0L, (long)WL);  // gq
  wconv_kernel<<<dim3(24, 24, 2), 256, 0, stream>>>(Wo,         Wb + 6 * DD, Dd, Dd, 1, 1, 0L, (long)WL);
  wconv_kernel<<<dim3(96, 24, 2), 256, 0, stream>>>(Wff1,       Wb + 7 * DD, Dd, 4 * Dd, 1, 1, 0L, (long)WL);
  wconv_kernel<<<dim3(24, 96, 2), 256, 0, stream>>>(Wff2,       Wb + 7 * DD + DF, 4 * Dd, Dd, 1, 1, 0L, (long)WL);

  embed_ln_kernel<<<Bb * Ss, 256, 0, stream>>>(ids, we, pe, te, embln, xb);

  for (int l = 0; l < Ll; ++l) {
    size_t wb = (size_t)l * WL;
    // fused QKV + global K/V projection (N=3840, 5 sections); grid 1920 %8==0
    gemm2_kernel<2, true><<<dim3(30, 64), 256, 0, stream>>>(xb, Wb + wb, (float*)(ws + o_bias) + (size_t)l * 3840,
        (u16*)(ws + o_qpk), (u16*)(ws + o_kpk), (u16*)(ws + o_vtpk),
        (u16*)(ws + o_kgf), (u16*)(ws + o_vgf), 3840, Dd, Dd, 0.125f);
    gather_kernel<<<Bb * Hh + Bb * Gg, 256, 0, stream>>>((u16*)(ws + o_kpk), (u16*)(ws + o_vtpk), xb, gposp,
        (u16*)(ws + o_kg), (u16*)(ws + o_vgt), (u16*)(ws + o_xg));
    // global q projection (M=128 padded rows); 6 blocks -> no XCD swizzle
    gemm2_kernel<4, false><<<dim3(6, 1), 256, 0, stream>>>((u16*)(ws + o_xg), Wb + wb + 5 * DD, bqkvg + (size_t)l * 3 * Dd,
        (u16*)(ws + o_qg), nullptr, nullptr, nullptr, nullptr, Dd, Dd, Dd, 0.125f);
    // attention
    attn_local_kernel<<<LOCAL_NB, 128, 0, stream>>>((u16*)(ws + o_qpk), (u16*)(ws + o_kpk), (u16*)(ws + o_vtpk), (u16*)(ws + o_kg), (u16*)(ws + o_vgt), amask, (u16*)(ws + o_ctx));
    attn_globalq_kernel<<<Bb * Hh * NCH, 192, 0, stream>>>((u16*)(ws + o_qg), (u16*)(ws + o_kgf), (u16*)(ws + o_vgf), amask, (float*)(ws + o_part));
    attn_gmerge_kernel<<<Bb * Hh, 256, 0, stream>>>((float*)(ws + o_part), gposp, (u16*)(ws + o_ctx));
    // output projection (split-K x2, both halves bf16) + LN  [kgf/vgf dead]
    gemm2_kernel<0, true><<<dim3(6, 64, 2), 256, 0, stream>>>((u16*)(ws + o_ctx), Wb + wb + 6 * DD, bo + (size_t)l * Dd,
        accA, accB, nullptr, nullptr, nullptr, Dd, Dd, Dd / 2, 1.0f);
    add_ln3_kernel<<<Bb * Ss, 256, 0, stream>>>(xb, accA, accB, ln1 + (size_t)l * 2 * Dd);
    // FFN
    gemm2_kernel<1, true><<<dim3(24, 64), 256, 0, stream>>>(xb, Wb + wb + 7 * DD, bff1 + (size_t)l * 4 * Dd,
        (u16*)(ws + o_f1b), nullptr, nullptr, nullptr, nullptr, 4 * Dd, Dd, Dd, 1.0f);
    gemm2_kernel<0, true><<<dim3(6, 64, 2), 256, 0, stream>>>((u16*)(ws + o_f1b), Wb + wb + 7 * DD + DF, bff2 + (size_t)l * Dd,
        accA, accB, nullptr, nullptr, nullptr, Dd, 4 * Dd, 2 * Dd, 1.0f);
    add_ln3_kernel<<<Bb * Ss, 256, 0, stream>>>(xb, accA, accB, ln2 + (size_t)l * 2 * Dd);
  }

  cls_kernel<<<Bb * NSEPn, 64, 0, stream>>>(xb, clsW, clsb, gposp, out);
}